// Round 1
// baseline (1279.976 us; speedup 1.0000x reference)
//
#include <hip/hip_runtime.h>
#include <hip/hip_bf16.h>

// Shapes
#define Bz 32
#define Tz 256
#define Fz 64
#define Dz 768
#define Sz 768
#define Hz 256
#define NHz 4
#define HDz 64
#define BTz 8192  // B*T

// ---------------------------------------------------------------------------
// Kernel 1: masking. valid/stoch/surv/safe + 64-bit survivor mask per (b,t).
// ---------------------------------------------------------------------------
__global__ __launch_bounds__(256) void mask_kernel(
    const float* __restrict__ bd, const float* __restrict__ mp,
    float* __restrict__ safe, float* __restrict__ stoch_out,
    unsigned long long* __restrict__ mask64)
{
    int idx = blockIdx.x * 256 + threadIdx.x;   // over B*T*F = 524288
    float x = bd[idx];
    float p = mp[idx];
    unsigned xb = __float_as_uint(x);
    bool valid = ((xb & 0x7fffffffu) <= 0x7f800000u);   // !isnan
    bool st = (p < 0.3f) && valid;
    bool sv = valid && !st;
    safe[idx] = sv ? x : 0.0f;
    stoch_out[idx] = st ? 1.0f : 0.0f;
    unsigned long long m = __ballot(sv);        // wave=64 == F
    if ((threadIdx.x & 63) == 0) mask64[idx >> 6] = m;
}

// ---------------------------------------------------------------------------
// Kernel 2: pooled sapbert query bias. pooled[h] = mean_f(E @ Wsap + b)[f,h]
// = colmean(E) @ Wsap + b.  One block, 256 threads.
// ---------------------------------------------------------------------------
__global__ __launch_bounds__(256) void pooled_kernel(
    const float* __restrict__ E, const float* __restrict__ W_sap,
    const float* __restrict__ b_sap, float* __restrict__ pooled)
{
    __shared__ float colmean[Sz];
    for (int s = threadIdx.x; s < Sz; s += 256) {
        float acc = 0.0f;
        for (int f = 0; f < Fz; ++f) acc += E[f * Sz + s];
        colmean[s] = acc * (1.0f / 64.0f);
    }
    __syncthreads();
    int h = threadIdx.x;
    float acc = b_sap[h];
    for (int s = 0; s < Sz; ++s) acc += colmean[s] * W_sap[s * Hz + h];
    pooled[h] = acc;
}

// ---------------------------------------------------------------------------
// Kernel 3: build list of present (i<j) pairs. plist[0]=count, pairs at [1..]
// pair encoded as i*64+j (direct row index into pair_emb).
// One block, 64 threads.
// ---------------------------------------------------------------------------
__global__ __launch_bounds__(64) void pairlist_kernel(
    const int* __restrict__ present, unsigned int* __restrict__ plist)
{
    __shared__ int cnt[64];
    __shared__ int off[64];
    int i = threadIdx.x;
    int c = 0;
    for (int j = i + 1; j < 64; ++j)
        if (present[i * 64 + j] != 0) c++;
    cnt[i] = c;
    __syncthreads();
    if (i == 0) {
        int t = 0;
        for (int r = 0; r < 64; ++r) { off[r] = t; t += cnt[r]; }
        plist[0] = (unsigned)t;
    }
    __syncthreads();
    int o = 1 + off[i];
    for (int j = i + 1; j < 64; ++j)
        if (present[i * 64 + j] != 0) plist[o++] = (unsigned)(i * 64 + j);
}

// ---------------------------------------------------------------------------
// Kernel 5: pair-context. One block per (b,t). Scan present-pair list against
// survivor bitmask (uniform branch), accumulate pair_emb rows (768 across 256
// threads, 3 elems/thread).
// ---------------------------------------------------------------------------
__global__ __launch_bounds__(256) void pairctx_kernel(
    const float* __restrict__ pair_emb, const unsigned int* __restrict__ plist,
    const unsigned long long* __restrict__ mask64, float* __restrict__ ctx)
{
    int bt = blockIdx.x;
    unsigned long long m = mask64[bt];
    int n = (int)plist[0];
    int t = threadIdx.x;
    float a0 = 0.0f, a1 = 0.0f, a2 = 0.0f;
    int count = 0;
    for (int p = 0; p < n; ++p) {
        unsigned ij = plist[1 + p];
        int i = ij >> 6, j = ij & 63;
        if (((m >> i) & 1ull) & ((m >> j) & 1ull)) {
            const float* src = pair_emb + (size_t)ij * Dz;
            a0 += src[t];
            a1 += src[t + 256];
            a2 += src[t + 512];
            count++;
        }
    }
    float s = (count > 0) ? (1.0f / (float)count) : 0.0f;
    float* dst = ctx + (size_t)bt * Dz;
    dst[t] = a0 * s; dst[t + 256] = a1 * s; dst[t + 512] = a2 * s;
}

// ---------------------------------------------------------------------------
// Generic tiled f32 GEMM: C[M,N] = (A (+A2)) @ B + bias (+bias2)
// A:[M,K] row-major, B:[K,N] row-major. All dims divide tile sizes.
// ---------------------------------------------------------------------------
template <int BM, int BN, int BK, int TM, int TN>
__global__ __launch_bounds__(256) void sgemm_kernel(
    const float* __restrict__ A, const float* __restrict__ A2,
    const float* __restrict__ Bm, const float* __restrict__ bias,
    const float* __restrict__ bias2, float* __restrict__ C,
    int M, int N, int K)
{
    __shared__ float As[BK][BM];
    __shared__ float Bs[BK][BN];
    const int tid = threadIdx.x;
    const int row0 = blockIdx.y * BM, col0 = blockIdx.x * BN;
    constexpr int NTX = BN / TN;
    const int tx = tid % NTX, ty = tid / NTX;
    float acc[TM][TN] = {};
    constexpr int AF4 = BM * BK / 4;
    constexpr int BF4 = BK * BN / 4;

    for (int k0 = 0; k0 < K; k0 += BK) {
        for (int idx = tid; idx < AF4; idx += 256) {
            int ar = idx / (BK / 4);
            int ac = (idx % (BK / 4)) * 4;
            float4 av = *(const float4*)&A[(size_t)(row0 + ar) * K + k0 + ac];
            if (A2) {
                float4 a2 = *(const float4*)&A2[(size_t)(row0 + ar) * K + k0 + ac];
                av.x += a2.x; av.y += a2.y; av.z += a2.z; av.w += a2.w;
            }
            As[ac + 0][ar] = av.x; As[ac + 1][ar] = av.y;
            As[ac + 2][ar] = av.z; As[ac + 3][ar] = av.w;
        }
        for (int idx = tid; idx < BF4; idx += 256) {
            int br = idx / (BN / 4);
            int bc = (idx % (BN / 4)) * 4;
            *(float4*)&Bs[br][bc] = *(const float4*)&Bm[(size_t)(k0 + br) * N + col0 + bc];
        }
        __syncthreads();
        #pragma unroll
        for (int kk = 0; kk < BK; ++kk) {
            float a[TM], b[TN];
            #pragma unroll
            for (int i = 0; i < TM; i += 4) *(float4*)&a[i] = *(const float4*)&As[kk][ty * TM + i];
            #pragma unroll
            for (int j = 0; j < TN; j += 4) *(float4*)&b[j] = *(const float4*)&Bs[kk][tx * TN + j];
            #pragma unroll
            for (int i = 0; i < TM; ++i)
                #pragma unroll
                for (int j = 0; j < TN; ++j)
                    acc[i][j] += a[i] * b[j];
        }
        __syncthreads();
    }

    #pragma unroll
    for (int i = 0; i < TM; ++i) {
        int r = row0 + ty * TM + i;
        #pragma unroll
        for (int j = 0; j < TN; j += 4) {
            int c = col0 + tx * TN + j;
            float4 o;
            o.x = acc[i][j]; o.y = acc[i][j + 1]; o.z = acc[i][j + 2]; o.w = acc[i][j + 3];
            if (bias)  { o.x += bias[c];  o.y += bias[c + 1];  o.z += bias[c + 2];  o.w += bias[c + 3]; }
            if (bias2) { o.x += bias2[c]; o.y += bias2[c + 1]; o.z += bias2[c + 2]; o.w += bias2[c + 3]; }
            *(float4*)&C[(size_t)r * N + c] = o;
        }
    }
}

// ---------------------------------------------------------------------------
// Kernel 10: attention. One block per (b,h,half); thread owns one query row.
// K tile in LDS (64 KiB); V read from cache. Writes PV (pre-Wo), unnormalized
// probs and per-row denominators.
// ---------------------------------------------------------------------------
__global__ __launch_bounds__(128) void attn_kernel(
    const float* __restrict__ q, const float* __restrict__ k,
    const float* __restrict__ v, float* __restrict__ pv,
    float* __restrict__ probs_un, float* __restrict__ denom)
{
    int bh = blockIdx.x >> 1;
    int half = blockIdx.x & 1;
    int b = bh >> 2, h = bh & 3;
    __shared__ float Kl[Tz][HDz];

    const float* kbase = k + (size_t)(b * Tz) * Hz + h * HDz;
    for (int e = threadIdx.x; e < Tz * HDz / 4; e += 128) {
        int row = e >> 4;              // 16 float4 per row
        int c4 = (e & 15) << 2;
        *(float4*)&Kl[row][c4] = *(const float4*)&kbase[(size_t)row * Hz + c4];
    }
    __syncthreads();

    int tq = half * 128 + threadIdx.x;
    float qr[HDz];
    const float* qrow = q + (size_t)(b * Tz + tq) * Hz + h * HDz;
    #pragma unroll
    for (int d = 0; d < HDz; d += 4) *(float4*)&qr[d] = *(const float4*)&qrow[d];
    #pragma unroll
    for (int d = 0; d < HDz; ++d) qr[d] *= 0.125f;   // 1/sqrt(64)

    // pass 1: row max
    float mmax = -1e30f;
    for (int tk = 0; tk < Tz; ++tk) {
        float s = 0.0f;
        #pragma unroll
        for (int d = 0; d < HDz; ++d) s += qr[d] * Kl[tk][d];
        mmax = fmaxf(mmax, s);
    }

    // pass 2: exp, sum, PV
    const float* vbase = v + (size_t)(b * Tz) * Hz + h * HDz;
    float acc[HDz];
    #pragma unroll
    for (int d = 0; d < HDz; ++d) acc[d] = 0.0f;
    float sum = 0.0f;
    float* prow = probs_un + ((size_t)bh * Tz + tq) * Tz;
    for (int tk = 0; tk < Tz; ++tk) {
        float s = 0.0f;
        #pragma unroll
        for (int d = 0; d < HDz; ++d) s += qr[d] * Kl[tk][d];
        float p = __expf(s - mmax);
        prow[tk] = p;
        sum += p;
        const float* vr = vbase + (size_t)tk * Hz;
        #pragma unroll
        for (int d = 0; d < HDz; ++d) acc[d] += p * vr[d];
    }
    float inv = 1.0f / sum;
    float* dst = pv + (size_t)(b * Tz + tq) * Hz + h * HDz;
    #pragma unroll
    for (int d = 0; d < HDz; d += 4) {
        float4 o; o.x = acc[d] * inv; o.y = acc[d + 1] * inv;
        o.z = acc[d + 2] * inv; o.w = acc[d + 3] * inv;
        *(float4*)&dst[d] = o;
    }
    denom[bh * Tz + tq] = sum;
}

// ---------------------------------------------------------------------------
// Kernel 12: mean over heads of normalized probs -> out3 [B,T,T]
// ---------------------------------------------------------------------------
__global__ __launch_bounds__(256) void meanheads_kernel(
    const float* __restrict__ probs_un, const float* __restrict__ denom,
    float* __restrict__ out3)
{
    int idx = blockIdx.x * 256 + threadIdx.x;  // float4 index over B*T*T/4
    int tk4 = idx & 63;                        // T/4 = 64 float4 per row
    int btq = idx >> 6;
    int b = btq >> 8, tq = btq & 255;
    float4 acc = {0, 0, 0, 0};
    #pragma unroll
    for (int h = 0; h < 4; ++h) {
        int bh = b * 4 + h;
        float inv = 0.25f / denom[bh * Tz + tq];
        float4 p = *(const float4*)&probs_un[(((size_t)bh * Tz + tq) << 8) + tk4 * 4];
        acc.x += p.x * inv; acc.y += p.y * inv; acc.z += p.z * inv; acc.w += p.w * inv;
    }
    *(float4*)&out3[(size_t)idx * 4] = acc;
}

// ---------------------------------------------------------------------------
extern "C" void kernel_launch(void* const* d_in, const int* in_sizes, int n_in,
                              void* d_out, int out_size, void* d_ws, size_t ws_size,
                              hipStream_t stream)
{
    const float* batch_data = (const float*)d_in[0];
    const float* mask_probs = (const float*)d_in[1];
    const float* sapE       = (const float*)d_in[2];
    const float* pair_emb   = (const float*)d_in[3];
    const int*   pair_present = (const int*)d_in[4];
    const float* W_num = (const float*)d_in[5];  const float* b_num = (const float*)d_in[6];
    const float* W_sap = (const float*)d_in[7];  const float* b_sap = (const float*)d_in[8];
    const float* W_ad  = (const float*)d_in[9];  const float* b_ad  = (const float*)d_in[10];
    const float* Wq = (const float*)d_in[11]; const float* bq = (const float*)d_in[12];
    const float* Wk = (const float*)d_in[13]; const float* bk = (const float*)d_in[14];
    const float* Wv = (const float*)d_in[15]; const float* bv = (const float*)d_in[16];
    const float* Wo = (const float*)d_in[17]; const float* bo = (const float*)d_in[18];
    const float* W_out = (const float*)d_in[19]; const float* b_out = (const float*)d_in[20];

    float* out = (float*)d_out;
    float* out_imputed = out;                 // [B,T,F]   524288
    float* out_stoch   = out + 524288;        // [B,T,F]   524288
    float* out_attn    = out + 1048576;       // [B,T,T]   2097152

    float* ws = (float*)d_ws;
    float* safe  = ws;                        // 524288
    float* query = ws + 524288;               // 2097152
    float* ctx   = ws + 2621440;              // 6291456   (aliased by probs_un later)
    float* kv    = ws + 8912896;              // 2097152   (inside probs_un alias, consumed before attn)
    float* qb    = ws + 11010048;             // 2097152   (later reused for attn_proj)
    float* kb    = ws + 13107200;             // 2097152
    float* vb    = ws + 15204352;             // 2097152
    float* pv    = ws + 17301504;             // 2097152
    float* pooled = ws + 19398656;            // 256
    unsigned long long* mask64 = (unsigned long long*)(ws + 19398912); // 8192 u64
    unsigned int* plist = (unsigned int*)(ws + 19415296);              // 4097 u32
    float* denom = ws + 19419392;             // 32768
    float* probs_un = ctx;                    // 8388608 (= ctx+kv region)

    // 1. masking
    mask_kernel<<<2048, 256, 0, stream>>>(batch_data, mask_probs, safe, out_stoch, mask64);
    // 2. pooled sapbert
    pooled_kernel<<<1, 256, 0, stream>>>(sapE, W_sap, b_sap, pooled);
    // 3. present-pair list
    pairlist_kernel<<<1, 64, 0, stream>>>(pair_present, plist);
    // 4. query = safe @ W_num + b_num + pooled   [8192,64]@[64,256]
    sgemm_kernel<128,128,8,8,8><<<dim3(2,64), 256, 0, stream>>>(
        safe, nullptr, W_num, b_num, pooled, query, BTz, Hz, Fz);
    // 5. pair context
    pairctx_kernel<<<BTz, 256, 0, stream>>>(pair_emb, plist, mask64, ctx);
    // 6. kv = ctx @ W_ad + b_ad   [8192,768]@[768,256]
    sgemm_kernel<128,128,8,8,8><<<dim3(2,64), 256, 0, stream>>>(
        ctx, nullptr, W_ad, b_ad, nullptr, kv, BTz, Hz, Dz);
    // 7-9. q,k,v projections [8192,256]@[256,256]
    sgemm_kernel<128,128,8,8,8><<<dim3(2,64), 256, 0, stream>>>(
        query, nullptr, Wq, bq, nullptr, qb, BTz, Hz, Hz);
    sgemm_kernel<128,128,8,8,8><<<dim3(2,64), 256, 0, stream>>>(
        kv, nullptr, Wk, bk, nullptr, kb, BTz, Hz, Hz);
    sgemm_kernel<128,128,8,8,8><<<dim3(2,64), 256, 0, stream>>>(
        kv, nullptr, Wv, bv, nullptr, vb, BTz, Hz, Hz);
    // 10. attention
    attn_kernel<<<256, 128, 0, stream>>>(qb, kb, vb, pv, probs_un, denom);
    // 11. attn_proj = pv @ Wo + bo  -> reuse qb
    sgemm_kernel<128,128,8,8,8><<<dim3(2,64), 256, 0, stream>>>(
        pv, nullptr, Wo, bo, nullptr, qb, BTz, Hz, Hz);
    // 12. mean over heads -> out3
    meanheads_kernel<<<2048, 256, 0, stream>>>(probs_un, denom, out_attn);
    // 13. imputed = (query + attn_proj) @ W_out + b_out  [8192,256]@[256,64]
    sgemm_kernel<64,64,8,4,4><<<dim3(1,128), 256, 0, stream>>>(
        query, qb, W_out, b_out, nullptr, out_imputed, BTz, Fz, Hz);
}

// Round 2
// 1159.574 us; speedup vs baseline: 1.1038x; 1.1038x over previous
//
#include <hip/hip_runtime.h>
#include <hip/hip_bf16.h>

// Shapes
#define Bz 32
#define Tz 256
#define Fz 64
#define Dz 768
#define Sz 768
#define Hz 256
#define NHz 4
#define HDz 64
#define BTz 8192  // B*T
#define Gz 16     // bt rows per pairctx block

// ---------------------------------------------------------------------------
// Kernel 1: masking. valid/stoch/surv/safe + 64-bit survivor mask per (b,t).
// ---------------------------------------------------------------------------
__global__ __launch_bounds__(256) void mask_kernel(
    const float* __restrict__ bd, const float* __restrict__ mp,
    float* __restrict__ safe, float* __restrict__ stoch_out,
    unsigned long long* __restrict__ mask64)
{
    int idx = blockIdx.x * 256 + threadIdx.x;   // over B*T*F = 524288
    float x = bd[idx];
    float p = mp[idx];
    unsigned xb = __float_as_uint(x);
    bool valid = ((xb & 0x7fffffffu) <= 0x7f800000u);   // !isnan
    bool st = (p < 0.3f) && valid;
    bool sv = valid && !st;
    safe[idx] = sv ? x : 0.0f;
    stoch_out[idx] = st ? 1.0f : 0.0f;
    unsigned long long m = __ballot(sv);        // wave=64 == F
    if ((threadIdx.x & 63) == 0) mask64[idx >> 6] = m;
}

// ---------------------------------------------------------------------------
// Kernel 2: pooled sapbert query bias. pooled[h] = colmean(E) @ Wsap + b.
// ---------------------------------------------------------------------------
__global__ __launch_bounds__(256) void pooled_kernel(
    const float* __restrict__ E, const float* __restrict__ W_sap,
    const float* __restrict__ b_sap, float* __restrict__ pooled)
{
    __shared__ float colmean[Sz];
    for (int s = threadIdx.x; s < Sz; s += 256) {
        float acc = 0.0f;
        for (int f = 0; f < Fz; ++f) acc += E[f * Sz + s];
        colmean[s] = acc * (1.0f / 64.0f);
    }
    __syncthreads();
    int h = threadIdx.x;
    float acc = b_sap[h];
    for (int s = 0; s < Sz; ++s) acc += colmean[s] * W_sap[s * Hz + h];
    pooled[h] = acc;
}

// ---------------------------------------------------------------------------
// Kernel 3: present (i<j) pair list + per-row present bitmasks.
// plist[0]=count, pairs at [1..] encoded i*64+j. rowmask[i] = bits j>i present.
// ---------------------------------------------------------------------------
__global__ __launch_bounds__(64) void pairlist_kernel(
    const int* __restrict__ present, unsigned int* __restrict__ plist,
    unsigned long long* __restrict__ rowmask)
{
    __shared__ int cnt[64];
    __shared__ int off[64];
    int i = threadIdx.x;
    int c = 0;
    unsigned long long rm = 0ull;
    for (int j = i + 1; j < 64; ++j)
        if (present[i * 64 + j] != 0) { c++; rm |= 1ull << j; }
    cnt[i] = c;
    rowmask[i] = rm;
    __syncthreads();
    if (i == 0) {
        int t = 0;
        for (int r = 0; r < 64; ++r) { off[r] = t; t += cnt[r]; }
        plist[0] = (unsigned)t;
    }
    __syncthreads();
    int o = 1 + off[i];
    for (int j = i + 1; j < 64; ++j)
        if (present[i * 64 + j] != 0) plist[o++] = (unsigned)(i * 64 + j);
}

// ---------------------------------------------------------------------------
// Kernel 5: grouped pair-context. One block per Gz bt rows. Each pair row is
// read once (3 coalesced floats/thread) and accumulated into Gz accumulators
// with a wave-uniform 0/1 float multiplier (SGPR). Count via popcount.
// ---------------------------------------------------------------------------
__global__ __launch_bounds__(256) void pairctx_grouped_kernel(
    const float* __restrict__ pair_emb, const unsigned int* __restrict__ plist,
    const unsigned long long* __restrict__ rowmask,
    const unsigned long long* __restrict__ mask64, float* __restrict__ ctx)
{
    const int bt0 = blockIdx.x * Gz;
    const int t = threadIdx.x;
    __shared__ float s_inv[Gz];

    unsigned long long m[Gz];
    #pragma unroll
    for (int g = 0; g < Gz; ++g) m[g] = mask64[bt0 + g];

    if (t < Gz) {
        unsigned long long mm = m[t];
        unsigned long long r = mm;
        int cnt = 0;
        while (r) {
            int i = __ffsll(r) - 1;
            r &= r - 1;
            cnt += __popcll(mm & rowmask[i]);
        }
        s_inv[t] = cnt > 0 ? 1.0f / (float)cnt : 0.0f;
    }

    const int n = (int)plist[0];
    float a[Gz][3] = {};

    int p = 0;
    for (; p + 4 <= n; p += 4) {
        unsigned ij0 = plist[1 + p + 0];
        unsigned ij1 = plist[1 + p + 1];
        unsigned ij2 = plist[1 + p + 2];
        unsigned ij3 = plist[1 + p + 3];
        const float* s0 = pair_emb + (size_t)ij0 * Dz;
        const float* s1 = pair_emb + (size_t)ij1 * Dz;
        const float* s2 = pair_emb + (size_t)ij2 * Dz;
        const float* s3 = pair_emb + (size_t)ij3 * Dz;
        float v00 = s0[t], v01 = s0[t + 256], v02 = s0[t + 512];
        float v10 = s1[t], v11 = s1[t + 256], v12 = s1[t + 512];
        float v20 = s2[t], v21 = s2[t + 256], v22 = s2[t + 512];
        float v30 = s3[t], v31 = s3[t + 256], v32 = s3[t + 512];
        int i0 = ij0 >> 6, j0 = ij0 & 63;
        int i1 = ij1 >> 6, j1 = ij1 & 63;
        int i2 = ij2 >> 6, j2 = ij2 & 63;
        int i3 = ij3 >> 6, j3 = ij3 & 63;
        #pragma unroll
        for (int g = 0; g < Gz; ++g) {
            float f0 = __uint_as_float(((m[g] >> i0) & (m[g] >> j0) & 1ull) ? 0x3f800000u : 0u);
            float f1 = __uint_as_float(((m[g] >> i1) & (m[g] >> j1) & 1ull) ? 0x3f800000u : 0u);
            float f2 = __uint_as_float(((m[g] >> i2) & (m[g] >> j2) & 1ull) ? 0x3f800000u : 0u);
            float f3 = __uint_as_float(((m[g] >> i3) & (m[g] >> j3) & 1ull) ? 0x3f800000u : 0u);
            a[g][0] = fmaf(f0, v00, a[g][0]); a[g][1] = fmaf(f0, v01, a[g][1]); a[g][2] = fmaf(f0, v02, a[g][2]);
            a[g][0] = fmaf(f1, v10, a[g][0]); a[g][1] = fmaf(f1, v11, a[g][1]); a[g][2] = fmaf(f1, v12, a[g][2]);
            a[g][0] = fmaf(f2, v20, a[g][0]); a[g][1] = fmaf(f2, v21, a[g][1]); a[g][2] = fmaf(f2, v22, a[g][2]);
            a[g][0] = fmaf(f3, v30, a[g][0]); a[g][1] = fmaf(f3, v31, a[g][1]); a[g][2] = fmaf(f3, v32, a[g][2]);
        }
    }
    for (; p < n; ++p) {
        unsigned ij = plist[1 + p];
        const float* src = pair_emb + (size_t)ij * Dz;
        float v0 = src[t], v1 = src[t + 256], v2 = src[t + 512];
        int i = ij >> 6, j = ij & 63;
        #pragma unroll
        for (int g = 0; g < Gz; ++g) {
            float f = __uint_as_float(((m[g] >> i) & (m[g] >> j) & 1ull) ? 0x3f800000u : 0u);
            a[g][0] = fmaf(f, v0, a[g][0]);
            a[g][1] = fmaf(f, v1, a[g][1]);
            a[g][2] = fmaf(f, v2, a[g][2]);
        }
    }

    __syncthreads();
    #pragma unroll
    for (int g = 0; g < Gz; ++g) {
        float inv = s_inv[g];
        float* dst = ctx + (size_t)(bt0 + g) * Dz;
        dst[t] = a[g][0] * inv;
        dst[t + 256] = a[g][1] * inv;
        dst[t + 512] = a[g][2] * inv;
    }
}

// ---------------------------------------------------------------------------
// Generic tiled f32 GEMM: C[M,N] = (A (+A2)) @ B + bias (+bias2)
// ---------------------------------------------------------------------------
template <int BM, int BN, int BK, int TM, int TN>
__global__ __launch_bounds__(256) void sgemm_kernel(
    const float* __restrict__ A, const float* __restrict__ A2,
    const float* __restrict__ Bm, const float* __restrict__ bias,
    const float* __restrict__ bias2, float* __restrict__ C,
    int M, int N, int K)
{
    __shared__ float As[BK][BM];
    __shared__ float Bs[BK][BN];
    const int tid = threadIdx.x;
    const int row0 = blockIdx.y * BM, col0 = blockIdx.x * BN;
    constexpr int NTX = BN / TN;
    const int tx = tid % NTX, ty = tid / NTX;
    float acc[TM][TN] = {};
    constexpr int AF4 = BM * BK / 4;
    constexpr int BF4 = BK * BN / 4;

    for (int k0 = 0; k0 < K; k0 += BK) {
        for (int idx = tid; idx < AF4; idx += 256) {
            int ar = idx / (BK / 4);
            int ac = (idx % (BK / 4)) * 4;
            float4 av = *(const float4*)&A[(size_t)(row0 + ar) * K + k0 + ac];
            if (A2) {
                float4 a2 = *(const float4*)&A2[(size_t)(row0 + ar) * K + k0 + ac];
                av.x += a2.x; av.y += a2.y; av.z += a2.z; av.w += a2.w;
            }
            As[ac + 0][ar] = av.x; As[ac + 1][ar] = av.y;
            As[ac + 2][ar] = av.z; As[ac + 3][ar] = av.w;
        }
        for (int idx = tid; idx < BF4; idx += 256) {
            int br = idx / (BN / 4);
            int bc = (idx % (BN / 4)) * 4;
            *(float4*)&Bs[br][bc] = *(const float4*)&Bm[(size_t)(k0 + br) * N + col0 + bc];
        }
        __syncthreads();
        #pragma unroll
        for (int kk = 0; kk < BK; ++kk) {
            float a[TM], b[TN];
            #pragma unroll
            for (int i = 0; i < TM; i += 4) *(float4*)&a[i] = *(const float4*)&As[kk][ty * TM + i];
            #pragma unroll
            for (int j = 0; j < TN; j += 4) *(float4*)&b[j] = *(const float4*)&Bs[kk][tx * TN + j];
            #pragma unroll
            for (int i = 0; i < TM; ++i)
                #pragma unroll
                for (int j = 0; j < TN; ++j)
                    acc[i][j] += a[i] * b[j];
        }
        __syncthreads();
    }

    #pragma unroll
    for (int i = 0; i < TM; ++i) {
        int r = row0 + ty * TM + i;
        #pragma unroll
        for (int j = 0; j < TN; j += 4) {
            int c = col0 + tx * TN + j;
            float4 o;
            o.x = acc[i][j]; o.y = acc[i][j + 1]; o.z = acc[i][j + 2]; o.w = acc[i][j + 3];
            if (bias)  { o.x += bias[c];  o.y += bias[c + 1];  o.z += bias[c + 2];  o.w += bias[c + 3]; }
            if (bias2) { o.x += bias2[c]; o.y += bias2[c + 1]; o.z += bias2[c + 2]; o.w += bias2[c + 3]; }
            *(float4*)&C[(size_t)r * N + c] = o;
        }
    }
}

// ---------------------------------------------------------------------------
// Kernel 10: attention. One block per (b,h,half); thread owns one query row.
// ---------------------------------------------------------------------------
__global__ __launch_bounds__(128) void attn_kernel(
    const float* __restrict__ q, const float* __restrict__ k,
    const float* __restrict__ v, float* __restrict__ pv,
    float* __restrict__ probs_un, float* __restrict__ denom)
{
    int bh = blockIdx.x >> 1;
    int half = blockIdx.x & 1;
    int b = bh >> 2, h = bh & 3;
    __shared__ float Kl[Tz][HDz];

    const float* kbase = k + (size_t)(b * Tz) * Hz + h * HDz;
    for (int e = threadIdx.x; e < Tz * HDz / 4; e += 128) {
        int row = e >> 4;
        int c4 = (e & 15) << 2;
        *(float4*)&Kl[row][c4] = *(const float4*)&kbase[(size_t)row * Hz + c4];
    }
    __syncthreads();

    int tq = half * 128 + threadIdx.x;
    float qr[HDz];
    const float* qrow = q + (size_t)(b * Tz + tq) * Hz + h * HDz;
    #pragma unroll
    for (int d = 0; d < HDz; d += 4) *(float4*)&qr[d] = *(const float4*)&qrow[d];
    #pragma unroll
    for (int d = 0; d < HDz; ++d) qr[d] *= 0.125f;

    float mmax = -1e30f;
    for (int tk = 0; tk < Tz; ++tk) {
        float s = 0.0f;
        #pragma unroll
        for (int d = 0; d < HDz; ++d) s += qr[d] * Kl[tk][d];
        mmax = fmaxf(mmax, s);
    }

    const float* vbase = v + (size_t)(b * Tz) * Hz + h * HDz;
    float acc[HDz];
    #pragma unroll
    for (int d = 0; d < HDz; ++d) acc[d] = 0.0f;
    float sum = 0.0f;
    float* prow = probs_un + ((size_t)bh * Tz + tq) * Tz;
    for (int tk = 0; tk < Tz; ++tk) {
        float s = 0.0f;
        #pragma unroll
        for (int d = 0; d < HDz; ++d) s += qr[d] * Kl[tk][d];
        float p = __expf(s - mmax);
        prow[tk] = p;
        sum += p;
        const float* vr = vbase + (size_t)tk * Hz;
        #pragma unroll
        for (int d = 0; d < HDz; ++d) acc[d] += p * vr[d];
    }
    float inv = 1.0f / sum;
    float* dst = pv + (size_t)(b * Tz + tq) * Hz + h * HDz;
    #pragma unroll
    for (int d = 0; d < HDz; d += 4) {
        float4 o; o.x = acc[d] * inv; o.y = acc[d + 1] * inv;
        o.z = acc[d + 2] * inv; o.w = acc[d + 3] * inv;
        *(float4*)&dst[d] = o;
    }
    denom[bh * Tz + tq] = sum;
}

// ---------------------------------------------------------------------------
// Kernel 12: mean over heads of normalized probs -> out3 [B,T,T]
// ---------------------------------------------------------------------------
__global__ __launch_bounds__(256) void meanheads_kernel(
    const float* __restrict__ probs_un, const float* __restrict__ denom,
    float* __restrict__ out3)
{
    int idx = blockIdx.x * 256 + threadIdx.x;
    int tk4 = idx & 63;
    int btq = idx >> 6;
    int b = btq >> 8, tq = btq & 255;
    float4 acc = {0, 0, 0, 0};
    #pragma unroll
    for (int h = 0; h < 4; ++h) {
        int bh = b * 4 + h;
        float inv = 0.25f / denom[bh * Tz + tq];
        float4 p = *(const float4*)&probs_un[(((size_t)bh * Tz + tq) << 8) + tk4 * 4];
        acc.x += p.x * inv; acc.y += p.y * inv; acc.z += p.z * inv; acc.w += p.w * inv;
    }
    *(float4*)&out3[(size_t)idx * 4] = acc;
}

// ---------------------------------------------------------------------------
extern "C" void kernel_launch(void* const* d_in, const int* in_sizes, int n_in,
                              void* d_out, int out_size, void* d_ws, size_t ws_size,
                              hipStream_t stream)
{
    const float* batch_data = (const float*)d_in[0];
    const float* mask_probs = (const float*)d_in[1];
    const float* sapE       = (const float*)d_in[2];
    const float* pair_emb   = (const float*)d_in[3];
    const int*   pair_present = (const int*)d_in[4];
    const float* W_num = (const float*)d_in[5];  const float* b_num = (const float*)d_in[6];
    const float* W_sap = (const float*)d_in[7];  const float* b_sap = (const float*)d_in[8];
    const float* W_ad  = (const float*)d_in[9];  const float* b_ad  = (const float*)d_in[10];
    const float* Wq = (const float*)d_in[11]; const float* bq = (const float*)d_in[12];
    const float* Wk = (const float*)d_in[13]; const float* bk = (const float*)d_in[14];
    const float* Wv = (const float*)d_in[15]; const float* bv = (const float*)d_in[16];
    const float* Wo = (const float*)d_in[17]; const float* bo = (const float*)d_in[18];
    const float* W_out = (const float*)d_in[19]; const float* b_out = (const float*)d_in[20];

    float* out = (float*)d_out;
    float* out_imputed = out;                 // [B,T,F]   524288
    float* out_stoch   = out + 524288;        // [B,T,F]   524288
    float* out_attn    = out + 1048576;       // [B,T,T]   2097152

    float* ws = (float*)d_ws;
    float* safe  = ws;                        // 524288
    float* query = ws + 524288;               // 2097152
    float* ctx   = ws + 2621440;              // 6291456   (aliased by probs_un later)
    float* kv    = ws + 8912896;              // 2097152   (consumed before attn)
    float* qb    = ws + 11010048;             // 2097152   (reused for attn_proj)
    float* kb    = ws + 13107200;             // 2097152
    float* vb    = ws + 15204352;             // 2097152
    float* pv    = ws + 17301504;             // 2097152
    float* pooled = ws + 19398656;            // 256
    unsigned long long* mask64 = (unsigned long long*)(ws + 19398912); // 8192 u64
    unsigned int* plist = (unsigned int*)(ws + 19415296);              // 2017 u32 used (4104 reserved)
    unsigned long long* rowmask = (unsigned long long*)(plist + 2020); // 64 u64, inside plist slack
    float* denom = ws + 19419392;             // 32768
    float* probs_un = ctx;                    // 8388608 (= ctx+kv region)

    // 1. masking
    mask_kernel<<<2048, 256, 0, stream>>>(batch_data, mask_probs, safe, out_stoch, mask64);
    // 2. pooled sapbert
    pooled_kernel<<<1, 256, 0, stream>>>(sapE, W_sap, b_sap, pooled);
    // 3. present-pair list + row masks
    pairlist_kernel<<<1, 64, 0, stream>>>(pair_present, plist, rowmask);
    // 4. query = safe @ W_num + b_num + pooled   [8192,64]@[64,256]
    sgemm_kernel<128,128,8,8,8><<<dim3(2,64), 256, 0, stream>>>(
        safe, nullptr, W_num, b_num, pooled, query, BTz, Hz, Fz);
    // 5. pair context (grouped, Gz bt per block)
    pairctx_grouped_kernel<<<BTz / Gz, 256, 0, stream>>>(pair_emb, plist, rowmask, mask64, ctx);
    // 6. kv = ctx @ W_ad + b_ad   [8192,768]@[768,256]
    sgemm_kernel<128,128,8,8,8><<<dim3(2,64), 256, 0, stream>>>(
        ctx, nullptr, W_ad, b_ad, nullptr, kv, BTz, Hz, Dz);
    // 7-9. q,k,v projections [8192,256]@[256,256]
    sgemm_kernel<128,128,8,8,8><<<dim3(2,64), 256, 0, stream>>>(
        query, nullptr, Wq, bq, nullptr, qb, BTz, Hz, Hz);
    sgemm_kernel<128,128,8,8,8><<<dim3(2,64), 256, 0, stream>>>(
        kv, nullptr, Wk, bk, nullptr, kb, BTz, Hz, Hz);
    sgemm_kernel<128,128,8,8,8><<<dim3(2,64), 256, 0, stream>>>(
        kv, nullptr, Wv, bv, nullptr, vb, BTz, Hz, Hz);
    // 10. attention
    attn_kernel<<<256, 128, 0, stream>>>(qb, kb, vb, pv, probs_un, denom);
    // 11. attn_proj = pv @ Wo + bo  -> reuse qb
    sgemm_kernel<128,128,8,8,8><<<dim3(2,64), 256, 0, stream>>>(
        pv, nullptr, Wo, bo, nullptr, qb, BTz, Hz, Hz);
    // 12. mean over heads -> out3
    meanheads_kernel<<<2048, 256, 0, stream>>>(probs_un, denom, out_attn);
    // 13. imputed = (query + attn_proj) @ W_out + b_out  [8192,256]@[256,64]
    sgemm_kernel<64,64,8,4,4><<<dim3(1,128), 256, 0, stream>>>(
        query, qb, W_out, b_out, nullptr, out_imputed, BTz, Fz, Hz);
}

// Round 3
// 711.281 us; speedup vs baseline: 1.7995x; 1.6303x over previous
//
#include <hip/hip_runtime.h>
#include <hip/hip_bf16.h>

// Shapes
#define Bz 32
#define Tz 256
#define Fz 64
#define Dz 768
#define Sz 768
#define Hz 256
#define NHz 4
#define HDz 64
#define BTz 8192  // B*T
#define NPAIRPAD 1024

typedef __attribute__((ext_vector_type(8))) short short8v;
typedef __attribute__((ext_vector_type(4))) float f32x4;

__device__ inline unsigned short f2bf_rne(float x) {
    unsigned u = __float_as_uint(x);
    unsigned r = (u + 0x7fffu + ((u >> 16) & 1u)) >> 16;
    return (unsigned short)r;
}

// ---------------------------------------------------------------------------
// Kernel 1: masking. valid/stoch/surv/safe + 64-bit survivor mask per (b,t).
// ---------------------------------------------------------------------------
__global__ __launch_bounds__(256) void mask_kernel(
    const float* __restrict__ bd, const float* __restrict__ mp,
    float* __restrict__ safe, float* __restrict__ stoch_out,
    unsigned long long* __restrict__ mask64)
{
    int idx = blockIdx.x * 256 + threadIdx.x;   // over B*T*F = 524288
    float x = bd[idx];
    float p = mp[idx];
    unsigned xb = __float_as_uint(x);
    bool valid = ((xb & 0x7fffffffu) <= 0x7f800000u);   // !isnan
    bool st = (p < 0.3f) && valid;
    bool sv = valid && !st;
    safe[idx] = sv ? x : 0.0f;
    stoch_out[idx] = st ? 1.0f : 0.0f;
    unsigned long long m = __ballot(sv);        // wave=64 == F
    if ((threadIdx.x & 63) == 0) mask64[idx >> 6] = m;
}

// ---------------------------------------------------------------------------
// Kernel 2: pooled sapbert query bias. pooled[h] = colmean(E) @ Wsap + b.
// ---------------------------------------------------------------------------
__global__ __launch_bounds__(256) void pooled_kernel(
    const float* __restrict__ E, const float* __restrict__ W_sap,
    const float* __restrict__ b_sap, float* __restrict__ pooled)
{
    __shared__ float colmean[Sz];
    for (int s = threadIdx.x; s < Sz; s += 256) {
        float acc = 0.0f;
        for (int f = 0; f < Fz; ++f) acc += E[f * Sz + s];
        colmean[s] = acc * (1.0f / 64.0f);
    }
    __syncthreads();
    int h = threadIdx.x;
    float acc = b_sap[h];
    for (int s = 0; s < Sz; ++s) acc += colmean[s] * W_sap[s * Hz + h];
    pooled[h] = acc;
}

// ---------------------------------------------------------------------------
// Kernel 3: present (i<j) pair list + per-row present bitmasks.
// ---------------------------------------------------------------------------
__global__ __launch_bounds__(64) void pairlist_kernel(
    const int* __restrict__ present, unsigned int* __restrict__ plist,
    unsigned long long* __restrict__ rowmask)
{
    __shared__ int cnt[64];
    __shared__ int off[64];
    int i = threadIdx.x;
    int c = 0;
    unsigned long long rm = 0ull;
    for (int j = i + 1; j < 64; ++j)
        if (present[i * 64 + j] != 0) { c++; rm |= 1ull << j; }
    cnt[i] = c;
    rowmask[i] = rm;
    __syncthreads();
    if (i == 0) {
        int t = 0;
        for (int r = 0; r < 64; ++r) { off[r] = t; t += cnt[r]; }
        plist[0] = (unsigned)t;
    }
    __syncthreads();
    int o = 1 + off[i];
    for (int j = i + 1; j < 64; ++j)
        if (present[i * 64 + j] != 0) plist[o++] = (unsigned)(i * 64 + j);
}

// ---------------------------------------------------------------------------
// Kernel 4a: build bf16 0/1 selection matrix Wm[BT][1024] + inv_cnt[BT].
// One block per bt. Thread t packs pairs 4t..4t+3 into one 8B store.
// ---------------------------------------------------------------------------
__global__ __launch_bounds__(256) void wbuild_kernel(
    const unsigned long long* __restrict__ mask64,
    const unsigned int* __restrict__ plist,
    const unsigned long long* __restrict__ rowmask,
    unsigned short* __restrict__ Wm, float* __restrict__ inv_cnt)
{
    int bt = blockIdx.x;
    int t = threadIdx.x;
    unsigned long long m = mask64[bt];
    int np = (int)plist[0];

    unsigned long long pack = 0ull;
    #pragma unroll
    for (int j = 0; j < 4; ++j) {
        int p = 4 * t + j;
        unsigned long long on = 0ull;
        if (p < np) {
            unsigned ij = plist[1 + p];
            on = (m >> (ij >> 6)) & (m >> (ij & 63)) & 1ull;
        }
        pack |= (on ? 0x3f80ull : 0ull) << (16 * j);
    }
    *(unsigned long long*)(Wm + (size_t)bt * NPAIRPAD + 4 * t) = pack;

    if (t < 64) {
        int c = ((m >> t) & 1ull) ? __popcll(m & rowmask[t]) : 0;
        #pragma unroll
        for (int off = 32; off; off >>= 1) c += __shfl_down(c, off);
        if (t == 0) inv_cnt[bt] = c > 0 ? 1.0f / (float)c : 0.0f;
    }
}

// ---------------------------------------------------------------------------
// Kernel 4b: gather pair_emb rows -> transposed bf16 PeT[768][1024].
// One block per pair slot p; coalesced reads, scattered 2B writes (small).
// ---------------------------------------------------------------------------
__global__ __launch_bounds__(256) void pebuild_kernel(
    const float* __restrict__ pair_emb, const unsigned int* __restrict__ plist,
    unsigned short* __restrict__ PeT)
{
    int p = blockIdx.x;
    int t = threadIdx.x;
    int np = (int)plist[0];
    if (p < np) {
        unsigned ij = plist[1 + p];
        const float* src = pair_emb + (size_t)ij * Dz;
        #pragma unroll
        for (int c = 0; c < 3; ++c)
            PeT[(size_t)(t + c * 256) * NPAIRPAD + p] = f2bf_rne(src[t + c * 256]);
    } else {
        #pragma unroll
        for (int c = 0; c < 3; ++c)
            PeT[(size_t)(t + c * 256) * NPAIRPAD + p] = 0;
    }
}

// ---------------------------------------------------------------------------
// Kernel 5: MFMA bf16 GEMM with per-row f32 scale.
// C[M][N] = rs[row] * (A[M][K]bf16 @ Bt[N][K]bf16^T), 128x128 tile, 4 waves.
// LDS row stride 40 ushorts (80B): 16B-aligned, 2-way bank alias (free).
// ---------------------------------------------------------------------------
__global__ __launch_bounds__(256) void mfma_gemm_rowscale(
    const unsigned short* __restrict__ A, const unsigned short* __restrict__ Bt,
    const float* __restrict__ rs, float* __restrict__ C,
    int M, int N, int K)
{
    __shared__ unsigned short As[128 * 40];
    __shared__ unsigned short Bs[128 * 40];
    const int tid = threadIdx.x;
    const int lane = tid & 63;
    const int wave = tid >> 6;
    const int wr = wave >> 1, wc = wave & 1;
    const int row0 = blockIdx.y * 128, col0 = blockIdx.x * 128;

    f32x4 acc[4][4] = {};

    for (int k0 = 0; k0 < K; k0 += 32) {
        __syncthreads();
        #pragma unroll
        for (int i = 0; i < 2; ++i) {
            int c = tid + i * 256;
            int r = c >> 2, cc = c & 3;
            float4 av = *(const float4*)(A + (size_t)(row0 + r) * K + k0 + cc * 8);
            *(float4*)(As + r * 40 + cc * 8) = av;
            float4 bv = *(const float4*)(Bt + (size_t)(col0 + r) * K + k0 + cc * 8);
            *(float4*)(Bs + r * 40 + cc * 8) = bv;
        }
        __syncthreads();

        short8v a[4], b[4];
        #pragma unroll
        for (int m = 0; m < 4; ++m)
            a[m] = *(const short8v*)(As + (wr * 64 + m * 16 + (lane & 15)) * 40 + (lane >> 4) * 8);
        #pragma unroll
        for (int n = 0; n < 4; ++n)
            b[n] = *(const short8v*)(Bs + (wc * 64 + n * 16 + (lane & 15)) * 40 + (lane >> 4) * 8);
        #pragma unroll
        for (int m = 0; m < 4; ++m)
            #pragma unroll
            for (int n = 0; n < 4; ++n)
                acc[m][n] = __builtin_amdgcn_mfma_f32_16x16x32_bf16(a[m], b[n], acc[m][n], 0, 0, 0);
    }

    #pragma unroll
    for (int m = 0; m < 4; ++m) {
        #pragma unroll
        for (int r = 0; r < 4; ++r) {
            int row = row0 + wr * 64 + m * 16 + (lane >> 4) * 4 + r;
            float s = rs[row];
            #pragma unroll
            for (int n = 0; n < 4; ++n) {
                int col = col0 + wc * 64 + n * 16 + (lane & 15);
                C[(size_t)row * N + col] = acc[m][n][r] * s;
            }
        }
    }
}

// ---------------------------------------------------------------------------
// Generic tiled f32 GEMM: C[M,N] = (A (+A2)) @ B + bias (+bias2)
// ---------------------------------------------------------------------------
template <int BM, int BN, int BK, int TM, int TN>
__global__ __launch_bounds__(256) void sgemm_kernel(
    const float* __restrict__ A, const float* __restrict__ A2,
    const float* __restrict__ Bm, const float* __restrict__ bias,
    const float* __restrict__ bias2, float* __restrict__ C,
    int M, int N, int K)
{
    __shared__ float As[BK][BM];
    __shared__ float Bs[BK][BN];
    const int tid = threadIdx.x;
    const int row0 = blockIdx.y * BM, col0 = blockIdx.x * BN;
    constexpr int NTX = BN / TN;
    const int tx = tid % NTX, ty = tid / NTX;
    float acc[TM][TN] = {};
    constexpr int AF4 = BM * BK / 4;
    constexpr int BF4 = BK * BN / 4;

    for (int k0 = 0; k0 < K; k0 += BK) {
        for (int idx = tid; idx < AF4; idx += 256) {
            int ar = idx / (BK / 4);
            int ac = (idx % (BK / 4)) * 4;
            float4 av = *(const float4*)&A[(size_t)(row0 + ar) * K + k0 + ac];
            if (A2) {
                float4 a2 = *(const float4*)&A2[(size_t)(row0 + ar) * K + k0 + ac];
                av.x += a2.x; av.y += a2.y; av.z += a2.z; av.w += a2.w;
            }
            As[ac + 0][ar] = av.x; As[ac + 1][ar] = av.y;
            As[ac + 2][ar] = av.z; As[ac + 3][ar] = av.w;
        }
        for (int idx = tid; idx < BF4; idx += 256) {
            int br = idx / (BN / 4);
            int bc = (idx % (BN / 4)) * 4;
            *(float4*)&Bs[br][bc] = *(const float4*)&Bm[(size_t)(k0 + br) * N + col0 + bc];
        }
        __syncthreads();
        #pragma unroll
        for (int kk = 0; kk < BK; ++kk) {
            float a[TM], b[TN];
            #pragma unroll
            for (int i = 0; i < TM; i += 4) *(float4*)&a[i] = *(const float4*)&As[kk][ty * TM + i];
            #pragma unroll
            for (int j = 0; j < TN; j += 4) *(float4*)&b[j] = *(const float4*)&Bs[kk][tx * TN + j];
            #pragma unroll
            for (int i = 0; i < TM; ++i)
                #pragma unroll
                for (int j = 0; j < TN; ++j)
                    acc[i][j] += a[i] * b[j];
        }
        __syncthreads();
    }

    #pragma unroll
    for (int i = 0; i < TM; ++i) {
        int r = row0 + ty * TM + i;
        #pragma unroll
        for (int j = 0; j < TN; j += 4) {
            int c = col0 + tx * TN + j;
            float4 o;
            o.x = acc[i][j]; o.y = acc[i][j + 1]; o.z = acc[i][j + 2]; o.w = acc[i][j + 3];
            if (bias)  { o.x += bias[c];  o.y += bias[c + 1];  o.z += bias[c + 2];  o.w += bias[c + 3]; }
            if (bias2) { o.x += bias2[c]; o.y += bias2[c + 1]; o.z += bias2[c + 2]; o.w += bias2[c + 3]; }
            *(float4*)&C[(size_t)r * N + c] = o;
        }
    }
}

// ---------------------------------------------------------------------------
// Kernel 10: attention. One block per (b,h,half); thread owns one query row.
// ---------------------------------------------------------------------------
__global__ __launch_bounds__(128) void attn_kernel(
    const float* __restrict__ q, const float* __restrict__ k,
    const float* __restrict__ v, float* __restrict__ pv,
    float* __restrict__ probs_un, float* __restrict__ denom)
{
    int bh = blockIdx.x >> 1;
    int half = blockIdx.x & 1;
    int b = bh >> 2, h = bh & 3;
    __shared__ float Kl[Tz][HDz];

    const float* kbase = k + (size_t)(b * Tz) * Hz + h * HDz;
    for (int e = threadIdx.x; e < Tz * HDz / 4; e += 128) {
        int row = e >> 4;
        int c4 = (e & 15) << 2;
        *(float4*)&Kl[row][c4] = *(const float4*)&kbase[(size_t)row * Hz + c4];
    }
    __syncthreads();

    int tq = half * 128 + threadIdx.x;
    float qr[HDz];
    const float* qrow = q + (size_t)(b * Tz + tq) * Hz + h * HDz;
    #pragma unroll
    for (int d = 0; d < HDz; d += 4) *(float4*)&qr[d] = *(const float4*)&qrow[d];
    #pragma unroll
    for (int d = 0; d < HDz; ++d) qr[d] *= 0.125f;

    float mmax = -1e30f;
    for (int tk = 0; tk < Tz; ++tk) {
        float s = 0.0f;
        #pragma unroll
        for (int d = 0; d < HDz; ++d) s += qr[d] * Kl[tk][d];
        mmax = fmaxf(mmax, s);
    }

    const float* vbase = v + (size_t)(b * Tz) * Hz + h * HDz;
    float acc[HDz];
    #pragma unroll
    for (int d = 0; d < HDz; ++d) acc[d] = 0.0f;
    float sum = 0.0f;
    float* prow = probs_un + ((size_t)bh * Tz + tq) * Tz;
    for (int tk = 0; tk < Tz; ++tk) {
        float s = 0.0f;
        #pragma unroll
        for (int d = 0; d < HDz; ++d) s += qr[d] * Kl[tk][d];
        float p = __expf(s - mmax);
        prow[tk] = p;
        sum += p;
        const float* vr = vbase + (size_t)tk * Hz;
        #pragma unroll
        for (int d = 0; d < HDz; ++d) acc[d] += p * vr[d];
    }
    float inv = 1.0f / sum;
    float* dst = pv + (size_t)(b * Tz + tq) * Hz + h * HDz;
    #pragma unroll
    for (int d = 0; d < HDz; d += 4) {
        float4 o; o.x = acc[d] * inv; o.y = acc[d + 1] * inv;
        o.z = acc[d + 2] * inv; o.w = acc[d + 3] * inv;
        *(float4*)&dst[d] = o;
    }
    denom[bh * Tz + tq] = sum;
}

// ---------------------------------------------------------------------------
// Kernel 12: mean over heads of normalized probs -> out3 [B,T,T]
// ---------------------------------------------------------------------------
__global__ __launch_bounds__(256) void meanheads_kernel(
    const float* __restrict__ probs_un, const float* __restrict__ denom,
    float* __restrict__ out3)
{
    int idx = blockIdx.x * 256 + threadIdx.x;
    int tk4 = idx & 63;
    int btq = idx >> 6;
    int b = btq >> 8, tq = btq & 255;
    float4 acc = {0, 0, 0, 0};
    #pragma unroll
    for (int h = 0; h < 4; ++h) {
        int bh = b * 4 + h;
        float inv = 0.25f / denom[bh * Tz + tq];
        float4 p = *(const float4*)&probs_un[(((size_t)bh * Tz + tq) << 8) + tk4 * 4];
        acc.x += p.x * inv; acc.y += p.y * inv; acc.z += p.z * inv; acc.w += p.w * inv;
    }
    *(float4*)&out3[(size_t)idx * 4] = acc;
}

// ---------------------------------------------------------------------------
extern "C" void kernel_launch(void* const* d_in, const int* in_sizes, int n_in,
                              void* d_out, int out_size, void* d_ws, size_t ws_size,
                              hipStream_t stream)
{
    const float* batch_data = (const float*)d_in[0];
    const float* mask_probs = (const float*)d_in[1];
    const float* sapE       = (const float*)d_in[2];
    const float* pair_emb   = (const float*)d_in[3];
    const int*   pair_present = (const int*)d_in[4];
    const float* W_num = (const float*)d_in[5];  const float* b_num = (const float*)d_in[6];
    const float* W_sap = (const float*)d_in[7];  const float* b_sap = (const float*)d_in[8];
    const float* W_ad  = (const float*)d_in[9];  const float* b_ad  = (const float*)d_in[10];
    const float* Wq = (const float*)d_in[11]; const float* bq = (const float*)d_in[12];
    const float* Wk = (const float*)d_in[13]; const float* bk = (const float*)d_in[14];
    const float* Wv = (const float*)d_in[15]; const float* bv = (const float*)d_in[16];
    const float* Wo = (const float*)d_in[17]; const float* bo = (const float*)d_in[18];
    const float* W_out = (const float*)d_in[19]; const float* b_out = (const float*)d_in[20];

    float* out = (float*)d_out;
    float* out_imputed = out;                 // [B,T,F]   524288
    float* out_stoch   = out + 524288;        // [B,T,F]   524288
    float* out_attn    = out + 1048576;       // [B,T,T]   2097152

    float* ws = (float*)d_ws;
    float* safe  = ws;                        // 524288
    float* query = ws + 524288;               // 2097152
    float* ctx   = ws + 2621440;              // (aliased by probs_un later)
    float* kv    = ws + 8912896;              // 2097152   (consumed before attn)
    float* qb    = ws + 11010048;             // 2097152   (reused: Wm 1st half, attn_proj)
    float* kb    = ws + 13107200;             // 2097152   (reused: Wm 2nd half)
    float* vb    = ws + 15204352;             // 2097152   (reused: PeT + inv_cnt)
    float* pv    = ws + 17301504;             // 2097152
    float* pooled = ws + 19398656;            // 256
    unsigned long long* mask64 = (unsigned long long*)(ws + 19398912); // 8192 u64
    unsigned int* plist = (unsigned int*)(ws + 19415296);              // npairs+1 u32
    unsigned long long* rowmask = (unsigned long long*)(plist + 2020); // 64 u64
    float* denom = ws + 19419392;             // 32768
    float* probs_un = ctx;                    // 8388608 (= ctx+kv region)

    // MFMA-pairctx scratch, aliased into regions written only later:
    unsigned short* Wm  = (unsigned short*)qb;          // 8192*1024 bf16 = 16 MB (qb+kb)
    unsigned short* PeT = (unsigned short*)vb;          // 768*1024 bf16
    float* inv_cnt = vb + 393216;                       // 8192 f32 (still in vb region)

    // 1. masking
    mask_kernel<<<2048, 256, 0, stream>>>(batch_data, mask_probs, safe, out_stoch, mask64);
    // 2. pooled sapbert
    pooled_kernel<<<1, 256, 0, stream>>>(sapE, W_sap, b_sap, pooled);
    // 3. present-pair list + row masks
    pairlist_kernel<<<1, 64, 0, stream>>>(pair_present, plist, rowmask);
    // 4. query = safe @ W_num + b_num + pooled   [8192,64]@[64,256]
    sgemm_kernel<128,128,8,8,8><<<dim3(2,64), 256, 0, stream>>>(
        safe, nullptr, W_num, b_num, pooled, query, BTz, Hz, Fz);
    // 5. pair context as MFMA GEMM: Wm[8192,1024] @ PeT^T -> ctx, scaled by inv_cnt
    wbuild_kernel<<<BTz, 256, 0, stream>>>(mask64, plist, rowmask, Wm, inv_cnt);
    pebuild_kernel<<<NPAIRPAD, 256, 0, stream>>>(pair_emb, plist, PeT);
    mfma_gemm_rowscale<<<dim3(Dz / 128, BTz / 128), 256, 0, stream>>>(
        Wm, PeT, inv_cnt, ctx, BTz, Dz, NPAIRPAD);
    // 6. kv = ctx @ W_ad + b_ad   [8192,768]@[768,256]
    sgemm_kernel<128,128,8,8,8><<<dim3(2,64), 256, 0, stream>>>(
        ctx, nullptr, W_ad, b_ad, nullptr, kv, BTz, Hz, Dz);
    // 7-9. q,k,v projections [8192,256]@[256,256]  (overwrite Wm/PeT regions)
    sgemm_kernel<128,128,8,8,8><<<dim3(2,64), 256, 0, stream>>>(
        query, nullptr, Wq, bq, nullptr, qb, BTz, Hz, Hz);
    sgemm_kernel<128,128,8,8,8><<<dim3(2,64), 256, 0, stream>>>(
        kv, nullptr, Wk, bk, nullptr, kb, BTz, Hz, Hz);
    sgemm_kernel<128,128,8,8,8><<<dim3(2,64), 256, 0, stream>>>(
        kv, nullptr, Wv, bv, nullptr, vb, BTz, Hz, Hz);
    // 10. attention
    attn_kernel<<<256, 128, 0, stream>>>(qb, kb, vb, pv, probs_un, denom);
    // 11. attn_proj = pv @ Wo + bo  -> reuse qb
    sgemm_kernel<128,128,8,8,8><<<dim3(2,64), 256, 0, stream>>>(
        pv, nullptr, Wo, bo, nullptr, qb, BTz, Hz, Hz);
    // 12. mean over heads -> out3
    meanheads_kernel<<<2048, 256, 0, stream>>>(probs_un, denom, out_attn);
    // 13. imputed = (query + attn_proj) @ W_out + b_out  [8192,256]@[256,64]
    sgemm_kernel<64,64,8,4,4><<<dim3(1,128), 256, 0, stream>>>(
        query, qb, W_out, b_out, nullptr, out_imputed, BTz, Fz, Hz);
}

// Round 4
// 484.868 us; speedup vs baseline: 2.6398x; 1.4670x over previous
//
#include <hip/hip_runtime.h>
#include <hip/hip_bf16.h>

// Shapes
#define Bz 32
#define Tz 256
#define Fz 64
#define Dz 768
#define Sz 768
#define Hz 256
#define NHz 4
#define HDz 64
#define BTz 8192  // B*T
#define NPAIRPAD 1024
#define QKPAD 72   // bf16 units; 144B row stride: 2-way bank alias (free)
#define VTPAD 264
#define PLPAD 40

typedef __attribute__((ext_vector_type(8))) short short8v;
typedef __attribute__((ext_vector_type(4))) float f32x4;

__device__ inline unsigned short f2bf_rne(float x) {
    unsigned u = __float_as_uint(x);
    unsigned r = (u + 0x7fffu + ((u >> 16) & 1u)) >> 16;
    return (unsigned short)r;
}

// ---------------------------------------------------------------------------
// Kernel 1: masking.
// ---------------------------------------------------------------------------
__global__ __launch_bounds__(256) void mask_kernel(
    const float* __restrict__ bd, const float* __restrict__ mp,
    float* __restrict__ safe, float* __restrict__ stoch_out,
    unsigned long long* __restrict__ mask64)
{
    int idx = blockIdx.x * 256 + threadIdx.x;
    float x = bd[idx];
    float p = mp[idx];
    unsigned xb = __float_as_uint(x);
    bool valid = ((xb & 0x7fffffffu) <= 0x7f800000u);
    bool st = (p < 0.3f) && valid;
    bool sv = valid && !st;
    safe[idx] = sv ? x : 0.0f;
    stoch_out[idx] = st ? 1.0f : 0.0f;
    unsigned long long m = __ballot(sv);
    if ((threadIdx.x & 63) == 0) mask64[idx >> 6] = m;
}

// ---------------------------------------------------------------------------
// Kernel 2: pooled sapbert query bias.
// ---------------------------------------------------------------------------
__global__ __launch_bounds__(256) void pooled_kernel(
    const float* __restrict__ E, const float* __restrict__ W_sap,
    const float* __restrict__ b_sap, float* __restrict__ pooled)
{
    __shared__ float colmean[Sz];
    for (int s = threadIdx.x; s < Sz; s += 256) {
        float acc = 0.0f;
        for (int f = 0; f < Fz; ++f) acc += E[f * Sz + s];
        colmean[s] = acc * (1.0f / 64.0f);
    }
    __syncthreads();
    int h = threadIdx.x;
    float acc = b_sap[h];
    for (int s = 0; s < Sz; ++s) acc += colmean[s] * W_sap[s * Hz + h];
    pooled[h] = acc;
}

// ---------------------------------------------------------------------------
// Kernel 3: present (i<j) pair list + per-row present bitmasks.
// ---------------------------------------------------------------------------
__global__ __launch_bounds__(64) void pairlist_kernel(
    const int* __restrict__ present, unsigned int* __restrict__ plist,
    unsigned long long* __restrict__ rowmask)
{
    __shared__ int cnt[64];
    __shared__ int off[64];
    int i = threadIdx.x;
    int c = 0;
    unsigned long long rm = 0ull;
    for (int j = i + 1; j < 64; ++j)
        if (present[i * 64 + j] != 0) { c++; rm |= 1ull << j; }
    cnt[i] = c;
    rowmask[i] = rm;
    __syncthreads();
    if (i == 0) {
        int t = 0;
        for (int r = 0; r < 64; ++r) { off[r] = t; t += cnt[r]; }
        plist[0] = (unsigned)t;
    }
    __syncthreads();
    int o = 1 + off[i];
    for (int j = i + 1; j < 64; ++j)
        if (present[i * 64 + j] != 0) plist[o++] = (unsigned)(i * 64 + j);
}

// ---------------------------------------------------------------------------
// Kernel 4a: build bf16 0/1 selection matrix Wm[BT][1024] + inv_cnt[BT].
// ---------------------------------------------------------------------------
__global__ __launch_bounds__(256) void wbuild_kernel(
    const unsigned long long* __restrict__ mask64,
    const unsigned int* __restrict__ plist,
    const unsigned long long* __restrict__ rowmask,
    unsigned short* __restrict__ Wm, float* __restrict__ inv_cnt)
{
    int bt = blockIdx.x;
    int t = threadIdx.x;
    unsigned long long m = mask64[bt];
    int np = (int)plist[0];

    unsigned long long pack = 0ull;
    #pragma unroll
    for (int j = 0; j < 4; ++j) {
        int p = 4 * t + j;
        unsigned long long on = 0ull;
        if (p < np) {
            unsigned ij = plist[1 + p];
            on = (m >> (ij >> 6)) & (m >> (ij & 63)) & 1ull;
        }
        pack |= (on ? 0x3f80ull : 0ull) << (16 * j);
    }
    *(unsigned long long*)(Wm + (size_t)bt * NPAIRPAD + 4 * t) = pack;

    if (t < 64) {
        int c = ((m >> t) & 1ull) ? __popcll(m & rowmask[t]) : 0;
        #pragma unroll
        for (int off = 32; off; off >>= 1) c += __shfl_down(c, off);
        if (t == 0) inv_cnt[bt] = c > 0 ? 1.0f / (float)c : 0.0f;
    }
}

// ---------------------------------------------------------------------------
// Kernel 4b: gather pair_emb rows -> transposed bf16 PeT[768][1024].
// ---------------------------------------------------------------------------
__global__ __launch_bounds__(256) void pebuild_kernel(
    const float* __restrict__ pair_emb, const unsigned int* __restrict__ plist,
    unsigned short* __restrict__ PeT)
{
    int p = blockIdx.x;
    int t = threadIdx.x;
    int np = (int)plist[0];
    if (p < np) {
        unsigned ij = plist[1 + p];
        const float* src = pair_emb + (size_t)ij * Dz;
        #pragma unroll
        for (int c = 0; c < 3; ++c)
            PeT[(size_t)(t + c * 256) * NPAIRPAD + p] = f2bf_rne(src[t + c * 256]);
    } else {
        #pragma unroll
        for (int c = 0; c < 3; ++c)
            PeT[(size_t)(t + c * 256) * NPAIRPAD + p] = 0;
    }
}

// ---------------------------------------------------------------------------
// Kernel 5: MFMA bf16 GEMM with per-row f32 scale (pair context).
// ---------------------------------------------------------------------------
__global__ __launch_bounds__(256) void mfma_gemm_rowscale(
    const unsigned short* __restrict__ A, const unsigned short* __restrict__ Bt,
    const float* __restrict__ rs, float* __restrict__ C,
    int M, int N, int K)
{
    __shared__ unsigned short As[128 * 40];
    __shared__ unsigned short Bs[128 * 40];
    const int tid = threadIdx.x;
    const int lane = tid & 63;
    const int wave = tid >> 6;
    const int wr = wave >> 1, wc = wave & 1;
    const int row0 = blockIdx.y * 128, col0 = blockIdx.x * 128;

    f32x4 acc[4][4] = {};

    for (int k0 = 0; k0 < K; k0 += 32) {
        __syncthreads();
        #pragma unroll
        for (int i = 0; i < 2; ++i) {
            int c = tid + i * 256;
            int r = c >> 2, cc = c & 3;
            float4 av = *(const float4*)(A + (size_t)(row0 + r) * K + k0 + cc * 8);
            *(float4*)(As + r * 40 + cc * 8) = av;
            float4 bv = *(const float4*)(Bt + (size_t)(col0 + r) * K + k0 + cc * 8);
            *(float4*)(Bs + r * 40 + cc * 8) = bv;
        }
        __syncthreads();

        short8v a[4], b[4];
        #pragma unroll
        for (int m = 0; m < 4; ++m)
            a[m] = *(const short8v*)(As + (wr * 64 + m * 16 + (lane & 15)) * 40 + (lane >> 4) * 8);
        #pragma unroll
        for (int n = 0; n < 4; ++n)
            b[n] = *(const short8v*)(Bs + (wc * 64 + n * 16 + (lane & 15)) * 40 + (lane >> 4) * 8);
        #pragma unroll
        for (int m = 0; m < 4; ++m)
            #pragma unroll
            for (int n = 0; n < 4; ++n)
                acc[m][n] = __builtin_amdgcn_mfma_f32_16x16x32_bf16(a[m], b[n], acc[m][n], 0, 0, 0);
    }

    #pragma unroll
    for (int m = 0; m < 4; ++m) {
        #pragma unroll
        for (int r = 0; r < 4; ++r) {
            int row = row0 + wr * 64 + m * 16 + (lane >> 4) * 4 + r;
            float s = rs[row];
            #pragma unroll
            for (int n = 0; n < 4; ++n) {
                int col = col0 + wc * 64 + n * 16 + (lane & 15);
                C[(size_t)row * N + col] = acc[m][n][r] * s;
            }
        }
    }
}

// ---------------------------------------------------------------------------
// Generic tiled f32 GEMM: C[M,N] = (A (+A2)) @ B + bias (+bias2)
// ---------------------------------------------------------------------------
template <int BM, int BN, int BK, int TM, int TN>
__global__ __launch_bounds__(256) void sgemm_kernel(
    const float* __restrict__ A, const float* __restrict__ A2,
    const float* __restrict__ Bm, const float* __restrict__ bias,
    const float* __restrict__ bias2, float* __restrict__ C,
    int M, int N, int K)
{
    __shared__ float As[BK][BM];
    __shared__ float Bs[BK][BN];
    const int tid = threadIdx.x;
    const int row0 = blockIdx.y * BM, col0 = blockIdx.x * BN;
    constexpr int NTX = BN / TN;
    const int tx = tid % NTX, ty = tid / NTX;
    float acc[TM][TN] = {};
    constexpr int AF4 = BM * BK / 4;
    constexpr int BF4 = BK * BN / 4;

    for (int k0 = 0; k0 < K; k0 += BK) {
        for (int idx = tid; idx < AF4; idx += 256) {
            int ar = idx / (BK / 4);
            int ac = (idx % (BK / 4)) * 4;
            float4 av = *(const float4*)&A[(size_t)(row0 + ar) * K + k0 + ac];
            if (A2) {
                float4 a2 = *(const float4*)&A2[(size_t)(row0 + ar) * K + k0 + ac];
                av.x += a2.x; av.y += a2.y; av.z += a2.z; av.w += a2.w;
            }
            As[ac + 0][ar] = av.x; As[ac + 1][ar] = av.y;
            As[ac + 2][ar] = av.z; As[ac + 3][ar] = av.w;
        }
        for (int idx = tid; idx < BF4; idx += 256) {
            int br = idx / (BN / 4);
            int bc = (idx % (BN / 4)) * 4;
            *(float4*)&Bs[br][bc] = *(const float4*)&Bm[(size_t)(k0 + br) * N + col0 + bc];
        }
        __syncthreads();
        #pragma unroll
        for (int kk = 0; kk < BK; ++kk) {
            float a[TM], b[TN];
            #pragma unroll
            for (int i = 0; i < TM; i += 4) *(float4*)&a[i] = *(const float4*)&As[kk][ty * TM + i];
            #pragma unroll
            for (int j = 0; j < TN; j += 4) *(float4*)&b[j] = *(const float4*)&Bs[kk][tx * TN + j];
            #pragma unroll
            for (int i = 0; i < TM; ++i)
                #pragma unroll
                for (int j = 0; j < TN; ++j)
                    acc[i][j] += a[i] * b[j];
        }
        __syncthreads();
    }

    #pragma unroll
    for (int i = 0; i < TM; ++i) {
        int r = row0 + ty * TM + i;
        #pragma unroll
        for (int j = 0; j < TN; j += 4) {
            int c = col0 + tx * TN + j;
            float4 o;
            o.x = acc[i][j]; o.y = acc[i][j + 1]; o.z = acc[i][j + 2]; o.w = acc[i][j + 3];
            if (bias)  { o.x += bias[c];  o.y += bias[c + 1];  o.z += bias[c + 2];  o.w += bias[c + 3]; }
            if (bias2) { o.x += bias2[c]; o.y += bias2[c + 1]; o.z += bias2[c + 2]; o.w += bias2[c + 3]; }
            *(float4*)&C[(size_t)r * N + c] = o;
        }
    }
}

// ---------------------------------------------------------------------------
// Kernel 10a: MFMA QK^T + in-register softmax -> normalized probs f32.
// Grid: (bh, half). 4 waves; wave owns 32 q-rows x 256 keys.
// ---------------------------------------------------------------------------
__global__ __launch_bounds__(256) void qkt_softmax_kernel(
    const float* __restrict__ q, const float* __restrict__ k,
    float* __restrict__ probs)
{
    int blk = blockIdx.x;
    int bh = blk >> 1, half = blk & 1;
    int b = bh >> 2, h = bh & 3;
    __shared__ unsigned short Ql[128 * QKPAD];
    __shared__ unsigned short Kl[256 * QKPAD];
    const int tid = threadIdx.x;

    const float* qbase = q + (size_t)(b * Tz + half * 128) * Hz + h * HDz;
    #pragma unroll
    for (int i = 0; i < 8; ++i) {
        int e = tid + i * 256;          // 128 rows x 16 float4
        int r = e >> 4, c4 = e & 15;
        float4 v = *(const float4*)&qbase[(size_t)r * Hz + c4 * 4];
        unsigned short* d = &Ql[r * QKPAD + c4 * 4];
        d[0] = f2bf_rne(v.x * 0.125f); d[1] = f2bf_rne(v.y * 0.125f);
        d[2] = f2bf_rne(v.z * 0.125f); d[3] = f2bf_rne(v.w * 0.125f);
    }
    const float* kbase = k + (size_t)(b * Tz) * Hz + h * HDz;
    #pragma unroll
    for (int i = 0; i < 16; ++i) {
        int e = tid + i * 256;          // 256 rows x 16 float4
        int r = e >> 4, c4 = e & 15;
        float4 v = *(const float4*)&kbase[(size_t)r * Hz + c4 * 4];
        unsigned short* d = &Kl[r * QKPAD + c4 * 4];
        d[0] = f2bf_rne(v.x); d[1] = f2bf_rne(v.y);
        d[2] = f2bf_rne(v.z); d[3] = f2bf_rne(v.w);
    }
    __syncthreads();

    const int lane = tid & 63, wave = tid >> 6;
    const int l15 = lane & 15, g = lane >> 4;

    f32x4 acc[2][16] = {};
    #pragma unroll
    for (int ks = 0; ks < 2; ++ks) {
        short8v a0 = *(const short8v*)&Ql[(wave * 32 + l15) * QKPAD + ks * 32 + g * 8];
        short8v a1 = *(const short8v*)&Ql[(wave * 32 + 16 + l15) * QKPAD + ks * 32 + g * 8];
        #pragma unroll
        for (int n = 0; n < 16; ++n) {
            short8v bn = *(const short8v*)&Kl[(n * 16 + l15) * QKPAD + ks * 32 + g * 8];
            acc[0][n] = __builtin_amdgcn_mfma_f32_16x16x32_bf16(a0, bn, acc[0][n], 0, 0, 0);
            acc[1][n] = __builtin_amdgcn_mfma_f32_16x16x32_bf16(a1, bn, acc[1][n], 0, 0, 0);
        }
    }

    // softmax: q-row (m, g*4+rr) spread over 16 lanes (same g) x 16 n-tiles
    #pragma unroll
    for (int m = 0; m < 2; ++m) {
        #pragma unroll
        for (int rr = 0; rr < 4; ++rr) {
            float mx = -1e30f;
            #pragma unroll
            for (int n = 0; n < 16; ++n) mx = fmaxf(mx, acc[m][n][rr]);
            #pragma unroll
            for (int s = 1; s < 16; s <<= 1) mx = fmaxf(mx, __shfl_xor(mx, s));
            float e[16];
            float sum = 0.0f;
            #pragma unroll
            for (int n = 0; n < 16; ++n) { e[n] = __expf(acc[m][n][rr] - mx); sum += e[n]; }
            #pragma unroll
            for (int s = 1; s < 16; s <<= 1) sum += __shfl_xor(sum, s);
            float inv = 1.0f / sum;
            int row = half * 128 + wave * 32 + m * 16 + g * 4 + rr;
            float* dst = probs + ((size_t)bh * Tz + row) * Tz;
            #pragma unroll
            for (int n = 0; n < 16; ++n) dst[n * 16 + l15] = e[n] * inv;
        }
    }
}

// ---------------------------------------------------------------------------
// Kernel 10b: PV = probs @ V via MFMA. Grid (bh, half); 4 waves x 32 rows.
// V^T staged bf16 once; P chunks cvt'd from f32 probs per k-step.
// ---------------------------------------------------------------------------
__global__ __launch_bounds__(256) void pv_kernel(
    const float* __restrict__ probs, const float* __restrict__ v,
    float* __restrict__ pv)
{
    int blk = blockIdx.x;
    int bh = blk >> 1, half = blk & 1;
    int b = bh >> 2, h = bh & 3;
    __shared__ unsigned short Vt[64 * VTPAD];    // [d][key]
    __shared__ unsigned short Pl[128 * PLPAD];   // [row][32-key chunk]
    const int tid = threadIdx.x;

    const float* vbase = v + (size_t)(b * Tz) * Hz + h * HDz;
    #pragma unroll
    for (int i = 0; i < 16; ++i) {
        int e = tid + i * 256;          // 256 keys x 16 float4
        int key = e >> 4, c4 = e & 15;
        float4 vv = *(const float4*)&vbase[(size_t)key * Hz + c4 * 4];
        Vt[(c4 * 4 + 0) * VTPAD + key] = f2bf_rne(vv.x);
        Vt[(c4 * 4 + 1) * VTPAD + key] = f2bf_rne(vv.y);
        Vt[(c4 * 4 + 2) * VTPAD + key] = f2bf_rne(vv.z);
        Vt[(c4 * 4 + 3) * VTPAD + key] = f2bf_rne(vv.w);
    }

    const int lane = tid & 63, wave = tid >> 6;
    const int l15 = lane & 15, g = lane >> 4;
    f32x4 acc[2][4] = {};
    const float* pbase = probs + ((size_t)bh * Tz + half * 128) * Tz;

    for (int k0 = 0; k0 < 256; k0 += 32) {
        __syncthreads();                 // first pass also covers Vt
        #pragma unroll
        for (int i = 0; i < 4; ++i) {
            int e = tid + i * 256;       // 128 rows x 8 float4
            int r = e >> 3, c4 = e & 7;
            float4 pvv = *(const float4*)&pbase[(size_t)r * Tz + k0 + c4 * 4];
            unsigned short* d = &Pl[r * PLPAD + c4 * 4];
            d[0] = f2bf_rne(pvv.x); d[1] = f2bf_rne(pvv.y);
            d[2] = f2bf_rne(pvv.z); d[3] = f2bf_rne(pvv.w);
        }
        __syncthreads();
        short8v a0 = *(const short8v*)&Pl[(wave * 32 + l15) * PLPAD + g * 8];
        short8v a1 = *(const short8v*)&Pl[(wave * 32 + 16 + l15) * PLPAD + g * 8];
        #pragma unroll
        for (int n = 0; n < 4; ++n) {
            short8v bn = *(const short8v*)&Vt[(n * 16 + l15) * VTPAD + k0 + g * 8];
            acc[0][n] = __builtin_amdgcn_mfma_f32_16x16x32_bf16(a0, bn, acc[0][n], 0, 0, 0);
            acc[1][n] = __builtin_amdgcn_mfma_f32_16x16x32_bf16(a1, bn, acc[1][n], 0, 0, 0);
        }
    }

    #pragma unroll
    for (int m = 0; m < 2; ++m) {
        #pragma unroll
        for (int rr = 0; rr < 4; ++rr) {
            int row = b * Tz + half * 128 + wave * 32 + m * 16 + g * 4 + rr;
            #pragma unroll
            for (int n = 0; n < 4; ++n)
                pv[(size_t)row * Hz + h * HDz + n * 16 + l15] = acc[m][n][rr];
        }
    }
}

// ---------------------------------------------------------------------------
// Kernel 12: mean over heads of normalized probs -> out3 [B,T,T]
// ---------------------------------------------------------------------------
__global__ __launch_bounds__(256) void meanheads_kernel(
    const float* __restrict__ probs, float* __restrict__ out3)
{
    int idx = blockIdx.x * 256 + threadIdx.x;
    int tk4 = idx & 63;
    int btq = idx >> 6;
    int b = btq >> 8, tq = btq & 255;
    float4 acc = {0, 0, 0, 0};
    #pragma unroll
    for (int h = 0; h < 4; ++h) {
        int bh = b * 4 + h;
        float4 p = *(const float4*)&probs[(((size_t)bh * Tz + tq) << 8) + tk4 * 4];
        acc.x += p.x * 0.25f; acc.y += p.y * 0.25f;
        acc.z += p.z * 0.25f; acc.w += p.w * 0.25f;
    }
    *(float4*)&out3[(size_t)idx * 4] = acc;
}

// ---------------------------------------------------------------------------
extern "C" void kernel_launch(void* const* d_in, const int* in_sizes, int n_in,
                              void* d_out, int out_size, void* d_ws, size_t ws_size,
                              hipStream_t stream)
{
    const float* batch_data = (const float*)d_in[0];
    const float* mask_probs = (const float*)d_in[1];
    const float* sapE       = (const float*)d_in[2];
    const float* pair_emb   = (const float*)d_in[3];
    const int*   pair_present = (const int*)d_in[4];
    const float* W_num = (const float*)d_in[5];  const float* b_num = (const float*)d_in[6];
    const float* W_sap = (const float*)d_in[7];  const float* b_sap = (const float*)d_in[8];
    const float* W_ad  = (const float*)d_in[9];  const float* b_ad  = (const float*)d_in[10];
    const float* Wq = (const float*)d_in[11]; const float* bq = (const float*)d_in[12];
    const float* Wk = (const float*)d_in[13]; const float* bk = (const float*)d_in[14];
    const float* Wv = (const float*)d_in[15]; const float* bv = (const float*)d_in[16];
    const float* Wo = (const float*)d_in[17]; const float* bo = (const float*)d_in[18];
    const float* W_out = (const float*)d_in[19]; const float* b_out = (const float*)d_in[20];

    float* out = (float*)d_out;
    float* out_imputed = out;                 // [B,T,F]   524288
    float* out_stoch   = out + 524288;        // [B,T,F]   524288
    float* out_attn    = out + 1048576;       // [B,T,T]   2097152

    float* ws = (float*)d_ws;
    float* safe  = ws;                        // 524288
    float* query = ws + 524288;               // 2097152
    float* ctx   = ws + 2621440;              // aliased by probs later
    float* kv    = ws + 8912896;              // 2097152 (consumed before attn)
    float* qb    = ws + 11010048;             // 2097152 (Wm 1st half; attn_proj)
    float* kb    = ws + 13107200;             // 2097152 (Wm 2nd half)
    float* vb    = ws + 15204352;             // 2097152 (PeT + inv_cnt)
    float* pv    = ws + 17301504;             // 2097152
    float* pooled = ws + 19398656;            // 256
    unsigned long long* mask64 = (unsigned long long*)(ws + 19398912); // 8192 u64
    unsigned int* plist = (unsigned int*)(ws + 19415296);
    unsigned long long* rowmask = (unsigned long long*)(plist + 2020);
    float* probs = ctx;                       // 8388608 f32 (= ctx+kv region)

    unsigned short* Wm  = (unsigned short*)qb;   // 8192*1024 bf16 (qb+kb regions)
    unsigned short* PeT = (unsigned short*)vb;   // 768*1024 bf16
    float* inv_cnt = vb + 393216;                // 8192 f32

    // 1. masking
    mask_kernel<<<2048, 256, 0, stream>>>(batch_data, mask_probs, safe, out_stoch, mask64);
    // 2. pooled sapbert
    pooled_kernel<<<1, 256, 0, stream>>>(sapE, W_sap, b_sap, pooled);
    // 3. present-pair list + row masks
    pairlist_kernel<<<1, 64, 0, stream>>>(pair_present, plist, rowmask);
    // 4. query = safe @ W_num + b_num + pooled
    sgemm_kernel<128,128,8,8,8><<<dim3(2,64), 256, 0, stream>>>(
        safe, nullptr, W_num, b_num, pooled, query, BTz, Hz, Fz);
    // 5. pair context as MFMA GEMM
    wbuild_kernel<<<BTz, 256, 0, stream>>>(mask64, plist, rowmask, Wm, inv_cnt);
    pebuild_kernel<<<NPAIRPAD, 256, 0, stream>>>(pair_emb, plist, PeT);
    mfma_gemm_rowscale<<<dim3(Dz / 128, BTz / 128), 256, 0, stream>>>(
        Wm, PeT, inv_cnt, ctx, BTz, Dz, NPAIRPAD);
    // 6. kv = ctx @ W_ad + b_ad
    sgemm_kernel<128,128,8,8,8><<<dim3(2,64), 256, 0, stream>>>(
        ctx, nullptr, W_ad, b_ad, nullptr, kv, BTz, Hz, Dz);
    // 7-9. q,k,v projections (overwrite Wm/PeT regions)
    sgemm_kernel<128,128,8,8,8><<<dim3(2,64), 256, 0, stream>>>(
        query, nullptr, Wq, bq, nullptr, qb, BTz, Hz, Hz);
    sgemm_kernel<128,128,8,8,8><<<dim3(2,64), 256, 0, stream>>>(
        kv, nullptr, Wk, bk, nullptr, kb, BTz, Hz, Hz);
    sgemm_kernel<128,128,8,8,8><<<dim3(2,64), 256, 0, stream>>>(
        kv, nullptr, Wv, bv, nullptr, vb, BTz, Hz, Hz);
    // 10. MFMA attention: QK^T+softmax -> probs (normalized); then PV
    qkt_softmax_kernel<<<256, 256, 0, stream>>>(qb, kb, probs);
    pv_kernel<<<256, 256, 0, stream>>>(probs, vb, pv);
    // 11. attn_proj = pv @ Wo + bo -> reuse qb
    sgemm_kernel<128,128,8,8,8><<<dim3(2,64), 256, 0, stream>>>(
        pv, nullptr, Wo, bo, nullptr, qb, BTz, Hz, Hz);
    // 12. mean over heads -> out3
    meanheads_kernel<<<2048, 256, 0, stream>>>(probs, out_attn);
    // 13. imputed = (query + attn_proj) @ W_out + b_out
    sgemm_kernel<64,64,8,4,4><<<dim3(1,128), 256, 0, stream>>>(
        query, qb, W_out, b_out, nullptr, out_imputed, BTz, Fz, Hz);
}

// Round 5
// 273.494 us; speedup vs baseline: 4.6801x; 1.7729x over previous
//
#include <hip/hip_runtime.h>
#include <hip/hip_bf16.h>

// Shapes
#define Bz 32
#define Tz 256
#define Fz 64
#define Dz 768
#define Sz 768
#define Hz 256
#define NHz 4
#define HDz 64
#define BTz 8192  // B*T
#define NPAIRPAD 1024
#define QKPAD 72   // bf16 units; 144B row stride: 2-way bank alias (free)
#define VTPAD 264
#define PLPAD 40

typedef __attribute__((ext_vector_type(8))) short short8v;
typedef __attribute__((ext_vector_type(4))) float f32x4;

__device__ inline unsigned short f2bf_rne(float x) {
    unsigned u = __float_as_uint(x);
    unsigned r = (u + 0x7fffu + ((u >> 16) & 1u)) >> 16;
    return (unsigned short)r;
}

// ---------------------------------------------------------------------------
// Kernel 1: masking.
// ---------------------------------------------------------------------------
__global__ __launch_bounds__(256) void mask_kernel(
    const float* __restrict__ bd, const float* __restrict__ mp,
    float* __restrict__ safe, float* __restrict__ stoch_out,
    unsigned long long* __restrict__ mask64)
{
    int idx = blockIdx.x * 256 + threadIdx.x;
    float x = bd[idx];
    float p = mp[idx];
    unsigned xb = __float_as_uint(x);
    bool valid = ((xb & 0x7fffffffu) <= 0x7f800000u);
    bool st = (p < 0.3f) && valid;
    bool sv = valid && !st;
    safe[idx] = sv ? x : 0.0f;
    stoch_out[idx] = st ? 1.0f : 0.0f;
    unsigned long long m = __ballot(sv);
    if ((threadIdx.x & 63) == 0) mask64[idx >> 6] = m;
}

// ---------------------------------------------------------------------------
// Kernel 2: pooled sapbert query bias.
// ---------------------------------------------------------------------------
__global__ __launch_bounds__(256) void pooled_kernel(
    const float* __restrict__ E, const float* __restrict__ W_sap,
    const float* __restrict__ b_sap, float* __restrict__ pooled)
{
    __shared__ float colmean[Sz];
    for (int s = threadIdx.x; s < Sz; s += 256) {
        float acc = 0.0f;
        for (int f = 0; f < Fz; ++f) acc += E[f * Sz + s];
        colmean[s] = acc * (1.0f / 64.0f);
    }
    __syncthreads();
    int h = threadIdx.x;
    float acc = b_sap[h];
    for (int s = 0; s < Sz; ++s) acc += colmean[s] * W_sap[s * Hz + h];
    pooled[h] = acc;
}

// ---------------------------------------------------------------------------
// Kernel 3: present (i<j) pair list + per-row present bitmasks.
// ---------------------------------------------------------------------------
__global__ __launch_bounds__(64) void pairlist_kernel(
    const int* __restrict__ present, unsigned int* __restrict__ plist,
    unsigned long long* __restrict__ rowmask)
{
    __shared__ int cnt[64];
    __shared__ int off[64];
    int i = threadIdx.x;
    int c = 0;
    unsigned long long rm = 0ull;
    for (int j = i + 1; j < 64; ++j)
        if (present[i * 64 + j] != 0) { c++; rm |= 1ull << j; }
    cnt[i] = c;
    rowmask[i] = rm;
    __syncthreads();
    if (i == 0) {
        int t = 0;
        for (int r = 0; r < 64; ++r) { off[r] = t; t += cnt[r]; }
        plist[0] = (unsigned)t;
    }
    __syncthreads();
    int o = 1 + off[i];
    for (int j = i + 1; j < 64; ++j)
        if (present[i * 64 + j] != 0) plist[o++] = (unsigned)(i * 64 + j);
}

// ---------------------------------------------------------------------------
// Weight transpose+cvt: in f32 [R][C] -> out bf16 [C][R]. 32x32 LDS tiles.
// ---------------------------------------------------------------------------
__device__ inline void transpose_tile(const float* __restrict__ in,
                                      unsigned short* __restrict__ out,
                                      int R, int C)
{
    __shared__ float t[32][33];
    const int tid = threadIdx.x;
    const int c0 = blockIdx.x * 32, r0 = blockIdx.y * 32;
    const int lc = tid & 31, lr8 = tid >> 5;   // 8 rows per pass
    #pragma unroll
    for (int i = 0; i < 4; ++i) {
        int r = lr8 + i * 8;
        t[r][lc] = in[(size_t)(r0 + r) * C + c0 + lc];
    }
    __syncthreads();
    #pragma unroll
    for (int i = 0; i < 4; ++i) {
        int oc = lr8 + i * 8;                   // c-dim index
        out[(size_t)(c0 + oc) * R + r0 + lc] = f2bf_rne(t[lc][oc]);
    }
}

__global__ __launch_bounds__(256) void wtrans_kernel(
    const float* __restrict__ in, unsigned short* __restrict__ out, int R, int C)
{
    transpose_tile(in, out, R, C);
}

__global__ __launch_bounds__(256) void wtrans4_kernel(
    const float* __restrict__ i0, const float* __restrict__ i1,
    const float* __restrict__ i2, const float* __restrict__ i3,
    unsigned short* __restrict__ o0, unsigned short* __restrict__ o1,
    unsigned short* __restrict__ o2, unsigned short* __restrict__ o3)
{
    const float* in; unsigned short* out;
    switch (blockIdx.z) {
        case 0: in = i0; out = o0; break;
        case 1: in = i1; out = o1; break;
        case 2: in = i2; out = o2; break;
        default: in = i3; out = o3; break;
    }
    transpose_tile(in, out, Hz, Hz);
}

// ---------------------------------------------------------------------------
// Kernel 4a: build bf16 0/1 selection matrix Wm[BT][1024] + inv_cnt[BT].
// ---------------------------------------------------------------------------
__global__ __launch_bounds__(256) void wbuild_kernel(
    const unsigned long long* __restrict__ mask64,
    const unsigned int* __restrict__ plist,
    const unsigned long long* __restrict__ rowmask,
    unsigned short* __restrict__ Wm, float* __restrict__ inv_cnt)
{
    int bt = blockIdx.x;
    int t = threadIdx.x;
    unsigned long long m = mask64[bt];
    int np = (int)plist[0];

    unsigned long long pack = 0ull;
    #pragma unroll
    for (int j = 0; j < 4; ++j) {
        int p = 4 * t + j;
        unsigned long long on = 0ull;
        if (p < np) {
            unsigned ij = plist[1 + p];
            on = (m >> (ij >> 6)) & (m >> (ij & 63)) & 1ull;
        }
        pack |= (on ? 0x3f80ull : 0ull) << (16 * j);
    }
    *(unsigned long long*)(Wm + (size_t)bt * NPAIRPAD + 4 * t) = pack;

    if (t < 64) {
        int c = ((m >> t) & 1ull) ? __popcll(m & rowmask[t]) : 0;
        #pragma unroll
        for (int off = 32; off; off >>= 1) c += __shfl_down(c, off);
        if (t == 0) inv_cnt[bt] = c > 0 ? 1.0f / (float)c : 0.0f;
    }
}

// ---------------------------------------------------------------------------
// Kernel 4b: gather pair_emb rows -> transposed bf16 PeT[768][1024].
// ---------------------------------------------------------------------------
__global__ __launch_bounds__(256) void pebuild_kernel(
    const float* __restrict__ pair_emb, const unsigned int* __restrict__ plist,
    unsigned short* __restrict__ PeT)
{
    int p = blockIdx.x;
    int t = threadIdx.x;
    int np = (int)plist[0];
    if (p < np) {
        unsigned ij = plist[1 + p];
        const float* src = pair_emb + (size_t)ij * Dz;
        #pragma unroll
        for (int c = 0; c < 3; ++c)
            PeT[(size_t)(t + c * 256) * NPAIRPAD + p] = f2bf_rne(src[t + c * 256]);
    } else {
        #pragma unroll
        for (int c = 0; c < 3; ++c)
            PeT[(size_t)(t + c * 256) * NPAIRPAD + p] = 0;
    }
}

// ---------------------------------------------------------------------------
// Kernel 5: MFMA bf16 GEMM with per-row f32 scale (pair context).
// ---------------------------------------------------------------------------
__global__ __launch_bounds__(256) void mfma_gemm_rowscale(
    const unsigned short* __restrict__ A, const unsigned short* __restrict__ Bt,
    const float* __restrict__ rs, float* __restrict__ C,
    int M, int N, int K)
{
    __shared__ unsigned short As[128 * 40];
    __shared__ unsigned short Bs[128 * 40];
    const int tid = threadIdx.x;
    const int lane = tid & 63;
    const int wave = tid >> 6;
    const int wr = wave >> 1, wc = wave & 1;
    const int row0 = blockIdx.y * 128, col0 = blockIdx.x * 128;

    f32x4 acc[4][4] = {};

    for (int k0 = 0; k0 < K; k0 += 32) {
        __syncthreads();
        #pragma unroll
        for (int i = 0; i < 2; ++i) {
            int c = tid + i * 256;
            int r = c >> 2, cc = c & 3;
            float4 av = *(const float4*)(A + (size_t)(row0 + r) * K + k0 + cc * 8);
            *(float4*)(As + r * 40 + cc * 8) = av;
            float4 bv = *(const float4*)(Bt + (size_t)(col0 + r) * K + k0 + cc * 8);
            *(float4*)(Bs + r * 40 + cc * 8) = bv;
        }
        __syncthreads();

        short8v a[4], b[4];
        #pragma unroll
        for (int m = 0; m < 4; ++m)
            a[m] = *(const short8v*)(As + (wr * 64 + m * 16 + (lane & 15)) * 40 + (lane >> 4) * 8);
        #pragma unroll
        for (int n = 0; n < 4; ++n)
            b[n] = *(const short8v*)(Bs + (wc * 64 + n * 16 + (lane & 15)) * 40 + (lane >> 4) * 8);
        #pragma unroll
        for (int m = 0; m < 4; ++m)
            #pragma unroll
            for (int n = 0; n < 4; ++n)
                acc[m][n] = __builtin_amdgcn_mfma_f32_16x16x32_bf16(a[m], b[n], acc[m][n], 0, 0, 0);
    }

    #pragma unroll
    for (int m = 0; m < 4; ++m) {
        #pragma unroll
        for (int r = 0; r < 4; ++r) {
            int row = row0 + wr * 64 + m * 16 + (lane >> 4) * 4 + r;
            float s = rs[row];
            #pragma unroll
            for (int n = 0; n < 4; ++n) {
                int col = col0 + wc * 64 + n * 16 + (lane & 15);
                C[(size_t)row * N + col] = acc[m][n][r] * s;
            }
        }
    }
}

// ---------------------------------------------------------------------------
// MFMA GEMM, A f32 (cvt at stage), Bt pre-transposed bf16 [N][K].
// C = (A (+A2)) @ Bt^T + bias (+bias2).  4 waves; wave owns BM/4 rows x BN cols.
// ---------------------------------------------------------------------------
template <int BM, int BN>
__global__ __launch_bounds__(256) void mfma_gemm_f32(
    const float* __restrict__ A, const float* __restrict__ A2,
    const unsigned short* __restrict__ Bt,
    const float* __restrict__ bias, const float* __restrict__ bias2,
    float* __restrict__ C, int M, int N, int K)
{
    constexpr int RW = BM / 4;        // rows per wave
    constexpr int MT = RW / 16;       // 16-row tiles per wave
    constexpr int NT = BN / 16;       // 16-col tiles
    constexpr int AI = BM * 8 / 256;  // A float4 loads per thread per k-step
    constexpr int BI = BN * 4 / 256;  // B 16B loads per thread per k-step
    __shared__ unsigned short As[BM * 40];
    __shared__ unsigned short Bs[BN * 40];
    const int tid = threadIdx.x;
    const int lane = tid & 63, wave = tid >> 6;
    const int l15 = lane & 15, g = lane >> 4;
    const int row0 = blockIdx.y * BM, col0 = blockIdx.x * BN;

    f32x4 acc[MT][NT] = {};

    for (int k0 = 0; k0 < K; k0 += 32) {
        __syncthreads();
        #pragma unroll
        for (int i = 0; i < AI; ++i) {
            int e = tid + i * 256;
            int r = e >> 3, c4 = e & 7;        // 8 float4 per 32-elem row
            float4 v = *(const float4*)&A[(size_t)(row0 + r) * K + k0 + c4 * 4];
            if (A2) {
                float4 v2 = *(const float4*)&A2[(size_t)(row0 + r) * K + k0 + c4 * 4];
                v.x += v2.x; v.y += v2.y; v.z += v2.z; v.w += v2.w;
            }
            short4 s;
            s.x = (short)f2bf_rne(v.x); s.y = (short)f2bf_rne(v.y);
            s.z = (short)f2bf_rne(v.z); s.w = (short)f2bf_rne(v.w);
            *(short4*)(As + r * 40 + c4 * 4) = s;
        }
        #pragma unroll
        for (int i = 0; i < BI; ++i) {
            int e = tid + i * 256;
            int n = e >> 2, c = e & 3;         // 4x16B per 32-elem row
            *(float4*)(Bs + n * 40 + c * 8) =
                *(const float4*)(Bt + (size_t)(col0 + n) * K + k0 + c * 8);
        }
        __syncthreads();

        short8v a[MT], b[NT];
        #pragma unroll
        for (int m = 0; m < MT; ++m)
            a[m] = *(const short8v*)(As + (wave * RW + m * 16 + l15) * 40 + g * 8);
        #pragma unroll
        for (int n = 0; n < NT; ++n)
            b[n] = *(const short8v*)(Bs + (n * 16 + l15) * 40 + g * 8);
        #pragma unroll
        for (int m = 0; m < MT; ++m)
            #pragma unroll
            for (int n = 0; n < NT; ++n)
                acc[m][n] = __builtin_amdgcn_mfma_f32_16x16x32_bf16(a[m], b[n], acc[m][n], 0, 0, 0);
    }

    #pragma unroll
    for (int m = 0; m < MT; ++m) {
        #pragma unroll
        for (int rr = 0; rr < 4; ++rr) {
            int row = row0 + wave * RW + m * 16 + g * 4 + rr;
            #pragma unroll
            for (int n = 0; n < NT; ++n) {
                int col = col0 + n * 16 + l15;
                float o = acc[m][n][rr];
                if (bias)  o += bias[col];
                if (bias2) o += bias2[col];
                C[(size_t)row * N + col] = o;
            }
        }
    }
}

// ---------------------------------------------------------------------------
// Kernel 10a: MFMA QK^T + in-register softmax -> normalized probs f32.
// ---------------------------------------------------------------------------
__global__ __launch_bounds__(256) void qkt_softmax_kernel(
    const float* __restrict__ q, const float* __restrict__ k,
    float* __restrict__ probs)
{
    int blk = blockIdx.x;
    int bh = blk >> 1, half = blk & 1;
    int b = bh >> 2, h = bh & 3;
    __shared__ unsigned short Ql[128 * QKPAD];
    __shared__ unsigned short Kl[256 * QKPAD];
    const int tid = threadIdx.x;

    const float* qbase = q + (size_t)(b * Tz + half * 128) * Hz + h * HDz;
    #pragma unroll
    for (int i = 0; i < 8; ++i) {
        int e = tid + i * 256;
        int r = e >> 4, c4 = e & 15;
        float4 v = *(const float4*)&qbase[(size_t)r * Hz + c4 * 4];
        unsigned short* d = &Ql[r * QKPAD + c4 * 4];
        d[0] = f2bf_rne(v.x * 0.125f); d[1] = f2bf_rne(v.y * 0.125f);
        d[2] = f2bf_rne(v.z * 0.125f); d[3] = f2bf_rne(v.w * 0.125f);
    }
    const float* kbase = k + (size_t)(b * Tz) * Hz + h * HDz;
    #pragma unroll
    for (int i = 0; i < 16; ++i) {
        int e = tid + i * 256;
        int r = e >> 4, c4 = e & 15;
        float4 v = *(const float4*)&kbase[(size_t)r * Hz + c4 * 4];
        unsigned short* d = &Kl[r * QKPAD + c4 * 4];
        d[0] = f2bf_rne(v.x); d[1] = f2bf_rne(v.y);
        d[2] = f2bf_rne(v.z); d[3] = f2bf_rne(v.w);
    }
    __syncthreads();

    const int lane = tid & 63, wave = tid >> 6;
    const int l15 = lane & 15, g = lane >> 4;

    f32x4 acc[2][16] = {};
    #pragma unroll
    for (int ks = 0; ks < 2; ++ks) {
        short8v a0 = *(const short8v*)&Ql[(wave * 32 + l15) * QKPAD + ks * 32 + g * 8];
        short8v a1 = *(const short8v*)&Ql[(wave * 32 + 16 + l15) * QKPAD + ks * 32 + g * 8];
        #pragma unroll
        for (int n = 0; n < 16; ++n) {
            short8v bn = *(const short8v*)&Kl[(n * 16 + l15) * QKPAD + ks * 32 + g * 8];
            acc[0][n] = __builtin_amdgcn_mfma_f32_16x16x32_bf16(a0, bn, acc[0][n], 0, 0, 0);
            acc[1][n] = __builtin_amdgcn_mfma_f32_16x16x32_bf16(a1, bn, acc[1][n], 0, 0, 0);
        }
    }

    #pragma unroll
    for (int m = 0; m < 2; ++m) {
        #pragma unroll
        for (int rr = 0; rr < 4; ++rr) {
            float mx = -1e30f;
            #pragma unroll
            for (int n = 0; n < 16; ++n) mx = fmaxf(mx, acc[m][n][rr]);
            #pragma unroll
            for (int s = 1; s < 16; s <<= 1) mx = fmaxf(mx, __shfl_xor(mx, s));
            float e[16];
            float sum = 0.0f;
            #pragma unroll
            for (int n = 0; n < 16; ++n) { e[n] = __expf(acc[m][n][rr] - mx); sum += e[n]; }
            #pragma unroll
            for (int s = 1; s < 16; s <<= 1) sum += __shfl_xor(sum, s);
            float inv = 1.0f / sum;
            int row = half * 128 + wave * 32 + m * 16 + g * 4 + rr;
            float* dst = probs + ((size_t)bh * Tz + row) * Tz;
            #pragma unroll
            for (int n = 0; n < 16; ++n) dst[n * 16 + l15] = e[n] * inv;
        }
    }
}

// ---------------------------------------------------------------------------
// Kernel 10b: PV = probs @ V via MFMA.
// ---------------------------------------------------------------------------
__global__ __launch_bounds__(256) void pv_kernel(
    const float* __restrict__ probs, const float* __restrict__ v,
    float* __restrict__ pv)
{
    int blk = blockIdx.x;
    int bh = blk >> 1, half = blk & 1;
    int b = bh >> 2, h = bh & 3;
    __shared__ unsigned short Vt[64 * VTPAD];
    __shared__ unsigned short Pl[128 * PLPAD];
    const int tid = threadIdx.x;

    const float* vbase = v + (size_t)(b * Tz) * Hz + h * HDz;
    #pragma unroll
    for (int i = 0; i < 16; ++i) {
        int e = tid + i * 256;
        int key = e >> 4, c4 = e & 15;
        float4 vv = *(const float4*)&vbase[(size_t)key * Hz + c4 * 4];
        Vt[(c4 * 4 + 0) * VTPAD + key] = f2bf_rne(vv.x);
        Vt[(c4 * 4 + 1) * VTPAD + key] = f2bf_rne(vv.y);
        Vt[(c4 * 4 + 2) * VTPAD + key] = f2bf_rne(vv.z);
        Vt[(c4 * 4 + 3) * VTPAD + key] = f2bf_rne(vv.w);
    }

    const int lane = tid & 63, wave = tid >> 6;
    const int l15 = lane & 15, g = lane >> 4;
    f32x4 acc[2][4] = {};
    const float* pbase = probs + ((size_t)bh * Tz + half * 128) * Tz;

    for (int k0 = 0; k0 < 256; k0 += 32) {
        __syncthreads();
        #pragma unroll
        for (int i = 0; i < 4; ++i) {
            int e = tid + i * 256;
            int r = e >> 3, c4 = e & 7;
            float4 pvv = *(const float4*)&pbase[(size_t)r * Tz + k0 + c4 * 4];
            unsigned short* d = &Pl[r * PLPAD + c4 * 4];
            d[0] = f2bf_rne(pvv.x); d[1] = f2bf_rne(pvv.y);
            d[2] = f2bf_rne(pvv.z); d[3] = f2bf_rne(pvv.w);
        }
        __syncthreads();
        short8v a0 = *(const short8v*)&Pl[(wave * 32 + l15) * PLPAD + g * 8];
        short8v a1 = *(const short8v*)&Pl[(wave * 32 + 16 + l15) * PLPAD + g * 8];
        #pragma unroll
        for (int n = 0; n < 4; ++n) {
            short8v bn = *(const short8v*)&Vt[(n * 16 + l15) * VTPAD + k0 + g * 8];
            acc[0][n] = __builtin_amdgcn_mfma_f32_16x16x32_bf16(a0, bn, acc[0][n], 0, 0, 0);
            acc[1][n] = __builtin_amdgcn_mfma_f32_16x16x32_bf16(a1, bn, acc[1][n], 0, 0, 0);
        }
    }

    #pragma unroll
    for (int m = 0; m < 2; ++m) {
        #pragma unroll
        for (int rr = 0; rr < 4; ++rr) {
            int row = b * Tz + half * 128 + wave * 32 + m * 16 + g * 4 + rr;
            #pragma unroll
            for (int n = 0; n < 4; ++n)
                pv[(size_t)row * Hz + h * HDz + n * 16 + l15] = acc[m][n][rr];
        }
    }
}

// ---------------------------------------------------------------------------
// Kernel 12: mean over heads of normalized probs -> out3 [B,T,T]
// ---------------------------------------------------------------------------
__global__ __launch_bounds__(256) void meanheads_kernel(
    const float* __restrict__ probs, float* __restrict__ out3)
{
    int idx = blockIdx.x * 256 + threadIdx.x;
    int tk4 = idx & 63;
    int btq = idx >> 6;
    int b = btq >> 8, tq = btq & 255;
    float4 acc = {0, 0, 0, 0};
    #pragma unroll
    for (int h = 0; h < 4; ++h) {
        int bh = b * 4 + h;
        float4 p = *(const float4*)&probs[(((size_t)bh * Tz + tq) << 8) + tk4 * 4];
        acc.x += p.x * 0.25f; acc.y += p.y * 0.25f;
        acc.z += p.z * 0.25f; acc.w += p.w * 0.25f;
    }
    *(float4*)&out3[(size_t)idx * 4] = acc;
}

// ---------------------------------------------------------------------------
extern "C" void kernel_launch(void* const* d_in, const int* in_sizes, int n_in,
                              void* d_out, int out_size, void* d_ws, size_t ws_size,
                              hipStream_t stream)
{
    const float* batch_data = (const float*)d_in[0];
    const float* mask_probs = (const float*)d_in[1];
    const float* sapE       = (const float*)d_in[2];
    const float* pair_emb   = (const float*)d_in[3];
    const int*   pair_present = (const int*)d_in[4];
    const float* W_num = (const float*)d_in[5];  const float* b_num = (const float*)d_in[6];
    const float* W_sap = (const float*)d_in[7];  const float* b_sap = (const float*)d_in[8];
    const float* W_ad  = (const float*)d_in[9];  const float* b_ad  = (const float*)d_in[10];
    const float* Wq = (const float*)d_in[11]; const float* bq = (const float*)d_in[12];
    const float* Wk = (const float*)d_in[13]; const float* bk = (const float*)d_in[14];
    const float* Wv = (const float*)d_in[15]; const float* bv = (const float*)d_in[16];
    const float* Wo = (const float*)d_in[17]; const float* bo = (const float*)d_in[18];
    const float* W_out = (const float*)d_in[19]; const float* b_out = (const float*)d_in[20];

    float* out = (float*)d_out;
    float* out_imputed = out;                 // [B,T,F]   524288
    float* out_stoch   = out + 524288;        // [B,T,F]   524288
    float* out_attn    = out + 1048576;       // [B,T,T]   2097152

    float* ws = (float*)d_ws;
    float* safe  = ws;                        // 524288
    float* query = ws + 524288;               // 2097152
    float* ctx   = ws + 2621440;              // aliased by probs later
    float* kv    = ws + 8912896;              // 2097152 (consumed before attn)
    float* qb    = ws + 11010048;             // 2097152 (Wm 1st half; attn_proj)
    float* kb    = ws + 13107200;             // 2097152 (Wm 2nd half)
    float* vb    = ws + 15204352;             // 2097152 (PeT + inv_cnt)
    float* pv    = ws + 17301504;             // 2097152
    float* pooled = ws + 19398656;            // 256
    unsigned long long* mask64 = (unsigned long long*)(ws + 19398912); // 8192 u64
    unsigned int* plist = (unsigned int*)(ws + 19415296);
    unsigned long long* rowmask = (unsigned long long*)(plist + 2020);
    float* probs = ctx;                       // 8388608 f32 (= ctx+kv region)

    unsigned short* Wm  = (unsigned short*)qb;   // 8192*1024 bf16 (qb+kb regions)
    unsigned short* PeT = (unsigned short*)vb;   // 768*1024 bf16
    float* inv_cnt = vb + 393216;                // 8192 f32

    // transposed bf16 weights (replaces dead denom region)
    unsigned short* wT = (unsigned short*)(ws + 19419392);
    unsigned short* WnumT = wT;                  // [256][64]
    unsigned short* WadT  = wT + 16384;          // [256][768]
    unsigned short* WqT   = wT + 212992;         // [256][256]
    unsigned short* WkT   = wT + 278528;
    unsigned short* WvT   = wT + 344064;
    unsigned short* WoT   = wT + 409600;
    unsigned short* WoutT = wT + 475136;         // [64][256]

    // 0. weight transposes (bf16)
    wtrans_kernel<<<dim3(Hz/32, Fz/32), 256, 0, stream>>>(W_num, WnumT, Fz, Hz);
    wtrans_kernel<<<dim3(Hz/32, Dz/32), 256, 0, stream>>>(W_ad, WadT, Dz, Hz);
    wtrans4_kernel<<<dim3(Hz/32, Hz/32, 4), 256, 0, stream>>>(
        Wq, Wk, Wv, Wo, WqT, WkT, WvT, WoT);
    wtrans_kernel<<<dim3(Fz/32, Hz/32), 256, 0, stream>>>(W_out, WoutT, Hz, Fz);

    // 1. masking
    mask_kernel<<<2048, 256, 0, stream>>>(batch_data, mask_probs, safe, out_stoch, mask64);
    // 2. pooled sapbert
    pooled_kernel<<<1, 256, 0, stream>>>(sapE, W_sap, b_sap, pooled);
    // 3. present-pair list + row masks
    pairlist_kernel<<<1, 64, 0, stream>>>(pair_present, plist, rowmask);
    // 4. query = safe @ W_num + b_num + pooled   [8192,64]@[64,256]
    mfma_gemm_f32<128,64><<<dim3(4,64), 256, 0, stream>>>(
        safe, nullptr, WnumT, b_num, pooled, query, BTz, Hz, Fz);
    // 5. pair context as MFMA GEMM
    wbuild_kernel<<<BTz, 256, 0, stream>>>(mask64, plist, rowmask, Wm, inv_cnt);
    pebuild_kernel<<<NPAIRPAD, 256, 0, stream>>>(pair_emb, plist, PeT);
    mfma_gemm_rowscale<<<dim3(Dz / 128, BTz / 128), 256, 0, stream>>>(
        Wm, PeT, inv_cnt, ctx, BTz, Dz, NPAIRPAD);
    // 6. kv = ctx @ W_ad + b_ad   [8192,768]@[768,256]
    mfma_gemm_f32<128,64><<<dim3(4,64), 256, 0, stream>>>(
        ctx, nullptr, WadT, b_ad, nullptr, kv, BTz, Hz, Dz);
    // 7-9. q,k,v projections (overwrite Wm/PeT regions)
    mfma_gemm_f32<128,64><<<dim3(4,64), 256, 0, stream>>>(
        query, nullptr, WqT, bq, nullptr, qb, BTz, Hz, Hz);
    mfma_gemm_f32<128,64><<<dim3(4,64), 256, 0, stream>>>(
        kv, nullptr, WkT, bk, nullptr, kb, BTz, Hz, Hz);
    mfma_gemm_f32<128,64><<<dim3(4,64), 256, 0, stream>>>(
        kv, nullptr, WvT, bv, nullptr, vb, BTz, Hz, Hz);
    // 10. MFMA attention
    qkt_softmax_kernel<<<256, 256, 0, stream>>>(qb, kb, probs);
    pv_kernel<<<256, 256, 0, stream>>>(probs, vb, pv);
    // 11. attn_proj = pv @ Wo + bo -> reuse qb
    mfma_gemm_f32<128,64><<<dim3(4,64), 256, 0, stream>>>(
        pv, nullptr, WoT, bo, nullptr, qb, BTz, Hz, Hz);
    // 12. mean over heads -> out3
    meanheads_kernel<<<2048, 256, 0, stream>>>(probs, out_attn);
    // 13. imputed = (query + attn_proj) @ W_out + b_out
    mfma_gemm_f32<64,64><<<dim3(1,128), 256, 0, stream>>>(
        query, qb, WoutT, b_out, nullptr, out_imputed, BTz, Fz, Hz);
}

// Round 6
// 270.246 us; speedup vs baseline: 4.7363x; 1.0120x over previous
//
#include <hip/hip_runtime.h>
#include <hip/hip_bf16.h>

// Shapes
#define Bz 32
#define Tz 256
#define Fz 64
#define Dz 768
#define Sz 768
#define Hz 256
#define NHz 4
#define HDz 64
#define BTz 8192  // B*T
#define NPAIRPAD 1024
#define QKPAD 72   // bf16 units; 144B row stride: 2-way bank alias (free)
#define VTPAD 264
#define PLPAD 40

typedef __attribute__((ext_vector_type(8))) short short8v;
typedef __attribute__((ext_vector_type(4))) float f32x4;

__device__ inline unsigned short f2bf_rne(float x) {
    unsigned u = __float_as_uint(x);
    unsigned r = (u + 0x7fffu + ((u >> 16) & 1u)) >> 16;
    return (unsigned short)r;
}

// ---------------------------------------------------------------------------
// Kernel 1: masking.
// ---------------------------------------------------------------------------
__global__ __launch_bounds__(256) void mask_kernel(
    const float* __restrict__ bd, const float* __restrict__ mp,
    float* __restrict__ safe, float* __restrict__ stoch_out,
    unsigned long long* __restrict__ mask64)
{
    int idx = blockIdx.x * 256 + threadIdx.x;
    float x = bd[idx];
    float p = mp[idx];
    unsigned xb = __float_as_uint(x);
    bool valid = ((xb & 0x7fffffffu) <= 0x7f800000u);
    bool st = (p < 0.3f) && valid;
    bool sv = valid && !st;
    safe[idx] = sv ? x : 0.0f;
    stoch_out[idx] = st ? 1.0f : 0.0f;
    unsigned long long m = __ballot(sv);
    if ((threadIdx.x & 63) == 0) mask64[idx >> 6] = m;
}

// ---------------------------------------------------------------------------
// Kernel 2a: colmean[s] = mean over f of E[f][s]. 3 blocks x 256 threads.
// ---------------------------------------------------------------------------
__global__ __launch_bounds__(256) void colmean_kernel(
    const float* __restrict__ E, float* __restrict__ colmean)
{
    int s = blockIdx.x * 256 + threadIdx.x;   // 768 columns
    float acc = 0.0f;
    #pragma unroll 8
    for (int f = 0; f < Fz; ++f) acc += E[(size_t)f * Sz + s];
    colmean[s] = acc * (1.0f / 64.0f);
}

// ---------------------------------------------------------------------------
// Kernel 2b: pooled[h] = b_sap[h] + sum_s colmean[s] * W_sap[s][h].
// 4 blocks x 256 threads; block owns 64 h; 4 s-groups per thread reduce in LDS.
// ---------------------------------------------------------------------------
__global__ __launch_bounds__(256) void pooled_gemv_kernel(
    const float* __restrict__ colmean, const float* __restrict__ W_sap,
    const float* __restrict__ b_sap, float* __restrict__ pooled)
{
    __shared__ float red[4][64];
    const int tid = threadIdx.x;
    const int hl = tid & 63, sg = tid >> 6;
    const int h = blockIdx.x * 64 + hl;
    float acc = 0.0f;
    #pragma unroll 4
    for (int s = sg; s < Sz; s += 4)
        acc = fmaf(colmean[s], W_sap[(size_t)s * Hz + h], acc);
    red[sg][hl] = acc;
    __syncthreads();
    if (sg == 0)
        pooled[h] = b_sap[h] + ((red[0][hl] + red[1][hl]) + (red[2][hl] + red[3][hl]));
}

// ---------------------------------------------------------------------------
// Kernel 3: present (i<j) pair list + per-row present bitmasks.
// ---------------------------------------------------------------------------
__global__ __launch_bounds__(64) void pairlist_kernel(
    const int* __restrict__ present, unsigned int* __restrict__ plist,
    unsigned long long* __restrict__ rowmask)
{
    __shared__ int cnt[64];
    __shared__ int off[64];
    int i = threadIdx.x;
    int c = 0;
    unsigned long long rm = 0ull;
    for (int j = i + 1; j < 64; ++j)
        if (present[i * 64 + j] != 0) { c++; rm |= 1ull << j; }
    cnt[i] = c;
    rowmask[i] = rm;
    __syncthreads();
    if (i == 0) {
        int t = 0;
        for (int r = 0; r < 64; ++r) { off[r] = t; t += cnt[r]; }
        plist[0] = (unsigned)t;
    }
    __syncthreads();
    int o = 1 + off[i];
    for (int j = i + 1; j < 64; ++j)
        if (present[i * 64 + j] != 0) plist[o++] = (unsigned)(i * 64 + j);
}

// ---------------------------------------------------------------------------
// Weight transpose+cvt: in f32 [R][C] -> out bf16 [C][R]. 32x32 LDS tiles.
// ---------------------------------------------------------------------------
__device__ inline void transpose_tile(const float* __restrict__ in,
                                      unsigned short* __restrict__ out,
                                      int R, int C)
{
    __shared__ float t[32][33];
    const int tid = threadIdx.x;
    const int c0 = blockIdx.x * 32, r0 = blockIdx.y * 32;
    const int lc = tid & 31, lr8 = tid >> 5;   // 8 rows per pass
    #pragma unroll
    for (int i = 0; i < 4; ++i) {
        int r = lr8 + i * 8;
        t[r][lc] = in[(size_t)(r0 + r) * C + c0 + lc];
    }
    __syncthreads();
    #pragma unroll
    for (int i = 0; i < 4; ++i) {
        int oc = lr8 + i * 8;                   // c-dim index
        out[(size_t)(c0 + oc) * R + r0 + lc] = f2bf_rne(t[lc][oc]);
    }
}

__global__ __launch_bounds__(256) void wtrans_kernel(
    const float* __restrict__ in, unsigned short* __restrict__ out, int R, int C)
{
    transpose_tile(in, out, R, C);
}

__global__ __launch_bounds__(256) void wtrans4_kernel(
    const float* __restrict__ i0, const float* __restrict__ i1,
    const float* __restrict__ i2, const float* __restrict__ i3,
    unsigned short* __restrict__ o0, unsigned short* __restrict__ o1,
    unsigned short* __restrict__ o2, unsigned short* __restrict__ o3)
{
    const float* in; unsigned short* out;
    switch (blockIdx.z) {
        case 0: in = i0; out = o0; break;
        case 1: in = i1; out = o1; break;
        case 2: in = i2; out = o2; break;
        default: in = i3; out = o3; break;
    }
    transpose_tile(in, out, Hz, Hz);
}

// ---------------------------------------------------------------------------
// Kernel 4a: build bf16 0/1 selection matrix Wm[BT][1024] + inv_cnt[BT].
// ---------------------------------------------------------------------------
__global__ __launch_bounds__(256) void wbuild_kernel(
    const unsigned long long* __restrict__ mask64,
    const unsigned int* __restrict__ plist,
    const unsigned long long* __restrict__ rowmask,
    unsigned short* __restrict__ Wm, float* __restrict__ inv_cnt)
{
    int bt = blockIdx.x;
    int t = threadIdx.x;
    unsigned long long m = mask64[bt];
    int np = (int)plist[0];

    unsigned long long pack = 0ull;
    #pragma unroll
    for (int j = 0; j < 4; ++j) {
        int p = 4 * t + j;
        unsigned long long on = 0ull;
        if (p < np) {
            unsigned ij = plist[1 + p];
            on = (m >> (ij >> 6)) & (m >> (ij & 63)) & 1ull;
        }
        pack |= (on ? 0x3f80ull : 0ull) << (16 * j);
    }
    *(unsigned long long*)(Wm + (size_t)bt * NPAIRPAD + 4 * t) = pack;

    if (t < 64) {
        int c = ((m >> t) & 1ull) ? __popcll(m & rowmask[t]) : 0;
        #pragma unroll
        for (int off = 32; off; off >>= 1) c += __shfl_down(c, off);
        if (t == 0) inv_cnt[bt] = c > 0 ? 1.0f / (float)c : 0.0f;
    }
}

// ---------------------------------------------------------------------------
// Kernel 4b: gather pair_emb rows -> transposed bf16 PeT[768][1024].
// ---------------------------------------------------------------------------
__global__ __launch_bounds__(256) void pebuild_kernel(
    const float* __restrict__ pair_emb, const unsigned int* __restrict__ plist,
    unsigned short* __restrict__ PeT)
{
    int p = blockIdx.x;
    int t = threadIdx.x;
    int np = (int)plist[0];
    if (p < np) {
        unsigned ij = plist[1 + p];
        const float* src = pair_emb + (size_t)ij * Dz;
        #pragma unroll
        for (int c = 0; c < 3; ++c)
            PeT[(size_t)(t + c * 256) * NPAIRPAD + p] = f2bf_rne(src[t + c * 256]);
    } else {
        #pragma unroll
        for (int c = 0; c < 3; ++c)
            PeT[(size_t)(t + c * 256) * NPAIRPAD + p] = 0;
    }
}

// ---------------------------------------------------------------------------
// Kernel 5: MFMA bf16 GEMM with per-row f32 scale (pair context).
// ---------------------------------------------------------------------------
__global__ __launch_bounds__(256) void mfma_gemm_rowscale(
    const unsigned short* __restrict__ A, const unsigned short* __restrict__ Bt,
    const float* __restrict__ rs, float* __restrict__ C,
    int M, int N, int K)
{
    __shared__ unsigned short As[128 * 40];
    __shared__ unsigned short Bs[128 * 40];
    const int tid = threadIdx.x;
    const int lane = tid & 63;
    const int wave = tid >> 6;
    const int wr = wave >> 1, wc = wave & 1;
    const int row0 = blockIdx.y * 128, col0 = blockIdx.x * 128;

    f32x4 acc[4][4] = {};

    for (int k0 = 0; k0 < K; k0 += 32) {
        __syncthreads();
        #pragma unroll
        for (int i = 0; i < 2; ++i) {
            int c = tid + i * 256;
            int r = c >> 2, cc = c & 3;
            float4 av = *(const float4*)(A + (size_t)(row0 + r) * K + k0 + cc * 8);
            *(float4*)(As + r * 40 + cc * 8) = av;
            float4 bv = *(const float4*)(Bt + (size_t)(col0 + r) * K + k0 + cc * 8);
            *(float4*)(Bs + r * 40 + cc * 8) = bv;
        }
        __syncthreads();

        short8v a[4], b[4];
        #pragma unroll
        for (int m = 0; m < 4; ++m)
            a[m] = *(const short8v*)(As + (wr * 64 + m * 16 + (lane & 15)) * 40 + (lane >> 4) * 8);
        #pragma unroll
        for (int n = 0; n < 4; ++n)
            b[n] = *(const short8v*)(Bs + (wc * 64 + n * 16 + (lane & 15)) * 40 + (lane >> 4) * 8);
        #pragma unroll
        for (int m = 0; m < 4; ++m)
            #pragma unroll
            for (int n = 0; n < 4; ++n)
                acc[m][n] = __builtin_amdgcn_mfma_f32_16x16x32_bf16(a[m], b[n], acc[m][n], 0, 0, 0);
    }

    #pragma unroll
    for (int m = 0; m < 4; ++m) {
        #pragma unroll
        for (int r = 0; r < 4; ++r) {
            int row = row0 + wr * 64 + m * 16 + (lane >> 4) * 4 + r;
            float s = rs[row];
            #pragma unroll
            for (int n = 0; n < 4; ++n) {
                int col = col0 + wc * 64 + n * 16 + (lane & 15);
                C[(size_t)row * N + col] = acc[m][n][r] * s;
            }
        }
    }
}

// ---------------------------------------------------------------------------
// MFMA GEMM, A f32 (cvt at stage), Bt pre-transposed bf16 [N][K].
// C = (A (+A2)) @ Bt^T + bias (+bias2).  4 waves; wave owns BM/4 rows x BN cols.
// ---------------------------------------------------------------------------
template <int BM, int BN>
__global__ __launch_bounds__(256) void mfma_gemm_f32(
    const float* __restrict__ A, const float* __restrict__ A2,
    const unsigned short* __restrict__ Bt,
    const float* __restrict__ bias, const float* __restrict__ bias2,
    float* __restrict__ C, int M, int N, int K)
{
    constexpr int RW = BM / 4;        // rows per wave
    constexpr int MT = RW / 16;       // 16-row tiles per wave
    constexpr int NT = BN / 16;       // 16-col tiles
    constexpr int AI = BM * 8 / 256;  // A float4 loads per thread per k-step
    constexpr int BI = BN * 4 / 256;  // B 16B loads per thread per k-step
    __shared__ unsigned short As[BM * 40];
    __shared__ unsigned short Bs[BN * 40];
    const int tid = threadIdx.x;
    const int lane = tid & 63, wave = tid >> 6;
    const int l15 = lane & 15, g = lane >> 4;
    const int row0 = blockIdx.y * BM, col0 = blockIdx.x * BN;

    f32x4 acc[MT][NT] = {};

    for (int k0 = 0; k0 < K; k0 += 32) {
        __syncthreads();
        #pragma unroll
        for (int i = 0; i < AI; ++i) {
            int e = tid + i * 256;
            int r = e >> 3, c4 = e & 7;        // 8 float4 per 32-elem row
            float4 v = *(const float4*)&A[(size_t)(row0 + r) * K + k0 + c4 * 4];
            if (A2) {
                float4 v2 = *(const float4*)&A2[(size_t)(row0 + r) * K + k0 + c4 * 4];
                v.x += v2.x; v.y += v2.y; v.z += v2.z; v.w += v2.w;
            }
            short4 s;
            s.x = (short)f2bf_rne(v.x); s.y = (short)f2bf_rne(v.y);
            s.z = (short)f2bf_rne(v.z); s.w = (short)f2bf_rne(v.w);
            *(short4*)(As + r * 40 + c4 * 4) = s;
        }
        #pragma unroll
        for (int i = 0; i < BI; ++i) {
            int e = tid + i * 256;
            int n = e >> 2, c = e & 3;         // 4x16B per 32-elem row
            *(float4*)(Bs + n * 40 + c * 8) =
                *(const float4*)(Bt + (size_t)(col0 + n) * K + k0 + c * 8);
        }
        __syncthreads();

        short8v a[MT], b[NT];
        #pragma unroll
        for (int m = 0; m < MT; ++m)
            a[m] = *(const short8v*)(As + (wave * RW + m * 16 + l15) * 40 + g * 8);
        #pragma unroll
        for (int n = 0; n < NT; ++n)
            b[n] = *(const short8v*)(Bs + (n * 16 + l15) * 40 + g * 8);
        #pragma unroll
        for (int m = 0; m < MT; ++m)
            #pragma unroll
            for (int n = 0; n < NT; ++n)
                acc[m][n] = __builtin_amdgcn_mfma_f32_16x16x32_bf16(a[m], b[n], acc[m][n], 0, 0, 0);
    }

    #pragma unroll
    for (int m = 0; m < MT; ++m) {
        #pragma unroll
        for (int rr = 0; rr < 4; ++rr) {
            int row = row0 + wave * RW + m * 16 + g * 4 + rr;
            #pragma unroll
            for (int n = 0; n < NT; ++n) {
                int col = col0 + n * 16 + l15;
                float o = acc[m][n][rr];
                if (bias)  o += bias[col];
                if (bias2) o += bias2[col];
                C[(size_t)row * N + col] = o;
            }
        }
    }
}

// ---------------------------------------------------------------------------
// Kernel 10a: MFMA QK^T + in-register softmax -> normalized probs f32.
// ---------------------------------------------------------------------------
__global__ __launch_bounds__(256) void qkt_softmax_kernel(
    const float* __restrict__ q, const float* __restrict__ k,
    float* __restrict__ probs)
{
    int blk = blockIdx.x;
    int bh = blk >> 1, half = blk & 1;
    int b = bh >> 2, h = bh & 3;
    __shared__ unsigned short Ql[128 * QKPAD];
    __shared__ unsigned short Kl[256 * QKPAD];
    const int tid = threadIdx.x;

    const float* qbase = q + (size_t)(b * Tz + half * 128) * Hz + h * HDz;
    #pragma unroll
    for (int i = 0; i < 8; ++i) {
        int e = tid + i * 256;
        int r = e >> 4, c4 = e & 15;
        float4 v = *(const float4*)&qbase[(size_t)r * Hz + c4 * 4];
        unsigned short* d = &Ql[r * QKPAD + c4 * 4];
        d[0] = f2bf_rne(v.x * 0.125f); d[1] = f2bf_rne(v.y * 0.125f);
        d[2] = f2bf_rne(v.z * 0.125f); d[3] = f2bf_rne(v.w * 0.125f);
    }
    const float* kbase = k + (size_t)(b * Tz) * Hz + h * HDz;
    #pragma unroll
    for (int i = 0; i < 16; ++i) {
        int e = tid + i * 256;
        int r = e >> 4, c4 = e & 15;
        float4 v = *(const float4*)&kbase[(size_t)r * Hz + c4 * 4];
        unsigned short* d = &Kl[r * QKPAD + c4 * 4];
        d[0] = f2bf_rne(v.x); d[1] = f2bf_rne(v.y);
        d[2] = f2bf_rne(v.z); d[3] = f2bf_rne(v.w);
    }
    __syncthreads();

    const int lane = tid & 63, wave = tid >> 6;
    const int l15 = lane & 15, g = lane >> 4;

    f32x4 acc[2][16] = {};
    #pragma unroll
    for (int ks = 0; ks < 2; ++ks) {
        short8v a0 = *(const short8v*)&Ql[(wave * 32 + l15) * QKPAD + ks * 32 + g * 8];
        short8v a1 = *(const short8v*)&Ql[(wave * 32 + 16 + l15) * QKPAD + ks * 32 + g * 8];
        #pragma unroll
        for (int n = 0; n < 16; ++n) {
            short8v bn = *(const short8v*)&Kl[(n * 16 + l15) * QKPAD + ks * 32 + g * 8];
            acc[0][n] = __builtin_amdgcn_mfma_f32_16x16x32_bf16(a0, bn, acc[0][n], 0, 0, 0);
            acc[1][n] = __builtin_amdgcn_mfma_f32_16x16x32_bf16(a1, bn, acc[1][n], 0, 0, 0);
        }
    }

    #pragma unroll
    for (int m = 0; m < 2; ++m) {
        #pragma unroll
        for (int rr = 0; rr < 4; ++rr) {
            float mx = -1e30f;
            #pragma unroll
            for (int n = 0; n < 16; ++n) mx = fmaxf(mx, acc[m][n][rr]);
            #pragma unroll
            for (int s = 1; s < 16; s <<= 1) mx = fmaxf(mx, __shfl_xor(mx, s));
            float e[16];
            float sum = 0.0f;
            #pragma unroll
            for (int n = 0; n < 16; ++n) { e[n] = __expf(acc[m][n][rr] - mx); sum += e[n]; }
            #pragma unroll
            for (int s = 1; s < 16; s <<= 1) sum += __shfl_xor(sum, s);
            float inv = 1.0f / sum;
            int row = half * 128 + wave * 32 + m * 16 + g * 4 + rr;
            float* dst = probs + ((size_t)bh * Tz + row) * Tz;
            #pragma unroll
            for (int n = 0; n < 16; ++n) dst[n * 16 + l15] = e[n] * inv;
        }
    }
}

// ---------------------------------------------------------------------------
// Kernel 10b: PV = probs @ V via MFMA.
// ---------------------------------------------------------------------------
__global__ __launch_bounds__(256) void pv_kernel(
    const float* __restrict__ probs, const float* __restrict__ v,
    float* __restrict__ pv)
{
    int blk = blockIdx.x;
    int bh = blk >> 1, half = blk & 1;
    int b = bh >> 2, h = bh & 3;
    __shared__ unsigned short Vt[64 * VTPAD];
    __shared__ unsigned short Pl[128 * PLPAD];
    const int tid = threadIdx.x;

    const float* vbase = v + (size_t)(b * Tz) * Hz + h * HDz;
    #pragma unroll
    for (int i = 0; i < 16; ++i) {
        int e = tid + i * 256;
        int key = e >> 4, c4 = e & 15;
        float4 vv = *(const float4*)&vbase[(size_t)key * Hz + c4 * 4];
        Vt[(c4 * 4 + 0) * VTPAD + key] = f2bf_rne(vv.x);
        Vt[(c4 * 4 + 1) * VTPAD + key] = f2bf_rne(vv.y);
        Vt[(c4 * 4 + 2) * VTPAD + key] = f2bf_rne(vv.z);
        Vt[(c4 * 4 + 3) * VTPAD + key] = f2bf_rne(vv.w);
    }

    const int lane = tid & 63, wave = tid >> 6;
    const int l15 = lane & 15, g = lane >> 4;
    f32x4 acc[2][4] = {};
    const float* pbase = probs + ((size_t)bh * Tz + half * 128) * Tz;

    for (int k0 = 0; k0 < 256; k0 += 32) {
        __syncthreads();
        #pragma unroll
        for (int i = 0; i < 4; ++i) {
            int e = tid + i * 256;
            int r = e >> 3, c4 = e & 7;
            float4 pvv = *(const float4*)&pbase[(size_t)r * Tz + k0 + c4 * 4];
            unsigned short* d = &Pl[r * PLPAD + c4 * 4];
            d[0] = f2bf_rne(pvv.x); d[1] = f2bf_rne(pvv.y);
            d[2] = f2bf_rne(pvv.z); d[3] = f2bf_rne(pvv.w);
        }
        __syncthreads();
        short8v a0 = *(const short8v*)&Pl[(wave * 32 + l15) * PLPAD + g * 8];
        short8v a1 = *(const short8v*)&Pl[(wave * 32 + 16 + l15) * PLPAD + g * 8];
        #pragma unroll
        for (int n = 0; n < 4; ++n) {
            short8v bn = *(const short8v*)&Vt[(n * 16 + l15) * VTPAD + k0 + g * 8];
            acc[0][n] = __builtin_amdgcn_mfma_f32_16x16x32_bf16(a0, bn, acc[0][n], 0, 0, 0);
            acc[1][n] = __builtin_amdgcn_mfma_f32_16x16x32_bf16(a1, bn, acc[1][n], 0, 0, 0);
        }
    }

    #pragma unroll
    for (int m = 0; m < 2; ++m) {
        #pragma unroll
        for (int rr = 0; rr < 4; ++rr) {
            int row = b * Tz + half * 128 + wave * 32 + m * 16 + g * 4 + rr;
            #pragma unroll
            for (int n = 0; n < 4; ++n)
                pv[(size_t)row * Hz + h * HDz + n * 16 + l15] = acc[m][n][rr];
        }
    }
}

// ---------------------------------------------------------------------------
// Kernel 12: mean over heads of normalized probs -> out3 [B,T,T]
// ---------------------------------------------------------------------------
__global__ __launch_bounds__(256) void meanheads_kernel(
    const float* __restrict__ probs, float* __restrict__ out3)
{
    int idx = blockIdx.x * 256 + threadIdx.x;
    int tk4 = idx & 63;
    int btq = idx >> 6;
    int b = btq >> 8, tq = btq & 255;
    float4 acc = {0, 0, 0, 0};
    #pragma unroll
    for (int h = 0; h < 4; ++h) {
        int bh = b * 4 + h;
        float4 p = *(const float4*)&probs[(((size_t)bh * Tz + tq) << 8) + tk4 * 4];
        acc.x += p.x * 0.25f; acc.y += p.y * 0.25f;
        acc.z += p.z * 0.25f; acc.w += p.w * 0.25f;
    }
    *(float4*)&out3[(size_t)idx * 4] = acc;
}

// ---------------------------------------------------------------------------
extern "C" void kernel_launch(void* const* d_in, const int* in_sizes, int n_in,
                              void* d_out, int out_size, void* d_ws, size_t ws_size,
                              hipStream_t stream)
{
    const float* batch_data = (const float*)d_in[0];
    const float* mask_probs = (const float*)d_in[1];
    const float* sapE       = (const float*)d_in[2];
    const float* pair_emb   = (const float*)d_in[3];
    const int*   pair_present = (const int*)d_in[4];
    const float* W_num = (const float*)d_in[5];  const float* b_num = (const float*)d_in[6];
    const float* W_sap = (const float*)d_in[7];  const float* b_sap = (const float*)d_in[8];
    const float* W_ad  = (const float*)d_in[9];  const float* b_ad  = (const float*)d_in[10];
    const float* Wq = (const float*)d_in[11]; const float* bq = (const float*)d_in[12];
    const float* Wk = (const float*)d_in[13]; const float* bk = (const float*)d_in[14];
    const float* Wv = (const float*)d_in[15]; const float* bv = (const float*)d_in[16];
    const float* Wo = (const float*)d_in[17]; const float* bo = (const float*)d_in[18];
    const float* W_out = (const float*)d_in[19]; const float* b_out = (const float*)d_in[20];

    float* out = (float*)d_out;
    float* out_imputed = out;                 // [B,T,F]   524288
    float* out_stoch   = out + 524288;        // [B,T,F]   524288
    float* out_attn    = out + 1048576;       // [B,T,T]   2097152

    float* ws = (float*)d_ws;
    float* safe  = ws;                        // 524288
    float* query = ws + 524288;               // 2097152
    float* ctx   = ws + 2621440;              // aliased by probs later
    float* kv    = ws + 8912896;              // 2097152 (consumed before attn)
    float* qb    = ws + 11010048;             // 2097152 (Wm 1st half; attn_proj)
    float* kb    = ws + 13107200;             // 2097152 (Wm 2nd half)
    float* vb    = ws + 15204352;             // 2097152 (PeT + inv_cnt)
    float* pv    = ws + 17301504;             // 2097152
    float* pooled = ws + 19398656;            // 256
    unsigned long long* mask64 = (unsigned long long*)(ws + 19398912); // 8192 u64
    unsigned int* plist = (unsigned int*)(ws + 19415296);
    unsigned long long* rowmask = (unsigned long long*)(plist + 2020);
    float* probs = ctx;                       // 8388608 f32 (= ctx+kv region)

    unsigned short* Wm  = (unsigned short*)qb;   // 8192*1024 bf16 (qb+kb regions)
    unsigned short* PeT = (unsigned short*)vb;   // 768*1024 bf16
    float* inv_cnt = vb + 393216;                // 8192 f32

    // transposed bf16 weights
    unsigned short* wT = (unsigned short*)(ws + 19419392);
    unsigned short* WnumT = wT;                  // [256][64]
    unsigned short* WadT  = wT + 16384;          // [256][768]
    unsigned short* WqT   = wT + 212992;         // [256][256]
    unsigned short* WkT   = wT + 278528;
    unsigned short* WvT   = wT + 344064;
    unsigned short* WoT   = wT + 409600;
    unsigned short* WoutT = wT + 475136;         // [64][256]
    // wT region ends at float offset 19419392 + 245760 = 19665152
    float* colmean = ws + 19665152;              // 768 f32

    // 0. weight transposes (bf16)
    wtrans_kernel<<<dim3(Hz/32, Fz/32), 256, 0, stream>>>(W_num, WnumT, Fz, Hz);
    wtrans_kernel<<<dim3(Hz/32, Dz/32), 256, 0, stream>>>(W_ad, WadT, Dz, Hz);
    wtrans4_kernel<<<dim3(Hz/32, Hz/32, 4), 256, 0, stream>>>(
        Wq, Wk, Wv, Wo, WqT, WkT, WvT, WoT);
    wtrans_kernel<<<dim3(Fz/32, Hz/32), 256, 0, stream>>>(W_out, WoutT, Hz, Fz);

    // 1. masking
    mask_kernel<<<2048, 256, 0, stream>>>(batch_data, mask_probs, safe, out_stoch, mask64);
    // 2. pooled sapbert (parallel: colmean then gemv)
    colmean_kernel<<<3, 256, 0, stream>>>(sapE, colmean);
    pooled_gemv_kernel<<<4, 256, 0, stream>>>(colmean, W_sap, b_sap, pooled);
    // 3. present-pair list + row masks
    pairlist_kernel<<<1, 64, 0, stream>>>(pair_present, plist, rowmask);
    // 4. query = safe @ W_num + b_num + pooled   [8192,64]@[64,256]
    mfma_gemm_f32<128,64><<<dim3(4,64), 256, 0, stream>>>(
        safe, nullptr, WnumT, b_num, pooled, query, BTz, Hz, Fz);
    // 5. pair context as MFMA GEMM
    wbuild_kernel<<<BTz, 256, 0, stream>>>(mask64, plist, rowmask, Wm, inv_cnt);
    pebuild_kernel<<<NPAIRPAD, 256, 0, stream>>>(pair_emb, plist, PeT);
    mfma_gemm_rowscale<<<dim3(Dz / 128, BTz / 128), 256, 0, stream>>>(
        Wm, PeT, inv_cnt, ctx, BTz, Dz, NPAIRPAD);
    // 6. kv = ctx @ W_ad + b_ad   [8192,768]@[768,256]
    mfma_gemm_f32<128,64><<<dim3(4,64), 256, 0, stream>>>(
        ctx, nullptr, WadT, b_ad, nullptr, kv, BTz, Hz, Dz);
    // 7-9. q,k,v projections (overwrite Wm/PeT regions)
    mfma_gemm_f32<128,64><<<dim3(4,64), 256, 0, stream>>>(
        query, nullptr, WqT, bq, nullptr, qb, BTz, Hz, Hz);
    mfma_gemm_f32<128,64><<<dim3(4,64), 256, 0, stream>>>(
        kv, nullptr, WkT, bk, nullptr, kb, BTz, Hz, Hz);
    mfma_gemm_f32<128,64><<<dim3(4,64), 256, 0, stream>>>(
        kv, nullptr, WvT, bv, nullptr, vb, BTz, Hz, Hz);
    // 10. MFMA attention
    qkt_softmax_kernel<<<256, 256, 0, stream>>>(qb, kb, probs);
    pv_kernel<<<256, 256, 0, stream>>>(probs, vb, pv);
    // 11. attn_proj = pv @ Wo + bo -> reuse qb
    mfma_gemm_f32<128,64><<<dim3(4,64), 256, 0, stream>>>(
        pv, nullptr, WoT, bo, nullptr, qb, BTz, Hz, Hz);
    // 12. mean over heads -> out3
    meanheads_kernel<<<2048, 256, 0, stream>>>(probs, out_attn);
    // 13. imputed = (query + attn_proj) @ W_out + b_out
    mfma_gemm_f32<64,64><<<dim3(1,128), 256, 0, stream>>>(
        query, qb, WoutT, b_out, nullptr, out_imputed, BTz, Fz, Hz);
}

// Round 7
// 212.206 us; speedup vs baseline: 6.0318x; 1.2735x over previous
//
#include <hip/hip_runtime.h>
#include <hip/hip_bf16.h>

// Shapes
#define Bz 32
#define Tz 256
#define Fz 64
#define Dz 768
#define Sz 768
#define Hz 256
#define NHz 4
#define HDz 64
#define BTz 8192  // B*T
#define NPAIRPAD 1024
#define QKPAD 72   // bf16 units; 144B row stride: 2-way bank alias (free)
#define VTPAD 264
#define PLPAD 40

typedef __attribute__((ext_vector_type(8))) short short8v;
typedef __attribute__((ext_vector_type(8))) unsigned short ushort8v;
typedef __attribute__((ext_vector_type(4))) float f32x4;

__device__ inline unsigned short f2bf_rne(float x) {
    unsigned u = __float_as_uint(x);
    unsigned r = (u + 0x7fffu + ((u >> 16) & 1u)) >> 16;
    return (unsigned short)r;
}
__device__ inline float bf2f(unsigned short x) {
    return __uint_as_float(((unsigned)x) << 16);
}

// ---------------------------------------------------------------------------
// Kernel 1: masking.
// ---------------------------------------------------------------------------
__global__ __launch_bounds__(256) void mask_kernel(
    const float* __restrict__ bd, const float* __restrict__ mp,
    float* __restrict__ safe, float* __restrict__ stoch_out,
    unsigned long long* __restrict__ mask64)
{
    int idx = blockIdx.x * 256 + threadIdx.x;
    float x = bd[idx];
    float p = mp[idx];
    unsigned xb = __float_as_uint(x);
    bool valid = ((xb & 0x7fffffffu) <= 0x7f800000u);
    bool st = (p < 0.3f) && valid;
    bool sv = valid && !st;
    safe[idx] = sv ? x : 0.0f;
    stoch_out[idx] = st ? 1.0f : 0.0f;
    unsigned long long m = __ballot(sv);
    if ((threadIdx.x & 63) == 0) mask64[idx >> 6] = m;
}

// ---------------------------------------------------------------------------
// Kernel 2a: colmean[s] = mean over f of E[f][s].
// ---------------------------------------------------------------------------
__global__ __launch_bounds__(256) void colmean_kernel(
    const float* __restrict__ E, float* __restrict__ colmean)
{
    int s = blockIdx.x * 256 + threadIdx.x;
    float acc = 0.0f;
    #pragma unroll 8
    for (int f = 0; f < Fz; ++f) acc += E[(size_t)f * Sz + s];
    colmean[s] = acc * (1.0f / 64.0f);
}

// ---------------------------------------------------------------------------
// Kernel 2b: pooled[h] = b_sap[h] + sum_s colmean[s] * W_sap[s][h].
// ---------------------------------------------------------------------------
__global__ __launch_bounds__(256) void pooled_gemv_kernel(
    const float* __restrict__ colmean, const float* __restrict__ W_sap,
    const float* __restrict__ b_sap, float* __restrict__ pooled)
{
    __shared__ float red[4][64];
    const int tid = threadIdx.x;
    const int hl = tid & 63, sg = tid >> 6;
    const int h = blockIdx.x * 64 + hl;
    float acc = 0.0f;
    #pragma unroll 4
    for (int s = sg; s < Sz; s += 4)
        acc = fmaf(colmean[s], W_sap[(size_t)s * Hz + h], acc);
    red[sg][hl] = acc;
    __syncthreads();
    if (sg == 0)
        pooled[h] = b_sap[h] + ((red[0][hl] + red[1][hl]) + (red[2][hl] + red[3][hl]));
}

// ---------------------------------------------------------------------------
// Kernel 3: present (i<j) pair list + per-row present bitmasks.
// ---------------------------------------------------------------------------
__global__ __launch_bounds__(64) void pairlist_kernel(
    const int* __restrict__ present, unsigned int* __restrict__ plist,
    unsigned long long* __restrict__ rowmask)
{
    __shared__ int cnt[64];
    __shared__ int off[64];
    int i = threadIdx.x;
    int c = 0;
    unsigned long long rm = 0ull;
    for (int j = i + 1; j < 64; ++j)
        if (present[i * 64 + j] != 0) { c++; rm |= 1ull << j; }
    cnt[i] = c;
    rowmask[i] = rm;
    __syncthreads();
    if (i == 0) {
        int t = 0;
        for (int r = 0; r < 64; ++r) { off[r] = t; t += cnt[r]; }
        plist[0] = (unsigned)t;
    }
    __syncthreads();
    int o = 1 + off[i];
    for (int j = i + 1; j < 64; ++j)
        if (present[i * 64 + j] != 0) plist[o++] = (unsigned)(i * 64 + j);
}

// ---------------------------------------------------------------------------
// Weight transpose+cvt: in f32 [R][C] -> out bf16 [C][R]. 32x32 LDS tiles.
// ---------------------------------------------------------------------------
__device__ inline void transpose_tile(const float* __restrict__ in,
                                      unsigned short* __restrict__ out,
                                      int R, int C)
{
    __shared__ float t[32][33];
    const int tid = threadIdx.x;
    const int c0 = blockIdx.x * 32, r0 = blockIdx.y * 32;
    const int lc = tid & 31, lr8 = tid >> 5;
    #pragma unroll
    for (int i = 0; i < 4; ++i) {
        int r = lr8 + i * 8;
        t[r][lc] = in[(size_t)(r0 + r) * C + c0 + lc];
    }
    __syncthreads();
    #pragma unroll
    for (int i = 0; i < 4; ++i) {
        int oc = lr8 + i * 8;
        out[(size_t)(c0 + oc) * R + r0 + lc] = f2bf_rne(t[lc][oc]);
    }
}

__global__ __launch_bounds__(256) void wtrans_kernel(
    const float* __restrict__ in, unsigned short* __restrict__ out, int R, int C)
{
    transpose_tile(in, out, R, C);
}

__global__ __launch_bounds__(256) void wtrans4_kernel(
    const float* __restrict__ i0, const float* __restrict__ i1,
    const float* __restrict__ i2, const float* __restrict__ i3,
    unsigned short* __restrict__ o0, unsigned short* __restrict__ o1,
    unsigned short* __restrict__ o2, unsigned short* __restrict__ o3)
{
    const float* in; unsigned short* out;
    switch (blockIdx.z) {
        case 0: in = i0; out = o0; break;
        case 1: in = i1; out = o1; break;
        case 2: in = i2; out = o2; break;
        default: in = i3; out = o3; break;
    }
    transpose_tile(in, out, Hz, Hz);
}

// ---------------------------------------------------------------------------
// Kernel 4a: build bf16 0/1 selection matrix Wm[BT][1024] + inv_cnt[BT].
// ---------------------------------------------------------------------------
__global__ __launch_bounds__(256) void wbuild_kernel(
    const unsigned long long* __restrict__ mask64,
    const unsigned int* __restrict__ plist,
    const unsigned long long* __restrict__ rowmask,
    unsigned short* __restrict__ Wm, float* __restrict__ inv_cnt)
{
    int bt = blockIdx.x;
    int t = threadIdx.x;
    unsigned long long m = mask64[bt];
    int np = (int)plist[0];

    unsigned long long pack = 0ull;
    #pragma unroll
    for (int j = 0; j < 4; ++j) {
        int p = 4 * t + j;
        unsigned long long on = 0ull;
        if (p < np) {
            unsigned ij = plist[1 + p];
            on = (m >> (ij >> 6)) & (m >> (ij & 63)) & 1ull;
        }
        pack |= (on ? 0x3f80ull : 0ull) << (16 * j);
    }
    *(unsigned long long*)(Wm + (size_t)bt * NPAIRPAD + 4 * t) = pack;

    if (t < 64) {
        int c = ((m >> t) & 1ull) ? __popcll(m & rowmask[t]) : 0;
        #pragma unroll
        for (int off = 32; off; off >>= 1) c += __shfl_down(c, off);
        if (t == 0) inv_cnt[bt] = c > 0 ? 1.0f / (float)c : 0.0f;
    }
}

// ---------------------------------------------------------------------------
// Kernel 4b: gather pair_emb rows -> transposed bf16 PeT[768][1024].
// ---------------------------------------------------------------------------
__global__ __launch_bounds__(256) void pebuild_kernel(
    const float* __restrict__ pair_emb, const unsigned int* __restrict__ plist,
    unsigned short* __restrict__ PeT)
{
    int p = blockIdx.x;
    int t = threadIdx.x;
    int np = (int)plist[0];
    if (p < np) {
        unsigned ij = plist[1 + p];
        const float* src = pair_emb + (size_t)ij * Dz;
        #pragma unroll
        for (int c = 0; c < 3; ++c)
            PeT[(size_t)(t + c * 256) * NPAIRPAD + p] = f2bf_rne(src[t + c * 256]);
    } else {
        #pragma unroll
        for (int c = 0; c < 3; ++c)
            PeT[(size_t)(t + c * 256) * NPAIRPAD + p] = 0;
    }
}

// ---------------------------------------------------------------------------
// Kernel 5: MFMA bf16 GEMM with per-row f32 scale -> bf16 ctx out.
// ---------------------------------------------------------------------------
__global__ __launch_bounds__(256) void mfma_gemm_rowscale(
    const unsigned short* __restrict__ A, const unsigned short* __restrict__ Bt,
    const float* __restrict__ rs, unsigned short* __restrict__ C,
    int M, int N, int K)
{
    __shared__ unsigned short As[128 * 40];
    __shared__ unsigned short Bs[128 * 40];
    const int tid = threadIdx.x;
    const int lane = tid & 63;
    const int wave = tid >> 6;
    const int wr = wave >> 1, wc = wave & 1;
    const int row0 = blockIdx.y * 128, col0 = blockIdx.x * 128;

    f32x4 acc[4][4] = {};

    for (int k0 = 0; k0 < K; k0 += 32) {
        __syncthreads();
        #pragma unroll
        for (int i = 0; i < 2; ++i) {
            int c = tid + i * 256;
            int r = c >> 2, cc = c & 3;
            float4 av = *(const float4*)(A + (size_t)(row0 + r) * K + k0 + cc * 8);
            *(float4*)(As + r * 40 + cc * 8) = av;
            float4 bv = *(const float4*)(Bt + (size_t)(col0 + r) * K + k0 + cc * 8);
            *(float4*)(Bs + r * 40 + cc * 8) = bv;
        }
        __syncthreads();

        short8v a[4], b[4];
        #pragma unroll
        for (int m = 0; m < 4; ++m)
            a[m] = *(const short8v*)(As + (wr * 64 + m * 16 + (lane & 15)) * 40 + (lane >> 4) * 8);
        #pragma unroll
        for (int n = 0; n < 4; ++n)
            b[n] = *(const short8v*)(Bs + (wc * 64 + n * 16 + (lane & 15)) * 40 + (lane >> 4) * 8);
        #pragma unroll
        for (int m = 0; m < 4; ++m)
            #pragma unroll
            for (int n = 0; n < 4; ++n)
                acc[m][n] = __builtin_amdgcn_mfma_f32_16x16x32_bf16(a[m], b[n], acc[m][n], 0, 0, 0);
    }

    #pragma unroll
    for (int m = 0; m < 4; ++m) {
        #pragma unroll
        for (int r = 0; r < 4; ++r) {
            int row = row0 + wr * 64 + m * 16 + (lane >> 4) * 4 + r;
            float s = rs[row];
            #pragma unroll
            for (int n = 0; n < 4; ++n) {
                int col = col0 + wc * 64 + n * 16 + (lane & 15);
                C[(size_t)row * N + col] = f2bf_rne(acc[m][n][r] * s);
            }
        }
    }
}

// ---------------------------------------------------------------------------
// Unified MFMA GEMM. A: f32 (cvt at stage, optional A2 add) or bf16.
// Bt: bf16 [N][K]. Out f32 or bf16. B2MODE: 0=none/bias only, 1=bias+bias2,
// 2=concat (col<N/2: bias, else bias2).
// Waves: WC=BN/64 cols x WR=4/WC rows; each wave 64 cols x BM/WR rows.
// ---------------------------------------------------------------------------
template <int BM, int BN, bool ABF16, bool OUTBF16, int B2MODE>
__global__ __launch_bounds__(256) void mfma_gemm2(
    const void* __restrict__ Av, const float* __restrict__ A2,
    const unsigned short* __restrict__ Bt,
    const float* __restrict__ bias, const float* __restrict__ bias2,
    void* __restrict__ Cv, int M, int N, int K)
{
    constexpr int WC = BN / 64;
    constexpr int WR = 4 / WC;
    constexpr int RW = BM / WR;
    constexpr int MT = RW / 16;
    constexpr int NT = 4;
    __shared__ unsigned short As[BM * 40];
    __shared__ unsigned short Bs[BN * 40];
    const int tid = threadIdx.x;
    const int lane = tid & 63, wave = tid >> 6;
    const int l15 = lane & 15, g = lane >> 4;
    const int wr = wave / WC, wc = wave % WC;
    const int row0 = blockIdx.y * BM, col0 = blockIdx.x * BN;

    f32x4 acc[MT][NT] = {};

    for (int k0 = 0; k0 < K; k0 += 32) {
        __syncthreads();
        if (ABF16) {
            const unsigned short* A = (const unsigned short*)Av;
            #pragma unroll
            for (int i = 0; i < BM * 4 / 256; ++i) {
                int e = tid + i * 256;
                int r = e >> 2, c8 = e & 3;
                *(ushort8v*)(As + r * 40 + c8 * 8) =
                    *(const ushort8v*)(A + (size_t)(row0 + r) * K + k0 + c8 * 8);
            }
        } else {
            const float* A = (const float*)Av;
            #pragma unroll
            for (int i = 0; i < BM * 8 / 256; ++i) {
                int e = tid + i * 256;
                int r = e >> 3, c4 = e & 7;
                float4 v = *(const float4*)&A[(size_t)(row0 + r) * K + k0 + c4 * 4];
                if (A2) {
                    float4 v2 = *(const float4*)&A2[(size_t)(row0 + r) * K + k0 + c4 * 4];
                    v.x += v2.x; v.y += v2.y; v.z += v2.z; v.w += v2.w;
                }
                short4 s;
                s.x = (short)f2bf_rne(v.x); s.y = (short)f2bf_rne(v.y);
                s.z = (short)f2bf_rne(v.z); s.w = (short)f2bf_rne(v.w);
                *(short4*)(As + r * 40 + c4 * 4) = s;
            }
        }
        #pragma unroll
        for (int i = 0; i < BN * 4 / 256; ++i) {
            int e = tid + i * 256;
            int n = e >> 2, c = e & 3;
            *(ushort8v*)(Bs + n * 40 + c * 8) =
                *(const ushort8v*)(Bt + (size_t)(col0 + n) * K + k0 + c * 8);
        }
        __syncthreads();

        short8v a[MT], b[NT];
        #pragma unroll
        for (int m = 0; m < MT; ++m)
            a[m] = *(const short8v*)(As + (wr * RW + m * 16 + l15) * 40 + g * 8);
        #pragma unroll
        for (int n = 0; n < NT; ++n)
            b[n] = *(const short8v*)(Bs + (wc * 64 + n * 16 + l15) * 40 + g * 8);
        #pragma unroll
        for (int m = 0; m < MT; ++m)
            #pragma unroll
            for (int n = 0; n < NT; ++n)
                acc[m][n] = __builtin_amdgcn_mfma_f32_16x16x32_bf16(a[m], b[n], acc[m][n], 0, 0, 0);
    }

    #pragma unroll
    for (int m = 0; m < MT; ++m) {
        #pragma unroll
        for (int rr = 0; rr < 4; ++rr) {
            int row = row0 + wr * RW + m * 16 + g * 4 + rr;
            #pragma unroll
            for (int n = 0; n < NT; ++n) {
                int col = col0 + wc * 64 + n * 16 + l15;
                float o = acc[m][n][rr];
                if (B2MODE == 2) {
                    o += (col < (N >> 1)) ? bias[col] : bias2[col - (N >> 1)];
                } else {
                    o += bias[col];
                    if (B2MODE == 1) o += bias2[col];
                }
                if (OUTBF16) ((unsigned short*)Cv)[(size_t)row * N + col] = f2bf_rne(o);
                else         ((float*)Cv)[(size_t)row * N + col] = o;
            }
        }
    }
}

// ---------------------------------------------------------------------------
// Kernel 10a: MFMA QK^T + in-register softmax -> probs bf16.
// q: bf16 [BT][256] (head slice); k: bf16 [BT][512] cols h*64 (kvproj).
// ---------------------------------------------------------------------------
__global__ __launch_bounds__(256) void qkt_softmax_kernel(
    const unsigned short* __restrict__ q, const unsigned short* __restrict__ kp,
    unsigned short* __restrict__ probs)
{
    int blk = blockIdx.x;
    int bh = blk >> 1, half = blk & 1;
    int b = bh >> 2, h = bh & 3;
    __shared__ unsigned short Ql[128 * QKPAD];
    __shared__ unsigned short Kl[256 * QKPAD];
    const int tid = threadIdx.x;

    const unsigned short* qbase = q + (size_t)(b * Tz + half * 128) * Hz + h * HDz;
    #pragma unroll
    for (int i = 0; i < 4; ++i) {
        int e = tid + i * 256;           // 128 rows x 8 chunks
        int r = e >> 3, c8 = e & 7;
        *(ushort8v*)&Ql[r * QKPAD + c8 * 8] =
            *(const ushort8v*)(qbase + (size_t)r * Hz + c8 * 8);
    }
    const unsigned short* kbase = kp + (size_t)(b * Tz) * 512 + h * HDz;
    #pragma unroll
    for (int i = 0; i < 8; ++i) {
        int e = tid + i * 256;           // 256 rows x 8 chunks
        int r = e >> 3, c8 = e & 7;
        *(ushort8v*)&Kl[r * QKPAD + c8 * 8] =
            *(const ushort8v*)(kbase + (size_t)r * 512 + c8 * 8);
    }
    __syncthreads();

    const int lane = tid & 63, wave = tid >> 6;
    const int l15 = lane & 15, g = lane >> 4;

    f32x4 acc[2][16] = {};
    #pragma unroll
    for (int ks = 0; ks < 2; ++ks) {
        short8v a0 = *(const short8v*)&Ql[(wave * 32 + l15) * QKPAD + ks * 32 + g * 8];
        short8v a1 = *(const short8v*)&Ql[(wave * 32 + 16 + l15) * QKPAD + ks * 32 + g * 8];
        #pragma unroll
        for (int n = 0; n < 16; ++n) {
            short8v bn = *(const short8v*)&Kl[(n * 16 + l15) * QKPAD + ks * 32 + g * 8];
            acc[0][n] = __builtin_amdgcn_mfma_f32_16x16x32_bf16(a0, bn, acc[0][n], 0, 0, 0);
            acc[1][n] = __builtin_amdgcn_mfma_f32_16x16x32_bf16(a1, bn, acc[1][n], 0, 0, 0);
        }
    }

    #pragma unroll
    for (int m = 0; m < 2; ++m) {
        #pragma unroll
        for (int rr = 0; rr < 4; ++rr) {
            float mx = -1e30f;
            #pragma unroll
            for (int n = 0; n < 16; ++n) mx = fmaxf(mx, acc[m][n][rr]);
            #pragma unroll
            for (int s = 1; s < 16; s <<= 1) mx = fmaxf(mx, __shfl_xor(mx, s));
            float e[16];
            float sum = 0.0f;
            #pragma unroll
            for (int n = 0; n < 16; ++n) {
                e[n] = __expf(0.125f * (acc[m][n][rr] - mx));   // scores/8
                sum += e[n];
            }
            #pragma unroll
            for (int s = 1; s < 16; s <<= 1) sum += __shfl_xor(sum, s);
            float inv = 1.0f / sum;
            int row = half * 128 + wave * 32 + m * 16 + g * 4 + rr;
            unsigned short* dst = probs + ((size_t)bh * Tz + row) * Tz;
            #pragma unroll
            for (int n = 0; n < 16; ++n) dst[n * 16 + l15] = f2bf_rne(e[n] * inv);
        }
    }
}

// ---------------------------------------------------------------------------
// Kernel 10b: PV = probs @ V via MFMA. probs bf16; V = kvproj cols 256+h*64.
// Output pv bf16 [BT][256].
// ---------------------------------------------------------------------------
__global__ __launch_bounds__(256) void pv_kernel(
    const unsigned short* __restrict__ probs, const unsigned short* __restrict__ kp,
    unsigned short* __restrict__ pv)
{
    int blk = blockIdx.x;
    int bh = blk >> 1, half = blk & 1;
    int b = bh >> 2, h = bh & 3;
    __shared__ unsigned short Vt[64 * VTPAD];
    __shared__ unsigned short Pl[128 * PLPAD];
    const int tid = threadIdx.x;

    const unsigned short* vbase = kp + (size_t)(b * Tz) * 512 + 256 + h * HDz;
    #pragma unroll
    for (int i = 0; i < 8; ++i) {
        int e = tid + i * 256;           // 256 keys x 8 chunks of 8 d
        int key = e >> 3, c8 = e & 7;
        ushort8v v8 = *(const ushort8v*)(vbase + (size_t)key * 512 + c8 * 8);
        #pragma unroll
        for (int j = 0; j < 8; ++j)
            Vt[(c8 * 8 + j) * VTPAD + key] = v8[j];
    }

    const int lane = tid & 63, wave = tid >> 6;
    const int l15 = lane & 15, g = lane >> 4;
    f32x4 acc[2][4] = {};
    const unsigned short* pbase = probs + ((size_t)bh * Tz + half * 128) * Tz;

    for (int k0 = 0; k0 < 256; k0 += 32) {
        __syncthreads();
        #pragma unroll
        for (int i = 0; i < 2; ++i) {
            int e = tid + i * 256;       // 128 rows x 4 chunks
            int r = e >> 2, c8 = e & 3;
            *(ushort8v*)&Pl[r * PLPAD + c8 * 8] =
                *(const ushort8v*)(pbase + (size_t)r * Tz + k0 + c8 * 8);
        }
        __syncthreads();
        short8v a0 = *(const short8v*)&Pl[(wave * 32 + l15) * PLPAD + g * 8];
        short8v a1 = *(const short8v*)&Pl[(wave * 32 + 16 + l15) * PLPAD + g * 8];
        #pragma unroll
        for (int n = 0; n < 4; ++n) {
            short8v bn = *(const short8v*)&Vt[(n * 16 + l15) * VTPAD + k0 + g * 8];
            acc[0][n] = __builtin_amdgcn_mfma_f32_16x16x32_bf16(a0, bn, acc[0][n], 0, 0, 0);
            acc[1][n] = __builtin_amdgcn_mfma_f32_16x16x32_bf16(a1, bn, acc[1][n], 0, 0, 0);
        }
    }

    #pragma unroll
    for (int m = 0; m < 2; ++m) {
        #pragma unroll
        for (int rr = 0; rr < 4; ++rr) {
            int row = b * Tz + half * 128 + wave * 32 + m * 16 + g * 4 + rr;
            #pragma unroll
            for (int n = 0; n < 4; ++n)
                pv[(size_t)row * Hz + h * HDz + n * 16 + l15] = f2bf_rne(acc[m][n][rr]);
        }
    }
}

// ---------------------------------------------------------------------------
// Kernel 12: mean over heads of bf16 probs -> out3 f32 [B,T,T].
// Thread handles 8 tk.
// ---------------------------------------------------------------------------
__global__ __launch_bounds__(256) void meanheads_kernel(
    const unsigned short* __restrict__ probs, float* __restrict__ out3)
{
    int idx = blockIdx.x * 256 + threadIdx.x;   // over B*T*T/8
    int tk8 = idx & 31;
    int btq = idx >> 5;
    int b = btq >> 8, tq = btq & 255;
    float acc[8] = {};
    #pragma unroll
    for (int h = 0; h < 4; ++h) {
        int bh = b * 4 + h;
        ushort8v p = *(const ushort8v*)&probs[(((size_t)bh * Tz + tq) << 8) + tk8 * 8];
        #pragma unroll
        for (int j = 0; j < 8; ++j) acc[j] += bf2f(p[j]) * 0.25f;
    }
    float* dst = out3 + ((size_t)btq << 8) + tk8 * 8;
    float4 o0 = {acc[0], acc[1], acc[2], acc[3]};
    float4 o1 = {acc[4], acc[5], acc[6], acc[7]};
    *(float4*)dst = o0;
    *(float4*)(dst + 4) = o1;
}

// ---------------------------------------------------------------------------
extern "C" void kernel_launch(void* const* d_in, const int* in_sizes, int n_in,
                              void* d_out, int out_size, void* d_ws, size_t ws_size,
                              hipStream_t stream)
{
    const float* batch_data = (const float*)d_in[0];
    const float* mask_probs = (const float*)d_in[1];
    const float* sapE       = (const float*)d_in[2];
    const float* pair_emb   = (const float*)d_in[3];
    const int*   pair_present = (const int*)d_in[4];
    const float* W_num = (const float*)d_in[5];  const float* b_num = (const float*)d_in[6];
    const float* W_sap = (const float*)d_in[7];  const float* b_sap = (const float*)d_in[8];
    const float* W_ad  = (const float*)d_in[9];  const float* b_ad  = (const float*)d_in[10];
    const float* Wq = (const float*)d_in[11]; const float* bq = (const float*)d_in[12];
    const float* Wk = (const float*)d_in[13]; const float* bk = (const float*)d_in[14];
    const float* Wv = (const float*)d_in[15]; const float* bv = (const float*)d_in[16];
    const float* Wo = (const float*)d_in[17]; const float* bo = (const float*)d_in[18];
    const float* W_out = (const float*)d_in[19]; const float* b_out = (const float*)d_in[20];

    float* out = (float*)d_out;
    float* out_imputed = out;                 // [B,T,F]
    float* out_stoch   = out + 524288;        // [B,T,F]
    float* out_attn    = out + 1048576;       // [B,T,T]

    float* ws = (float*)d_ws;
    // f32-offset layout (regions re-used across phases; all deps verified):
    float* safe  = ws;                                   // 0..524288
    float* query = ws + 524288;                          // f32 [8192][256]
    unsigned short* probs = (unsigned short*)(ws + 2621440);   // bf16 [128][256][256] -> 4194304 f32
    unsigned short* ctxb  = (unsigned short*)(ws + 6815744);   // bf16 [8192][768] -> 3145728 f32
    unsigned short* kvb   = (unsigned short*)(ws + 9961472);   // bf16 [8192][256] -> 1048576 f32
    unsigned short* Wm    = (unsigned short*)(ws + 11010048);  // bf16 [8192][1024] -> 4194304 f32 (dead after rowscale)
    unsigned short* qbb   = (unsigned short*)(ws + 11010048);  // bf16 [8192][256] (over dead Wm)
    float* attn_proj      = ws + 13107200;               // f32 [8192][256] (over dead Wm tail)
    unsigned short* PeT   = (unsigned short*)(ws + 15204352);  // bf16 [768][1024] (dead after rowscale)
    float* inv_cnt        = ws + 15204352 + 393216;      // 8192 f32 (in PeT region slack)
    unsigned short* kvproj = (unsigned short*)(ws + 15204352); // bf16 [8192][512] (over dead PeT)
    unsigned short* pvb   = (unsigned short*)(ws + 17301504);  // bf16 [8192][256]
    float* pooled = ws + 19398656;
    unsigned long long* mask64 = (unsigned long long*)(ws + 19398912);
    unsigned int* plist = (unsigned int*)(ws + 19415296);
    unsigned long long* rowmask = (unsigned long long*)(plist + 2020);

    unsigned short* wT = (unsigned short*)(ws + 19419392);
    unsigned short* WnumT = wT;                  // [256][64]
    unsigned short* WadT  = wT + 16384;          // [256][768]
    unsigned short* WqT   = wT + 212992;         // [256][256]
    unsigned short* WkT   = wT + 278528;         // [256][256]  (WkT,WvT contiguous = [512][256])
    unsigned short* WvT   = wT + 344064;
    unsigned short* WoT   = wT + 409600;
    unsigned short* WoutT = wT + 475136;         // [64][256]
    float* colmean = ws + 19665152;              // 768 f32

    // 0. weight transposes (bf16)
    wtrans_kernel<<<dim3(Hz/32, Fz/32), 256, 0, stream>>>(W_num, WnumT, Fz, Hz);
    wtrans_kernel<<<dim3(Hz/32, Dz/32), 256, 0, stream>>>(W_ad, WadT, Dz, Hz);
    wtrans4_kernel<<<dim3(Hz/32, Hz/32, 4), 256, 0, stream>>>(
        Wq, Wk, Wv, Wo, WqT, WkT, WvT, WoT);
    wtrans_kernel<<<dim3(Fz/32, Hz/32), 256, 0, stream>>>(W_out, WoutT, Hz, Fz);

    // 1. masking
    mask_kernel<<<2048, 256, 0, stream>>>(batch_data, mask_probs, safe, out_stoch, mask64);
    // 2. pooled sapbert
    colmean_kernel<<<3, 256, 0, stream>>>(sapE, colmean);
    pooled_gemv_kernel<<<4, 256, 0, stream>>>(colmean, W_sap, b_sap, pooled);
    // 3. present-pair list + row masks
    pairlist_kernel<<<1, 64, 0, stream>>>(pair_present, plist, rowmask);
    // 4. query = safe @ W_num + b_num + pooled  (f32 out, needed for residual)
    mfma_gemm2<128,128,false,false,1><<<dim3(2,64), 256, 0, stream>>>(
        safe, nullptr, WnumT, b_num, pooled, query, BTz, Hz, Fz);
    // 5. pair context as MFMA GEMM -> ctx bf16
    wbuild_kernel<<<BTz, 256, 0, stream>>>(mask64, plist, rowmask, Wm, inv_cnt);
    pebuild_kernel<<<NPAIRPAD, 256, 0, stream>>>(pair_emb, plist, PeT);
    mfma_gemm_rowscale<<<dim3(Dz / 128, BTz / 128), 256, 0, stream>>>(
        Wm, PeT, inv_cnt, ctxb, BTz, Dz, NPAIRPAD);
    // 6. kv = ctx @ W_ad + b_ad -> bf16
    mfma_gemm2<128,128,true,true,0><<<dim3(2,64), 256, 0, stream>>>(
        ctxb, nullptr, WadT, b_ad, nullptr, kvb, BTz, Hz, Dz);
    // 7. q projection (query f32 -> bf16 out, over dead Wm)
    mfma_gemm2<128,128,false,true,0><<<dim3(2,64), 256, 0, stream>>>(
        query, nullptr, WqT, bq, nullptr, qbb, BTz, Hz, Hz);
    // 8. combined k|v projection -> kvproj bf16 [8192][512] (over dead PeT)
    mfma_gemm2<128,128,true,true,2><<<dim3(4,64), 256, 0, stream>>>(
        kvb, nullptr, WkT, bk, bv, kvproj, BTz, 512, Hz);
    // 10. MFMA attention (bf16 end-to-end, f32 softmax)
    qkt_softmax_kernel<<<256, 256, 0, stream>>>(qbb, kvproj, probs);
    pv_kernel<<<256, 256, 0, stream>>>(probs, kvproj, pvb);
    // 11. attn_proj = pv @ Wo + bo (f32, for residual)
    mfma_gemm2<128,128,true,false,0><<<dim3(2,64), 256, 0, stream>>>(
        pvb, nullptr, WoT, bo, nullptr, attn_proj, BTz, Hz, Hz);
    // 12. mean over heads -> out3
    meanheads_kernel<<<1024, 256, 0, stream>>>(probs, out_attn);
    // 13. imputed = (query + attn_proj) @ W_out + b_out
    mfma_gemm2<64,64,false,false,0><<<dim3(1,128), 256, 0, stream>>>(
        query, attn_proj, WoutT, b_out, nullptr, out_imputed, BTz, Fz, Hz);
}

// Round 8
// 199.624 us; speedup vs baseline: 6.4119x; 1.0630x over previous
//
#include <hip/hip_runtime.h>
#include <hip/hip_bf16.h>

// Shapes
#define Bz 32
#define Tz 256
#define Fz 64
#define Dz 768
#define Sz 768
#define Hz 256
#define NHz 4
#define HDz 64
#define BTz 8192  // B*T
#define NPAIRPAD 1024
#define QKPAD 72   // bf16 units; 144B row stride: 2-way bank alias (free)
#define VTPAD 264
#define PLPAD 40

typedef __attribute__((ext_vector_type(8))) short short8v;
typedef __attribute__((ext_vector_type(8))) unsigned short ushort8v;
typedef __attribute__((ext_vector_type(4))) float f32x4;

__device__ inline unsigned short f2bf_rne(float x) {
    unsigned u = __float_as_uint(x);
    unsigned r = (u + 0x7fffu + ((u >> 16) & 1u)) >> 16;
    return (unsigned short)r;
}
__device__ inline float bf2f(unsigned short x) {
    return __uint_as_float(((unsigned)x) << 16);
}

// ---------------------------------------------------------------------------
// Kernel 1: masking.
// ---------------------------------------------------------------------------
__global__ __launch_bounds__(256) void mask_kernel(
    const float* __restrict__ bd, const float* __restrict__ mp,
    float* __restrict__ safe, float* __restrict__ stoch_out,
    unsigned long long* __restrict__ mask64)
{
    int idx = blockIdx.x * 256 + threadIdx.x;
    float x = bd[idx];
    float p = mp[idx];
    unsigned xb = __float_as_uint(x);
    bool valid = ((xb & 0x7fffffffu) <= 0x7f800000u);
    bool st = (p < 0.3f) && valid;
    bool sv = valid && !st;
    safe[idx] = sv ? x : 0.0f;
    stoch_out[idx] = st ? 1.0f : 0.0f;
    unsigned long long m = __ballot(sv);
    if ((threadIdx.x & 63) == 0) mask64[idx >> 6] = m;
}

// ---------------------------------------------------------------------------
// pooled2: self-contained (colmean in LDS + gemv slice). 4 blocks.
// ---------------------------------------------------------------------------
__global__ __launch_bounds__(256) void pooled2_kernel(
    const float* __restrict__ E, const float* __restrict__ W_sap,
    const float* __restrict__ b_sap, float* __restrict__ pooled)
{
    __shared__ float colmean[Sz];
    __shared__ float red[4][64];
    const int tid = threadIdx.x;
    for (int s = tid; s < Sz; s += 256) {
        float a = 0.0f;
        #pragma unroll 8
        for (int f = 0; f < Fz; ++f) a += E[(size_t)f * Sz + s];
        colmean[s] = a * (1.0f / 64.0f);
    }
    __syncthreads();
    const int hl = tid & 63, sg = tid >> 6;
    const int h = blockIdx.x * 64 + hl;
    float acc = 0.0f;
    #pragma unroll 4
    for (int s = sg; s < Sz; s += 4)
        acc = fmaf(colmean[s], W_sap[(size_t)s * Hz + h], acc);
    red[sg][hl] = acc;
    __syncthreads();
    if (sg == 0)
        pooled[h] = b_sap[h] + ((red[0][hl] + red[1][hl]) + (red[2][hl] + red[3][hl]));
}

// ---------------------------------------------------------------------------
// prep: all weight transposes + pairlist + bocomb, one kernel.
// Block map: [0,16) WnumT | [16,208) WadT | [208,272) Wq | [272,336) Wk |
// [336,400) Wv | [400,464) Wo | [464,480) Wout | 480 pairlist | 481 bocomb.
// ---------------------------------------------------------------------------
__device__ inline void transpose_tile2(const float* __restrict__ in,
                                       unsigned short* __restrict__ out,
                                       int R, int C, int bx, int by, int tid)
{
    __shared__ float t[32][33];
    const int c0 = bx * 32, r0 = by * 32;
    const int lc = tid & 31, lr8 = tid >> 5;
    #pragma unroll
    for (int i = 0; i < 4; ++i) {
        int r = lr8 + i * 8;
        t[r][lc] = in[(size_t)(r0 + r) * C + c0 + lc];
    }
    __syncthreads();
    #pragma unroll
    for (int i = 0; i < 4; ++i) {
        int oc = lr8 + i * 8;
        out[(size_t)(c0 + oc) * R + r0 + lc] = f2bf_rne(t[lc][oc]);
    }
}

__global__ __launch_bounds__(256) void prep_kernel(
    const float* __restrict__ W_num, const float* __restrict__ W_ad,
    const float* __restrict__ Wq, const float* __restrict__ Wk,
    const float* __restrict__ Wv, const float* __restrict__ Wo,
    const float* __restrict__ W_out, const float* __restrict__ bo,
    const float* __restrict__ b_out, const int* __restrict__ present,
    unsigned short* __restrict__ WnumT, unsigned short* __restrict__ WadT,
    unsigned short* __restrict__ WqT, unsigned short* __restrict__ WkT,
    unsigned short* __restrict__ WvT, unsigned short* __restrict__ WoT,
    unsigned short* __restrict__ WoutT, float* __restrict__ bocomb,
    unsigned int* __restrict__ plist, unsigned long long* __restrict__ rowmask)
{
    const int bid = blockIdx.x;
    const int tid = threadIdx.x;
    if (bid < 16) {                       // WnumT: R=64,C=256, nx=8
        transpose_tile2(W_num, WnumT, Fz, Hz, bid & 7, bid >> 3, tid);
    } else if (bid < 208) {               // WadT: R=768,C=256, nx=8
        int lid = bid - 16;
        transpose_tile2(W_ad, WadT, Dz, Hz, lid & 7, lid >> 3, tid);
    } else if (bid < 464) {               // Wq/Wk/Wv/Wo: 64 tiles each, nx=8
        int lid = bid - 208;
        int which = lid >> 6, t8 = lid & 63;
        const float* in = which == 0 ? Wq : which == 1 ? Wk : which == 2 ? Wv : Wo;
        unsigned short* out = which == 0 ? WqT : which == 1 ? WkT : which == 2 ? WvT : WoT;
        transpose_tile2(in, out, Hz, Hz, t8 & 7, t8 >> 3, tid);
    } else if (bid < 480) {               // WoutT: R=256,C=64, nx=2
        int lid = bid - 464;
        transpose_tile2(W_out, WoutT, Hz, Fz, lid & 1, lid >> 1, tid);
    } else if (bid == 480) {              // pairlist
        __shared__ int cnt[64];
        __shared__ int off[64];
        int i = tid;
        if (i < 64) {
            int c = 0;
            unsigned long long rm = 0ull;
            for (int j = i + 1; j < 64; ++j)
                if (present[i * 64 + j] != 0) { c++; rm |= 1ull << j; }
            cnt[i] = c;
            rowmask[i] = rm;
        }
        __syncthreads();
        if (i == 0) {
            int t = 0;
            for (int r = 0; r < 64; ++r) { off[r] = t; t += cnt[r]; }
            plist[0] = (unsigned)t;
        }
        __syncthreads();
        if (i < 64) {
            int o = 1 + off[i];
            for (int j = i + 1; j < 64; ++j)
                if (present[i * 64 + j] != 0) plist[o++] = (unsigned)(i * 64 + j);
        }
    } else {                              // bocomb[c] = b_out[c] + bo @ W_out
        int c = tid;
        if (c < 64) {
            float a = b_out[c];
            for (int j = 0; j < 256; ++j) a = fmaf(bo[j], W_out[(size_t)j * 64 + c], a);
            bocomb[c] = a;
        }
    }
}

// ---------------------------------------------------------------------------
// Kernel 4a: build bf16 0/1 selection matrix Wm[BT][1024] + inv_cnt[BT].
// ---------------------------------------------------------------------------
__global__ __launch_bounds__(256) void wbuild_kernel(
    const unsigned long long* __restrict__ mask64,
    const unsigned int* __restrict__ plist,
    const unsigned long long* __restrict__ rowmask,
    unsigned short* __restrict__ Wm, float* __restrict__ inv_cnt)
{
    int bt = blockIdx.x;
    int t = threadIdx.x;
    unsigned long long m = mask64[bt];
    int np = (int)plist[0];

    unsigned long long pack = 0ull;
    #pragma unroll
    for (int j = 0; j < 4; ++j) {
        int p = 4 * t + j;
        unsigned long long on = 0ull;
        if (p < np) {
            unsigned ij = plist[1 + p];
            on = (m >> (ij >> 6)) & (m >> (ij & 63)) & 1ull;
        }
        pack |= (on ? 0x3f80ull : 0ull) << (16 * j);
    }
    *(unsigned long long*)(Wm + (size_t)bt * NPAIRPAD + 4 * t) = pack;

    if (t < 64) {
        int c = ((m >> t) & 1ull) ? __popcll(m & rowmask[t]) : 0;
        #pragma unroll
        for (int off = 32; off; off >>= 1) c += __shfl_down(c, off);
        if (t == 0) inv_cnt[bt] = c > 0 ? 1.0f / (float)c : 0.0f;
    }
}

// ---------------------------------------------------------------------------
// Kernel 4b: gather pair_emb rows -> transposed bf16 PeT[768][1024].
// ---------------------------------------------------------------------------
__global__ __launch_bounds__(256) void pebuild_kernel(
    const float* __restrict__ pair_emb, const unsigned int* __restrict__ plist,
    unsigned short* __restrict__ PeT)
{
    int p = blockIdx.x;
    int t = threadIdx.x;
    int np = (int)plist[0];
    if (p < np) {
        unsigned ij = plist[1 + p];
        const float* src = pair_emb + (size_t)ij * Dz;
        #pragma unroll
        for (int c = 0; c < 3; ++c)
            PeT[(size_t)(t + c * 256) * NPAIRPAD + p] = f2bf_rne(src[t + c * 256]);
    } else {
        #pragma unroll
        for (int c = 0; c < 3; ++c)
            PeT[(size_t)(t + c * 256) * NPAIRPAD + p] = 0;
    }
}

// ---------------------------------------------------------------------------
// Kernel 5: MFMA bf16 GEMM with per-row f32 scale -> bf16 ctx out.
// ---------------------------------------------------------------------------
__global__ __launch_bounds__(256) void mfma_gemm_rowscale(
    const unsigned short* __restrict__ A, const unsigned short* __restrict__ Bt,
    const float* __restrict__ rs, unsigned short* __restrict__ C,
    int M, int N, int K)
{
    __shared__ unsigned short As[128 * 40];
    __shared__ unsigned short Bs[128 * 40];
    const int tid = threadIdx.x;
    const int lane = tid & 63;
    const int wave = tid >> 6;
    const int wr = wave >> 1, wc = wave & 1;
    const int row0 = blockIdx.y * 128, col0 = blockIdx.x * 128;

    f32x4 acc[4][4] = {};

    for (int k0 = 0; k0 < K; k0 += 32) {
        __syncthreads();
        #pragma unroll
        for (int i = 0; i < 2; ++i) {
            int c = tid + i * 256;
            int r = c >> 2, cc = c & 3;
            float4 av = *(const float4*)(A + (size_t)(row0 + r) * K + k0 + cc * 8);
            *(float4*)(As + r * 40 + cc * 8) = av;
            float4 bv = *(const float4*)(Bt + (size_t)(col0 + r) * K + k0 + cc * 8);
            *(float4*)(Bs + r * 40 + cc * 8) = bv;
        }
        __syncthreads();

        short8v a[4], b[4];
        #pragma unroll
        for (int m = 0; m < 4; ++m)
            a[m] = *(const short8v*)(As + (wr * 64 + m * 16 + (lane & 15)) * 40 + (lane >> 4) * 8);
        #pragma unroll
        for (int n = 0; n < 4; ++n)
            b[n] = *(const short8v*)(Bs + (wc * 64 + n * 16 + (lane & 15)) * 40 + (lane >> 4) * 8);
        #pragma unroll
        for (int m = 0; m < 4; ++m)
            #pragma unroll
            for (int n = 0; n < 4; ++n)
                acc[m][n] = __builtin_amdgcn_mfma_f32_16x16x32_bf16(a[m], b[n], acc[m][n], 0, 0, 0);
    }

    #pragma unroll
    for (int m = 0; m < 4; ++m) {
        #pragma unroll
        for (int r = 0; r < 4; ++r) {
            int row = row0 + wr * 64 + m * 16 + (lane >> 4) * 4 + r;
            float s = rs[row];
            #pragma unroll
            for (int n = 0; n < 4; ++n) {
                int col = col0 + wc * 64 + n * 16 + (lane & 15);
                C[(size_t)row * N + col] = f2bf_rne(acc[m][n][r] * s);
            }
        }
    }
}

// ---------------------------------------------------------------------------
// Unified MFMA GEMM. A: f32 (cvt at stage, optional A2 add) or bf16.
// Bt: bf16 [N][K]. Out f32 or bf16. B2MODE: 0=bias, 1=bias+bias2,
// 2=concat (col<N/2: bias else bias2), 3=no bias.
// ---------------------------------------------------------------------------
template <int BM, int BN, bool ABF16, bool OUTBF16, int B2MODE>
__global__ __launch_bounds__(256) void mfma_gemm2(
    const void* __restrict__ Av, const float* __restrict__ A2,
    const unsigned short* __restrict__ Bt,
    const float* __restrict__ bias, const float* __restrict__ bias2,
    void* __restrict__ Cv, int M, int N, int K)
{
    constexpr int WC = BN / 64;
    constexpr int WR = 4 / WC;
    constexpr int RW = BM / WR;
    constexpr int MT = RW / 16;
    constexpr int NT = 4;
    __shared__ unsigned short As[BM * 40];
    __shared__ unsigned short Bs[BN * 40];
    const int tid = threadIdx.x;
    const int lane = tid & 63, wave = tid >> 6;
    const int l15 = lane & 15, g = lane >> 4;
    const int wr = wave / WC, wc = wave % WC;
    const int row0 = blockIdx.y * BM, col0 = blockIdx.x * BN;

    f32x4 acc[MT][NT] = {};

    for (int k0 = 0; k0 < K; k0 += 32) {
        __syncthreads();
        if (ABF16) {
            const unsigned short* A = (const unsigned short*)Av;
            #pragma unroll
            for (int i = 0; i < BM * 4 / 256; ++i) {
                int e = tid + i * 256;
                int r = e >> 2, c8 = e & 3;
                *(ushort8v*)(As + r * 40 + c8 * 8) =
                    *(const ushort8v*)(A + (size_t)(row0 + r) * K + k0 + c8 * 8);
            }
        } else {
            const float* A = (const float*)Av;
            #pragma unroll
            for (int i = 0; i < BM * 8 / 256; ++i) {
                int e = tid + i * 256;
                int r = e >> 3, c4 = e & 7;
                float4 v = *(const float4*)&A[(size_t)(row0 + r) * K + k0 + c4 * 4];
                if (A2) {
                    float4 v2 = *(const float4*)&A2[(size_t)(row0 + r) * K + k0 + c4 * 4];
                    v.x += v2.x; v.y += v2.y; v.z += v2.z; v.w += v2.w;
                }
                short4 s;
                s.x = (short)f2bf_rne(v.x); s.y = (short)f2bf_rne(v.y);
                s.z = (short)f2bf_rne(v.z); s.w = (short)f2bf_rne(v.w);
                *(short4*)(As + r * 40 + c4 * 4) = s;
            }
        }
        #pragma unroll
        for (int i = 0; i < BN * 4 / 256; ++i) {
            int e = tid + i * 256;
            int n = e >> 2, c = e & 3;
            *(ushort8v*)(Bs + n * 40 + c * 8) =
                *(const ushort8v*)(Bt + (size_t)(col0 + n) * K + k0 + c * 8);
        }
        __syncthreads();

        short8v a[MT], b[NT];
        #pragma unroll
        for (int m = 0; m < MT; ++m)
            a[m] = *(const short8v*)(As + (wr * RW + m * 16 + l15) * 40 + g * 8);
        #pragma unroll
        for (int n = 0; n < NT; ++n)
            b[n] = *(const short8v*)(Bs + (wc * 64 + n * 16 + l15) * 40 + g * 8);
        #pragma unroll
        for (int m = 0; m < MT; ++m)
            #pragma unroll
            for (int n = 0; n < NT; ++n)
                acc[m][n] = __builtin_amdgcn_mfma_f32_16x16x32_bf16(a[m], b[n], acc[m][n], 0, 0, 0);
    }

    #pragma unroll
    for (int m = 0; m < MT; ++m) {
        #pragma unroll
        for (int rr = 0; rr < 4; ++rr) {
            int row = row0 + wr * RW + m * 16 + g * 4 + rr;
            #pragma unroll
            for (int n = 0; n < NT; ++n) {
                int col = col0 + wc * 64 + n * 16 + l15;
                float o = acc[m][n][rr];
                if (B2MODE == 2) {
                    o += (col < (N >> 1)) ? bias[col] : bias2[col - (N >> 1)];
                } else if (B2MODE != 3) {
                    o += bias[col];
                    if (B2MODE == 1) o += bias2[col];
                }
                if (OUTBF16) ((unsigned short*)Cv)[(size_t)row * N + col] = f2bf_rne(o);
                else         ((float*)Cv)[(size_t)row * N + col] = o;
            }
        }
    }
}

// ---------------------------------------------------------------------------
// Fused attention: QK^T -> softmax (in-register, probs to global) -> PV,
// one kernel per (bh, half). LDS reused: {Q,K} then {V^T, P-chunk}.
// ---------------------------------------------------------------------------
__global__ __launch_bounds__(256) void attn_fused_kernel(
    const unsigned short* __restrict__ q, const unsigned short* __restrict__ kp,
    unsigned short* __restrict__ probs, unsigned short* __restrict__ pv)
{
    int blk = blockIdx.x;
    int bh = blk >> 1, half = blk & 1;
    int b = bh >> 2, h = bh & 3;
    __shared__ unsigned short smem[128 * QKPAD + 256 * QKPAD];  // 55296 B
    unsigned short* Ql = smem;
    unsigned short* Kl = smem + 128 * QKPAD;
    const int tid = threadIdx.x;

    const unsigned short* qbase = q + (size_t)(b * Tz + half * 128) * Hz + h * HDz;
    #pragma unroll
    for (int i = 0; i < 4; ++i) {
        int e = tid + i * 256;
        int r = e >> 3, c8 = e & 7;
        *(ushort8v*)&Ql[r * QKPAD + c8 * 8] =
            *(const ushort8v*)(qbase + (size_t)r * Hz + c8 * 8);
    }
    const unsigned short* kbase = kp + (size_t)(b * Tz) * 512 + h * HDz;
    #pragma unroll
    for (int i = 0; i < 8; ++i) {
        int e = tid + i * 256;
        int r = e >> 3, c8 = e & 7;
        *(ushort8v*)&Kl[r * QKPAD + c8 * 8] =
            *(const ushort8v*)(kbase + (size_t)r * 512 + c8 * 8);
    }
    __syncthreads();

    const int lane = tid & 63, wave = tid >> 6;
    const int l15 = lane & 15, g = lane >> 4;

    f32x4 acc[2][16] = {};
    #pragma unroll
    for (int ks = 0; ks < 2; ++ks) {
        short8v a0 = *(const short8v*)&Ql[(wave * 32 + l15) * QKPAD + ks * 32 + g * 8];
        short8v a1 = *(const short8v*)&Ql[(wave * 32 + 16 + l15) * QKPAD + ks * 32 + g * 8];
        #pragma unroll
        for (int n = 0; n < 16; ++n) {
            short8v bn = *(const short8v*)&Kl[(n * 16 + l15) * QKPAD + ks * 32 + g * 8];
            acc[0][n] = __builtin_amdgcn_mfma_f32_16x16x32_bf16(a0, bn, acc[0][n], 0, 0, 0);
            acc[1][n] = __builtin_amdgcn_mfma_f32_16x16x32_bf16(a1, bn, acc[1][n], 0, 0, 0);
        }
    }

    // softmax: normalize acc in place, write probs (bf16) to global
    #pragma unroll
    for (int m = 0; m < 2; ++m) {
        #pragma unroll
        for (int rr = 0; rr < 4; ++rr) {
            float mx = -1e30f;
            #pragma unroll
            for (int n = 0; n < 16; ++n) mx = fmaxf(mx, acc[m][n][rr]);
            #pragma unroll
            for (int s = 1; s < 16; s <<= 1) mx = fmaxf(mx, __shfl_xor(mx, s));
            float sum = 0.0f;
            #pragma unroll
            for (int n = 0; n < 16; ++n) {
                float e = __expf(0.125f * (acc[m][n][rr] - mx));
                acc[m][n][rr] = e;
                sum += e;
            }
            #pragma unroll
            for (int s = 1; s < 16; s <<= 1) sum += __shfl_xor(sum, s);
            float inv = 1.0f / sum;
            int row = half * 128 + wave * 32 + m * 16 + g * 4 + rr;
            unsigned short* dst = probs + ((size_t)bh * Tz + row) * Tz;
            #pragma unroll
            for (int n = 0; n < 16; ++n) {
                float p = acc[m][n][rr] * inv;
                acc[m][n][rr] = p;
                dst[n * 16 + l15] = f2bf_rne(p);
            }
        }
    }
    __syncthreads();   // all QK^T LDS reads done; safe to overwrite

    unsigned short* Vt = smem;                 // [64][VTPAD]
    unsigned short* Pl = smem + 64 * VTPAD;    // [128][PLPAD]
    const unsigned short* vbase = kp + (size_t)(b * Tz) * 512 + 256 + h * HDz;
    #pragma unroll
    for (int i = 0; i < 8; ++i) {
        int e = tid + i * 256;
        int key = e >> 3, c8 = e & 7;
        ushort8v v8 = *(const ushort8v*)(vbase + (size_t)key * 512 + c8 * 8);
        #pragma unroll
        for (int j = 0; j < 8; ++j)
            Vt[(c8 * 8 + j) * VTPAD + key] = v8[j];
    }

    f32x4 accpv[2][4] = {};
    for (int ks = 0; ks < 8; ++ks) {
        // write this chunk's P slice (rows owned by this wave)
        #pragma unroll
        for (int m = 0; m < 2; ++m) {
            #pragma unroll
            for (int rr = 0; rr < 4; ++rr) {
                int row = wave * 32 + m * 16 + g * 4 + rr;
                Pl[row * PLPAD + l15]      = f2bf_rne(acc[m][2 * ks][rr]);
                Pl[row * PLPAD + 16 + l15] = f2bf_rne(acc[m][2 * ks + 1][rr]);
            }
        }
        __syncthreads();   // Vt ready (1st iter) + Pl ready
        short8v a0 = *(const short8v*)&Pl[(wave * 32 + l15) * PLPAD + g * 8];
        short8v a1 = *(const short8v*)&Pl[(wave * 32 + 16 + l15) * PLPAD + g * 8];
        #pragma unroll
        for (int n = 0; n < 4; ++n) {
            short8v bn = *(const short8v*)&Vt[(n * 16 + l15) * VTPAD + ks * 32 + g * 8];
            accpv[0][n] = __builtin_amdgcn_mfma_f32_16x16x32_bf16(a0, bn, accpv[0][n], 0, 0, 0);
            accpv[1][n] = __builtin_amdgcn_mfma_f32_16x16x32_bf16(a1, bn, accpv[1][n], 0, 0, 0);
        }
        __syncthreads();   // before next Pl overwrite
    }

    #pragma unroll
    for (int m = 0; m < 2; ++m) {
        #pragma unroll
        for (int rr = 0; rr < 4; ++rr) {
            int row = b * Tz + half * 128 + wave * 32 + m * 16 + g * 4 + rr;
            #pragma unroll
            for (int n = 0; n < 4; ++n)
                pv[(size_t)row * Hz + h * HDz + n * 16 + l15] = f2bf_rne(accpv[m][n][rr]);
        }
    }
}

// ---------------------------------------------------------------------------
// meanheads: mean over heads of bf16 probs -> out3 f32 [B,T,T].
// ---------------------------------------------------------------------------
__global__ __launch_bounds__(256) void meanheads_kernel(
    const unsigned short* __restrict__ probs, float* __restrict__ out3)
{
    int idx = blockIdx.x * 256 + threadIdx.x;   // over B*T*T/8
    int tk8 = idx & 31;
    int btq = idx >> 5;
    int b = btq >> 8, tq = btq & 255;
    float acc[8] = {};
    #pragma unroll
    for (int h = 0; h < 4; ++h) {
        int bh = b * 4 + h;
        ushort8v p = *(const ushort8v*)&probs[(((size_t)bh * Tz + tq) << 8) + tk8 * 8];
        #pragma unroll
        for (int j = 0; j < 8; ++j) acc[j] += bf2f(p[j]) * 0.25f;
    }
    float* dst = out3 + ((size_t)btq << 8) + tk8 * 8;
    float4 o0 = {acc[0], acc[1], acc[2], acc[3]};
    float4 o1 = {acc[4], acc[5], acc[6], acc[7]};
    *(float4*)dst = o0;
    *(float4*)(dst + 4) = o1;
}

// ---------------------------------------------------------------------------
// final_gemm: out = query @ WoutT^T + pvb @ WWT^T + bocomb.  BM=BN=64.
// ---------------------------------------------------------------------------
__global__ __launch_bounds__(256) void final_gemm_kernel(
    const float* __restrict__ query, const unsigned short* __restrict__ pvb,
    const unsigned short* __restrict__ WoutT, const unsigned short* __restrict__ WWT,
    const float* __restrict__ bias, float* __restrict__ C)
{
    __shared__ unsigned short As[64 * 40];
    __shared__ unsigned short Bs[64 * 40];
    const int tid = threadIdx.x;
    const int lane = tid & 63, wave = tid >> 6;
    const int l15 = lane & 15, g = lane >> 4;
    const int row0 = blockIdx.x * 64;

    f32x4 acc[4] = {};

    // phase 1: query (f32) @ WoutT
    for (int k0 = 0; k0 < 256; k0 += 32) {
        __syncthreads();
        #pragma unroll
        for (int i = 0; i < 2; ++i) {
            int e = tid + i * 256;
            int r = e >> 3, c4 = e & 7;
            float4 v = *(const float4*)&query[(size_t)(row0 + r) * Hz + k0 + c4 * 4];
            short4 s;
            s.x = (short)f2bf_rne(v.x); s.y = (short)f2bf_rne(v.y);
            s.z = (short)f2bf_rne(v.z); s.w = (short)f2bf_rne(v.w);
            *(short4*)(As + r * 40 + c4 * 4) = s;
        }
        {
            int n = tid >> 2, c = tid & 3;
            *(ushort8v*)(Bs + n * 40 + c * 8) =
                *(const ushort8v*)(WoutT + (size_t)n * Hz + k0 + c * 8);
        }
        __syncthreads();
        short8v a = *(const short8v*)(As + (wave * 16 + l15) * 40 + g * 8);
        #pragma unroll
        for (int n = 0; n < 4; ++n) {
            short8v bn = *(const short8v*)(Bs + (n * 16 + l15) * 40 + g * 8);
            acc[n] = __builtin_amdgcn_mfma_f32_16x16x32_bf16(a, bn, acc[n], 0, 0, 0);
        }
    }
    // phase 2: pvb (bf16) @ WWT
    for (int k0 = 0; k0 < 256; k0 += 32) {
        __syncthreads();
        {
            int r = tid >> 2, c8 = tid & 3;
            *(ushort8v*)(As + r * 40 + c8 * 8) =
                *(const ushort8v*)(pvb + (size_t)(row0 + r) * Hz + k0 + c8 * 8);
            int n = tid >> 2, c = tid & 3;
            *(ushort8v*)(Bs + n * 40 + c * 8) =
                *(const ushort8v*)(WWT + (size_t)n * Hz + k0 + c * 8);
        }
        __syncthreads();
        short8v a = *(const short8v*)(As + (wave * 16 + l15) * 40 + g * 8);
        #pragma unroll
        for (int n = 0; n < 4; ++n) {
            short8v bn = *(const short8v*)(Bs + (n * 16 + l15) * 40 + g * 8);
            acc[n] = __builtin_amdgcn_mfma_f32_16x16x32_bf16(a, bn, acc[n], 0, 0, 0);
        }
    }

    #pragma unroll
    for (int rr = 0; rr < 4; ++rr) {
        int row = row0 + wave * 16 + g * 4 + rr;
        #pragma unroll
        for (int n = 0; n < 4; ++n) {
            int col = n * 16 + l15;
            C[(size_t)row * Fz + col] = acc[n][rr] + bias[col];
        }
    }
}

// ---------------------------------------------------------------------------
extern "C" void kernel_launch(void* const* d_in, const int* in_sizes, int n_in,
                              void* d_out, int out_size, void* d_ws, size_t ws_size,
                              hipStream_t stream)
{
    const float* batch_data = (const float*)d_in[0];
    const float* mask_probs = (const float*)d_in[1];
    const float* sapE       = (const float*)d_in[2];
    const float* pair_emb   = (const float*)d_in[3];
    const int*   pair_present = (const int*)d_in[4];
    const float* W_num = (const float*)d_in[5];  const float* b_num = (const float*)d_in[6];
    const float* W_sap = (const float*)d_in[7];  const float* b_sap = (const float*)d_in[8];
    const float* W_ad  = (const float*)d_in[9];  const float* b_ad  = (const float*)d_in[10];
    const float* Wq = (const float*)d_in[11]; const float* bq = (const float*)d_in[12];
    const float* Wk = (const float*)d_in[13]; const float* bk = (const float*)d_in[14];
    const float* Wv = (const float*)d_in[15]; const float* bv = (const float*)d_in[16];
    const float* Wo = (const float*)d_in[17]; const float* bo = (const float*)d_in[18];
    const float* W_out = (const float*)d_in[19]; const float* b_out = (const float*)d_in[20];

    float* out = (float*)d_out;
    float* out_imputed = out;                 // [B,T,F]
    float* out_stoch   = out + 524288;        // [B,T,F]
    float* out_attn    = out + 1048576;       // [B,T,T]

    float* ws = (float*)d_ws;
    float* safe  = ws;                                         // 0..524288
    float* query = ws + 524288;                                // f32 [8192][256]
    unsigned short* probs = (unsigned short*)(ws + 2621440);   // bf16 [128][256][256]
    unsigned short* ctxb  = (unsigned short*)(ws + 6815744);   // bf16 [8192][768]
    unsigned short* kvb   = (unsigned short*)(ws + 9961472);   // bf16 [8192][256]
    unsigned short* Wm    = (unsigned short*)(ws + 11010048);  // bf16 [8192][1024] (dead after rowscale)
    unsigned short* qbb   = (unsigned short*)(ws + 11010048);  // bf16 [8192][256] (over dead Wm)
    unsigned short* PeT   = (unsigned short*)(ws + 15204352);  // bf16 [768][1024] (dead after rowscale)
    float* inv_cnt        = ws + 15204352 + 393216;            // 8192 f32
    unsigned short* kvproj = (unsigned short*)(ws + 15204352); // bf16 [8192][512] (over dead PeT)
    unsigned short* pvb   = (unsigned short*)(ws + 17301504);  // bf16 [8192][256] -> ends 18350080
    unsigned short* WoWoutT = (unsigned short*)(ws + 18350080);// bf16 [64][256] (8192 f32)
    float* bocomb = ws + 18358272;                             // 64 f32
    float* pooled = ws + 19398656;
    unsigned long long* mask64 = (unsigned long long*)(ws + 19398912);
    unsigned int* plist = (unsigned int*)(ws + 19415296);
    unsigned long long* rowmask = (unsigned long long*)(plist + 2020);

    unsigned short* wT = (unsigned short*)(ws + 19419392);
    unsigned short* WnumT = wT;                  // [256][64]
    unsigned short* WadT  = wT + 16384;          // [256][768]
    unsigned short* WqT   = wT + 212992;         // [256][256]
    unsigned short* WkT   = wT + 278528;         // (WkT,WvT contiguous)
    unsigned short* WvT   = wT + 344064;
    unsigned short* WoT   = wT + 409600;
    unsigned short* WoutT = wT + 475136;         // [64][256]

    // 1. prep: transposes + pairlist + bocomb
    prep_kernel<<<482, 256, 0, stream>>>(
        W_num, W_ad, Wq, Wk, Wv, Wo, W_out, bo, b_out, pair_present,
        WnumT, WadT, WqT, WkT, WvT, WoT, WoutT, bocomb, plist, rowmask);
    // 2. WoWoutT = WoutT @ WoT^T  (== (Wo @ W_out)^T), bf16 [64][256]
    mfma_gemm2<64,128,true,true,3><<<dim3(2,1), 256, 0, stream>>>(
        WoutT, nullptr, WoT, nullptr, nullptr, WoWoutT, 64, Hz, Hz);
    // 3. pooled sapbert
    pooled2_kernel<<<4, 256, 0, stream>>>(sapE, W_sap, b_sap, pooled);
    // 4. masking
    mask_kernel<<<2048, 256, 0, stream>>>(batch_data, mask_probs, safe, out_stoch, mask64);
    // 5. query = safe @ W_num + b_num + pooled (f32 out, for residual)
    mfma_gemm2<128,128,false,false,1><<<dim3(2,64), 256, 0, stream>>>(
        safe, nullptr, WnumT, b_num, pooled, query, BTz, Hz, Fz);
    // 6. pair context as MFMA GEMM -> ctx bf16
    wbuild_kernel<<<BTz, 256, 0, stream>>>(mask64, plist, rowmask, Wm, inv_cnt);
    pebuild_kernel<<<NPAIRPAD, 256, 0, stream>>>(pair_emb, plist, PeT);
    mfma_gemm_rowscale<<<dim3(Dz / 128, BTz / 128), 256, 0, stream>>>(
        Wm, PeT, inv_cnt, ctxb, BTz, Dz, NPAIRPAD);
    // 7. kv = ctx @ W_ad + b_ad -> bf16
    mfma_gemm2<128,128,true,true,0><<<dim3(2,64), 256, 0, stream>>>(
        ctxb, nullptr, WadT, b_ad, nullptr, kvb, BTz, Hz, Dz);
    // 8. q projection (over dead Wm)
    mfma_gemm2<128,128,false,true,0><<<dim3(2,64), 256, 0, stream>>>(
        query, nullptr, WqT, bq, nullptr, qbb, BTz, Hz, Hz);
    // 9. combined k|v projection -> kvproj bf16 [8192][512]
    mfma_gemm2<128,128,true,true,2><<<dim3(4,64), 256, 0, stream>>>(
        kvb, nullptr, WkT, bk, bv, kvproj, BTz, 512, Hz);
    // 10. fused attention
    attn_fused_kernel<<<256, 256, 0, stream>>>(qbb, kvproj, probs, pvb);
    // 11. mean over heads -> out3
    meanheads_kernel<<<1024, 256, 0, stream>>>(probs, out_attn);
    // 12. imputed = query @ W_out + pv @ (Wo@W_out) + bocomb
    final_gemm_kernel<<<128, 256, 0, stream>>>(
        query, pvb, WoutT, WoWoutT, bocomb, out_imputed);
}

// Round 9
// 187.161 us; speedup vs baseline: 6.8389x; 1.0666x over previous
//
#include <hip/hip_runtime.h>
#include <hip/hip_bf16.h>

// Shapes
#define Bz 32
#define Tz 256
#define Fz 64
#define Dz 768
#define Sz 768
#define Hz 256
#define NHz 4
#define HDz 64
#define BTz 8192  // B*T
#define NPAIRPAD 1024
#define QKPAD 72   // bf16 units; 144B row stride: 2-way bank alias (free)
#define VTPAD 264
#define PLPAD 40

typedef __attribute__((ext_vector_type(8))) short short8v;
typedef __attribute__((ext_vector_type(8))) unsigned short ushort8v;
typedef __attribute__((ext_vector_type(4))) float f32x4;

__device__ inline unsigned short f2bf_rne(float x) {
    unsigned u = __float_as_uint(x);
    unsigned r = (u + 0x7fffu + ((u >> 16) & 1u)) >> 16;
    return (unsigned short)r;
}
__device__ inline float bf2f(unsigned short x) {
    return __uint_as_float(((unsigned)x) << 16);
}

// ---------------------------------------------------------------------------
// Kernel 1: masking -> safe bf16 + stoch f32 + survivor bitmask.
// ---------------------------------------------------------------------------
__global__ __launch_bounds__(256) void mask_kernel(
    const float* __restrict__ bd, const float* __restrict__ mp,
    unsigned short* __restrict__ safe_bf, float* __restrict__ stoch_out,
    unsigned long long* __restrict__ mask64)
{
    int idx = blockIdx.x * 256 + threadIdx.x;
    float x = bd[idx];
    float p = mp[idx];
    unsigned xb = __float_as_uint(x);
    bool valid = ((xb & 0x7fffffffu) <= 0x7f800000u);
    bool st = (p < 0.3f) && valid;
    bool sv = valid && !st;
    safe_bf[idx] = sv ? f2bf_rne(x) : 0;
    stoch_out[idx] = st ? 1.0f : 0.0f;
    unsigned long long m = __ballot(sv);
    if ((threadIdx.x & 63) == 0) mask64[idx >> 6] = m;
}

// ---------------------------------------------------------------------------
// pooled2: self-contained (colmean in LDS + gemv slice). 4 blocks.
// ---------------------------------------------------------------------------
__global__ __launch_bounds__(256) void pooled2_kernel(
    const float* __restrict__ E, const float* __restrict__ W_sap,
    const float* __restrict__ b_sap, float* __restrict__ pooled)
{
    __shared__ float colmean[Sz];
    __shared__ float red[4][64];
    const int tid = threadIdx.x;
    for (int s = tid; s < Sz; s += 256) {
        float a = 0.0f;
        #pragma unroll 8
        for (int f = 0; f < Fz; ++f) a += E[(size_t)f * Sz + s];
        colmean[s] = a * (1.0f / 64.0f);
    }
    __syncthreads();
    const int hl = tid & 63, sg = tid >> 6;
    const int h = blockIdx.x * 64 + hl;
    float acc = 0.0f;
    #pragma unroll 4
    for (int s = sg; s < Sz; s += 4)
        acc = fmaf(colmean[s], W_sap[(size_t)s * Hz + h], acc);
    red[sg][hl] = acc;
    __syncthreads();
    if (sg == 0)
        pooled[h] = b_sap[h] + ((red[0][hl] + red[1][hl]) + (red[2][hl] + red[3][hl]));
}

// ---------------------------------------------------------------------------
// prep: weight transposes + pairlist + bocomb + bkv + WadB, one kernel.
// Block map: [0,16) WnumT | [16,208) WadT | [208,464) Wq/Wk/Wv/Wo |
// [464,480) WoutT | 480 pairlist | 481 bocomb | 482-483 bkv | [484,676) WadB.
// ---------------------------------------------------------------------------
__device__ inline void transpose_tile2(const float* __restrict__ in,
                                       unsigned short* __restrict__ out,
                                       int R, int C, int bx, int by, int tid)
{
    __shared__ float t[32][33];
    const int c0 = bx * 32, r0 = by * 32;
    const int lc = tid & 31, lr8 = tid >> 5;
    #pragma unroll
    for (int i = 0; i < 4; ++i) {
        int r = lr8 + i * 8;
        t[r][lc] = in[(size_t)(r0 + r) * C + c0 + lc];
    }
    __syncthreads();
    #pragma unroll
    for (int i = 0; i < 4; ++i) {
        int oc = lr8 + i * 8;
        out[(size_t)(c0 + oc) * R + r0 + lc] = f2bf_rne(t[lc][oc]);
    }
}

__global__ __launch_bounds__(256) void prep_kernel(
    const float* __restrict__ W_num, const float* __restrict__ W_ad,
    const float* __restrict__ Wq, const float* __restrict__ Wk,
    const float* __restrict__ Wv, const float* __restrict__ Wo,
    const float* __restrict__ W_out, const float* __restrict__ bo,
    const float* __restrict__ b_out, const float* __restrict__ b_ad,
    const float* __restrict__ bk, const float* __restrict__ bv,
    const int* __restrict__ present,
    unsigned short* __restrict__ WnumT, unsigned short* __restrict__ WadT,
    unsigned short* __restrict__ WqT, unsigned short* __restrict__ WkT,
    unsigned short* __restrict__ WvT, unsigned short* __restrict__ WoT,
    unsigned short* __restrict__ WoutT, float* __restrict__ bocomb,
    float* __restrict__ bkv, unsigned short* __restrict__ WadB,
    unsigned int* __restrict__ plist, unsigned long long* __restrict__ rowmask)
{
    const int bid = blockIdx.x;
    const int tid = threadIdx.x;
    if (bid < 16) {
        transpose_tile2(W_num, WnumT, Fz, Hz, bid & 7, bid >> 3, tid);
    } else if (bid < 208) {
        int lid = bid - 16;
        transpose_tile2(W_ad, WadT, Dz, Hz, lid & 7, lid >> 3, tid);
    } else if (bid < 464) {
        int lid = bid - 208;
        int which = lid >> 6, t8 = lid & 63;
        const float* in = which == 0 ? Wq : which == 1 ? Wk : which == 2 ? Wv : Wo;
        unsigned short* out = which == 0 ? WqT : which == 1 ? WkT : which == 2 ? WvT : WoT;
        transpose_tile2(in, out, Hz, Hz, t8 & 7, t8 >> 3, tid);
    } else if (bid < 480) {
        int lid = bid - 464;
        transpose_tile2(W_out, WoutT, Hz, Fz, lid & 1, lid >> 1, tid);
    } else if (bid == 480) {              // pairlist
        __shared__ int cnt[64];
        __shared__ int off[64];
        int i = tid;
        if (i < 64) {
            int c = 0;
            unsigned long long rm = 0ull;
            for (int j = i + 1; j < 64; ++j)
                if (present[i * 64 + j] != 0) { c++; rm |= 1ull << j; }
            cnt[i] = c;
            rowmask[i] = rm;
        }
        __syncthreads();
        if (i == 0) {
            int t = 0;
            for (int r = 0; r < 64; ++r) { off[r] = t; t += cnt[r]; }
            plist[0] = (unsigned)t;
        }
        __syncthreads();
        if (i < 64) {
            int o = 1 + off[i];
            for (int j = i + 1; j < 64; ++j)
                if (present[i * 64 + j] != 0) plist[o++] = (unsigned)(i * 64 + j);
        }
    } else if (bid == 481) {              // bocomb[c] = b_out[c] + bo @ W_out
        int c = tid;
        if (c < 64) {
            float a = b_out[c];
            for (int j = 0; j < 256; ++j) a = fmaf(bo[j], W_out[(size_t)j * 64 + c], a);
            bocomb[c] = a;
        }
    } else if (bid < 484) {               // bkv: [0,256)=b_ad@Wk+bk, [256,512)=b_ad@Wv+bv
        int c = tid;
        const float* Wx = (bid == 482) ? Wk : Wv;
        const float* bx = (bid == 482) ? bk : bv;
        float a = bx[c];
        for (int j = 0; j < 256; ++j) a = fmaf(b_ad[j], Wx[(size_t)j * Hz + c], a);
        bkv[(bid - 482) * 256 + c] = a;
    } else {                              // WadB: f32 [768][256] -> bf16 copy
        int lid = bid - 484;              // 192 blocks x 1024 elems
        int base = lid * 1024 + tid * 4;
        #pragma unroll
        for (int j = 0; j < 4; ++j) WadB[base + j] = f2bf_rne(W_ad[base + j]);
    }
}

// ---------------------------------------------------------------------------
// wbuild_compact: sel[bt][16] u64 bit-per-pair + inv_cnt. Block = 16 bt.
// ---------------------------------------------------------------------------
__global__ __launch_bounds__(256) void wbuild_compact_kernel(
    const unsigned long long* __restrict__ mask64,
    const unsigned int* __restrict__ plist,
    unsigned long long* __restrict__ sel, float* __restrict__ inv_cnt)
{
    __shared__ unsigned int pl[NPAIRPAD];
    const int tid = threadIdx.x;
    for (int i = tid; i < NPAIRPAD; i += 256) pl[i] = plist[1 + i];
    __syncthreads();
    const int np = (int)plist[0];
    const int btl = tid >> 4, w = tid & 15;
    const int bt = blockIdx.x * 16 + btl;
    unsigned long long m = mask64[bt];
    unsigned long long word = 0ull;
    int pbase = w * 64;
    int jmax = min(64, np - pbase);
    for (int j = 0; j < jmax; ++j) {
        unsigned ij = pl[pbase + j];
        unsigned long long bit = (m >> (ij >> 6)) & (m >> (ij & 63)) & 1ull;
        word |= bit << j;
    }
    sel[(size_t)bt * 16 + w] = word;
    int c = __popcll(word);
    #pragma unroll
    for (int s = 1; s < 16; s <<= 1) c += __shfl_xor(c, s);
    if (w == 0) inv_cnt[bt] = c > 0 ? 1.0f / (float)c : 0.0f;
}

// ---------------------------------------------------------------------------
// Kernel 4b: gather pair_emb rows -> transposed bf16 PeT[768][1024].
// ---------------------------------------------------------------------------
__global__ __launch_bounds__(256) void pebuild_kernel(
    const float* __restrict__ pair_emb, const unsigned int* __restrict__ plist,
    unsigned short* __restrict__ PeT)
{
    int p = blockIdx.x;
    int t = threadIdx.x;
    int np = (int)plist[0];
    if (p < np) {
        unsigned ij = plist[1 + p];
        const float* src = pair_emb + (size_t)ij * Dz;
        #pragma unroll
        for (int c = 0; c < 3; ++c)
            PeT[(size_t)(t + c * 256) * NPAIRPAD + p] = f2bf_rne(src[t + c * 256]);
    } else {
        #pragma unroll
        for (int c = 0; c < 3; ++c)
            PeT[(size_t)(t + c * 256) * NPAIRPAD + p] = 0;
    }
}

// ---------------------------------------------------------------------------
// mfma_gemm_sel: pairctx GEMM. A built in-LDS from sel bits (0/1 bf16),
// B = PeT [N][K], per-row scale -> bf16 out.
// ---------------------------------------------------------------------------
__global__ __launch_bounds__(256) void mfma_gemm_sel(
    const unsigned long long* __restrict__ sel,
    const unsigned short* __restrict__ Bt,
    const float* __restrict__ rs, unsigned short* __restrict__ C,
    int M, int N, int K)
{
    __shared__ unsigned short As[128 * 40];
    __shared__ unsigned short Bs[128 * 40];
    const int tid = threadIdx.x;
    const int lane = tid & 63;
    const int wave = tid >> 6;
    const int wr = wave >> 1, wc = wave & 1;
    const int row0 = blockIdx.y * 128, col0 = blockIdx.x * 128;

    f32x4 acc[4][4] = {};

    for (int k0 = 0; k0 < K; k0 += 32) {
        __syncthreads();
        {   // A-stage: expand 16 selection bits per thread
            int r = tid >> 1, half = tid & 1;
            unsigned long long w = sel[(size_t)(row0 + r) * 16 + (k0 >> 6)];
            unsigned bits = (unsigned)(w >> ((k0 & 32) + half * 16)) & 0xFFFFu;
            unsigned short* dst = As + r * 40 + half * 16;
            #pragma unroll
            for (int j = 0; j < 16; j += 4) {
                unsigned long long pk = 0ull;
                if (bits & (1u << j))       pk |= 0x3f80ull;
                if (bits & (1u << (j + 1))) pk |= 0x3f80ull << 16;
                if (bits & (1u << (j + 2))) pk |= 0x3f80ull << 32;
                if (bits & (1u << (j + 3))) pk |= 0x3f80ull << 48;
                *(unsigned long long*)(dst + j) = pk;
            }
        }
        #pragma unroll
        for (int i = 0; i < 2; ++i) {   // B-stage
            int e = tid + i * 256;
            int n = e >> 2, c = e & 3;
            *(ushort8v*)(Bs + n * 40 + c * 8) =
                *(const ushort8v*)(Bt + (size_t)(col0 + n) * K + k0 + c * 8);
        }
        __syncthreads();

        short8v a[4], b[4];
        #pragma unroll
        for (int m = 0; m < 4; ++m)
            a[m] = *(const short8v*)(As + (wr * 64 + m * 16 + (lane & 15)) * 40 + (lane >> 4) * 8);
        #pragma unroll
        for (int n = 0; n < 4; ++n)
            b[n] = *(const short8v*)(Bs + (wc * 64 + n * 16 + (lane & 15)) * 40 + (lane >> 4) * 8);
        #pragma unroll
        for (int m = 0; m < 4; ++m)
            #pragma unroll
            for (int n = 0; n < 4; ++n)
                acc[m][n] = __builtin_amdgcn_mfma_f32_16x16x32_bf16(a[m], b[n], acc[m][n], 0, 0, 0);
    }

    #pragma unroll
    for (int m = 0; m < 4; ++m) {
        #pragma unroll
        for (int r = 0; r < 4; ++r) {
            int row = row0 + wr * 64 + m * 16 + (lane >> 4) * 4 + r;
            float s = rs[row];
            #pragma unroll
            for (int n = 0; n < 4; ++n) {
                int col = col0 + wc * 64 + n * 16 + (lane & 15);
                C[(size_t)row * N + col] = f2bf_rne(acc[m][n][r] * s);
            }
        }
    }
}

// ---------------------------------------------------------------------------
// Unified MFMA GEMM. A: f32 (cvt at stage, optional A2 add) or bf16.
// Bt: bf16 [N][K]. Out f32 or bf16. B2MODE: 0=bias, 1=bias+bias2,
// 2=concat (col<N/2: bias else bias2), 3=no bias.
// ---------------------------------------------------------------------------
template <int BM, int BN, bool ABF16, bool OUTBF16, int B2MODE>
__global__ __launch_bounds__(256) void mfma_gemm2(
    const void* __restrict__ Av, const float* __restrict__ A2,
    const unsigned short* __restrict__ Bt,
    const float* __restrict__ bias, const float* __restrict__ bias2,
    void* __restrict__ Cv, int M, int N, int K)
{
    constexpr int WC = BN / 64;
    constexpr int WR = 4 / WC;
    constexpr int RW = BM / WR;
    constexpr int MT = RW / 16;
    constexpr int NT = 4;
    __shared__ unsigned short As[BM * 40];
    __shared__ unsigned short Bs[BN * 40];
    const int tid = threadIdx.x;
    const int lane = tid & 63, wave = tid >> 6;
    const int l15 = lane & 15, g = lane >> 4;
    const int wr = wave / WC, wc = wave % WC;
    const int row0 = blockIdx.y * BM, col0 = blockIdx.x * BN;

    f32x4 acc[MT][NT] = {};

    for (int k0 = 0; k0 < K; k0 += 32) {
        __syncthreads();
        if (ABF16) {
            const unsigned short* A = (const unsigned short*)Av;
            #pragma unroll
            for (int i = 0; i < BM * 4 / 256; ++i) {
                int e = tid + i * 256;
                int r = e >> 2, c8 = e & 3;
                *(ushort8v*)(As + r * 40 + c8 * 8) =
                    *(const ushort8v*)(A + (size_t)(row0 + r) * K + k0 + c8 * 8);
            }
        } else {
            const float* A = (const float*)Av;
            #pragma unroll
            for (int i = 0; i < BM * 8 / 256; ++i) {
                int e = tid + i * 256;
                int r = e >> 3, c4 = e & 7;
                float4 v = *(const float4*)&A[(size_t)(row0 + r) * K + k0 + c4 * 4];
                if (A2) {
                    float4 v2 = *(const float4*)&A2[(size_t)(row0 + r) * K + k0 + c4 * 4];
                    v.x += v2.x; v.y += v2.y; v.z += v2.z; v.w += v2.w;
                }
                short4 s;
                s.x = (short)f2bf_rne(v.x); s.y = (short)f2bf_rne(v.y);
                s.z = (short)f2bf_rne(v.z); s.w = (short)f2bf_rne(v.w);
                *(short4*)(As + r * 40 + c4 * 4) = s;
            }
        }
        #pragma unroll
        for (int i = 0; i < BN * 4 / 256; ++i) {
            int e = tid + i * 256;
            int n = e >> 2, c = e & 3;
            *(ushort8v*)(Bs + n * 40 + c * 8) =
                *(const ushort8v*)(Bt + (size_t)(col0 + n) * K + k0 + c * 8);
        }
        __syncthreads();

        short8v a[MT], b[NT];
        #pragma unroll
        for (int m = 0; m < MT; ++m)
            a[m] = *(const short8v*)(As + (wr * RW + m * 16 + l15) * 40 + g * 8);
        #pragma unroll
        for (int n = 0; n < NT; ++n)
            b[n] = *(const short8v*)(Bs + (wc * 64 + n * 16 + l15) * 40 + g * 8);
        #pragma unroll
        for (int m = 0; m < MT; ++m)
            #pragma unroll
            for (int n = 0; n < NT; ++n)
                acc[m][n] = __builtin_amdgcn_mfma_f32_16x16x32_bf16(a[m], b[n], acc[m][n], 0, 0, 0);
    }

    #pragma unroll
    for (int m = 0; m < MT; ++m) {
        #pragma unroll
        for (int rr = 0; rr < 4; ++rr) {
            int row = row0 + wr * RW + m * 16 + g * 4 + rr;
            #pragma unroll
            for (int n = 0; n < NT; ++n) {
                int col = col0 + wc * 64 + n * 16 + l15;
                float o = acc[m][n][rr];
                if (B2MODE == 2) {
                    o += (col < (N >> 1)) ? bias[col] : bias2[col - (N >> 1)];
                } else if (B2MODE != 3) {
                    o += bias[col];
                    if (B2MODE == 1) o += bias2[col];
                }
                if (OUTBF16) ((unsigned short*)Cv)[(size_t)row * N + col] = f2bf_rne(o);
                else         ((float*)Cv)[(size_t)row * N + col] = o;
            }
        }
    }
}

// ---------------------------------------------------------------------------
// Fused attention: QK^T -> softmax (in-register, probs to global) -> PV.
// ---------------------------------------------------------------------------
__global__ __launch_bounds__(256) void attn_fused_kernel(
    const unsigned short* __restrict__ q, const unsigned short* __restrict__ kp,
    unsigned short* __restrict__ probs, unsigned short* __restrict__ pv)
{
    int blk = blockIdx.x;
    int bh = blk >> 1, half = blk & 1;
    int b = bh >> 2, h = bh & 3;
    __shared__ unsigned short smem[128 * QKPAD + 256 * QKPAD];
    unsigned short* Ql = smem;
    unsigned short* Kl = smem + 128 * QKPAD;
    const int tid = threadIdx.x;

    const unsigned short* qbase = q + (size_t)(b * Tz + half * 128) * Hz + h * HDz;
    #pragma unroll
    for (int i = 0; i < 4; ++i) {
        int e = tid + i * 256;
        int r = e >> 3, c8 = e & 7;
        *(ushort8v*)&Ql[r * QKPAD + c8 * 8] =
            *(const ushort8v*)(qbase + (size_t)r * Hz + c8 * 8);
    }
    const unsigned short* kbase = kp + (size_t)(b * Tz) * 512 + h * HDz;
    #pragma unroll
    for (int i = 0; i < 8; ++i) {
        int e = tid + i * 256;
        int r = e >> 3, c8 = e & 7;
        *(ushort8v*)&Kl[r * QKPAD + c8 * 8] =
            *(const ushort8v*)(kbase + (size_t)r * 512 + c8 * 8);
    }
    __syncthreads();

    const int lane = tid & 63, wave = tid >> 6;
    const int l15 = lane & 15, g = lane >> 4;

    f32x4 acc[2][16] = {};
    #pragma unroll
    for (int ks = 0; ks < 2; ++ks) {
        short8v a0 = *(const short8v*)&Ql[(wave * 32 + l15) * QKPAD + ks * 32 + g * 8];
        short8v a1 = *(const short8v*)&Ql[(wave * 32 + 16 + l15) * QKPAD + ks * 32 + g * 8];
        #pragma unroll
        for (int n = 0; n < 16; ++n) {
            short8v bn = *(const short8v*)&Kl[(n * 16 + l15) * QKPAD + ks * 32 + g * 8];
            acc[0][n] = __builtin_amdgcn_mfma_f32_16x16x32_bf16(a0, bn, acc[0][n], 0, 0, 0);
            acc[1][n] = __builtin_amdgcn_mfma_f32_16x16x32_bf16(a1, bn, acc[1][n], 0, 0, 0);
        }
    }

    #pragma unroll
    for (int m = 0; m < 2; ++m) {
        #pragma unroll
        for (int rr = 0; rr < 4; ++rr) {
            float mx = -1e30f;
            #pragma unroll
            for (int n = 0; n < 16; ++n) mx = fmaxf(mx, acc[m][n][rr]);
            #pragma unroll
            for (int s = 1; s < 16; s <<= 1) mx = fmaxf(mx, __shfl_xor(mx, s));
            float sum = 0.0f;
            #pragma unroll
            for (int n = 0; n < 16; ++n) {
                float e = __expf(0.125f * (acc[m][n][rr] - mx));
                acc[m][n][rr] = e;
                sum += e;
            }
            #pragma unroll
            for (int s = 1; s < 16; s <<= 1) sum += __shfl_xor(sum, s);
            float inv = 1.0f / sum;
            int row = half * 128 + wave * 32 + m * 16 + g * 4 + rr;
            unsigned short* dst = probs + ((size_t)bh * Tz + row) * Tz;
            #pragma unroll
            for (int n = 0; n < 16; ++n) {
                float p = acc[m][n][rr] * inv;
                acc[m][n][rr] = p;
                dst[n * 16 + l15] = f2bf_rne(p);
            }
        }
    }
    __syncthreads();

    unsigned short* Vt = smem;
    unsigned short* Pl = smem + 64 * VTPAD;
    const unsigned short* vbase = kp + (size_t)(b * Tz) * 512 + 256 + h * HDz;
    #pragma unroll
    for (int i = 0; i < 8; ++i) {
        int e = tid + i * 256;
        int key = e >> 3, c8 = e & 7;
        ushort8v v8 = *(const ushort8v*)(vbase + (size_t)key * 512 + c8 * 8);
        #pragma unroll
        for (int j = 0; j < 8; ++j)
            Vt[(c8 * 8 + j) * VTPAD + key] = v8[j];
    }

    f32x4 accpv[2][4] = {};
    for (int ks = 0; ks < 8; ++ks) {
        #pragma unroll
        for (int m = 0; m < 2; ++m) {
            #pragma unroll
            for (int rr = 0; rr < 4; ++rr) {
                int row = wave * 32 + m * 16 + g * 4 + rr;
                Pl[row * PLPAD + l15]      = f2bf_rne(acc[m][2 * ks][rr]);
                Pl[row * PLPAD + 16 + l15] = f2bf_rne(acc[m][2 * ks + 1][rr]);
            }
        }
        __syncthreads();
        short8v a0 = *(const short8v*)&Pl[(wave * 32 + l15) * PLPAD + g * 8];
        short8v a1 = *(const short8v*)&Pl[(wave * 32 + 16 + l15) * PLPAD + g * 8];
        #pragma unroll
        for (int n = 0; n < 4; ++n) {
            short8v bn = *(const short8v*)&Vt[(n * 16 + l15) * VTPAD + ks * 32 + g * 8];
            accpv[0][n] = __builtin_amdgcn_mfma_f32_16x16x32_bf16(a0, bn, accpv[0][n], 0, 0, 0);
            accpv[1][n] = __builtin_amdgcn_mfma_f32_16x16x32_bf16(a1, bn, accpv[1][n], 0, 0, 0);
        }
        __syncthreads();
    }

    #pragma unroll
    for (int m = 0; m < 2; ++m) {
        #pragma unroll
        for (int rr = 0; rr < 4; ++rr) {
            int row = b * Tz + half * 128 + wave * 32 + m * 16 + g * 4 + rr;
            #pragma unroll
            for (int n = 0; n < 4; ++n)
                pv[(size_t)row * Hz + h * HDz + n * 16 + l15] = f2bf_rne(accpv[m][n][rr]);
        }
    }
}

// ---------------------------------------------------------------------------
// meanheads: mean over heads of bf16 probs -> out3 f32 [B,T,T].
// ---------------------------------------------------------------------------
__global__ __launch_bounds__(256) void meanheads_kernel(
    const unsigned short* __restrict__ probs, float* __restrict__ out3)
{
    int idx = blockIdx.x * 256 + threadIdx.x;
    int tk8 = idx & 31;
    int btq = idx >> 5;
    int b = btq >> 8, tq = btq & 255;
    float acc[8] = {};
    #pragma unroll
    for (int h = 0; h < 4; ++h) {
        int bh = b * 4 + h;
        ushort8v p = *(const ushort8v*)&probs[(((size_t)bh * Tz + tq) << 8) + tk8 * 8];
        #pragma unroll
        for (int j = 0; j < 8; ++j) acc[j] += bf2f(p[j]) * 0.25f;
    }
    float* dst = out3 + ((size_t)btq << 8) + tk8 * 8;
    float4 o0 = {acc[0], acc[1], acc[2], acc[3]};
    float4 o1 = {acc[4], acc[5], acc[6], acc[7]};
    *(float4*)dst = o0;
    *(float4*)(dst + 4) = o1;
}

// ---------------------------------------------------------------------------
// final_gemm: out = qBF @ WoutT^T + pvb @ WWT^T + bocomb.  BM=BN=64.
// ---------------------------------------------------------------------------
__global__ __launch_bounds__(256) void final_gemm_kernel(
    const unsigned short* __restrict__ qBF, const unsigned short* __restrict__ pvb,
    const unsigned short* __restrict__ WoutT, const unsigned short* __restrict__ WWT,
    const float* __restrict__ bias, float* __restrict__ C)
{
    __shared__ unsigned short As[64 * 40];
    __shared__ unsigned short Bs[64 * 40];
    const int tid = threadIdx.x;
    const int lane = tid & 63, wave = tid >> 6;
    const int l15 = lane & 15, g = lane >> 4;
    const int row0 = blockIdx.x * 64;

    f32x4 acc[4] = {};

    for (int ph = 0; ph < 2; ++ph) {
        const unsigned short* Am = ph == 0 ? qBF : pvb;
        const unsigned short* Bm = ph == 0 ? WoutT : WWT;
        for (int k0 = 0; k0 < 256; k0 += 32) {
            __syncthreads();
            {
                int r = tid >> 2, c8 = tid & 3;
                *(ushort8v*)(As + r * 40 + c8 * 8) =
                    *(const ushort8v*)(Am + (size_t)(row0 + r) * Hz + k0 + c8 * 8);
                *(ushort8v*)(Bs + r * 40 + c8 * 8) =
                    *(const ushort8v*)(Bm + (size_t)r * Hz + k0 + c8 * 8);
            }
            __syncthreads();
            short8v a = *(const short8v*)(As + (wave * 16 + l15) * 40 + g * 8);
            #pragma unroll
            for (int n = 0; n < 4; ++n) {
                short8v bn = *(const short8v*)(Bs + (n * 16 + l15) * 40 + g * 8);
                acc[n] = __builtin_amdgcn_mfma_f32_16x16x32_bf16(a, bn, acc[n], 0, 0, 0);
            }
        }
    }

    #pragma unroll
    for (int rr = 0; rr < 4; ++rr) {
        int row = row0 + wave * 16 + g * 4 + rr;
        #pragma unroll
        for (int n = 0; n < 4; ++n) {
            int col = n * 16 + l15;
            C[(size_t)row * Fz + col] = acc[n][rr] + bias[col];
        }
    }
}

// ---------------------------------------------------------------------------
extern "C" void kernel_launch(void* const* d_in, const int* in_sizes, int n_in,
                              void* d_out, int out_size, void* d_ws, size_t ws_size,
                              hipStream_t stream)
{
    const float* batch_data = (const float*)d_in[0];
    const float* mask_probs = (const float*)d_in[1];
    const float* sapE       = (const float*)d_in[2];
    const float* pair_emb   = (const float*)d_in[3];
    const int*   pair_present = (const int*)d_in[4];
    const float* W_num = (const float*)d_in[5];  const float* b_num = (const float*)d_in[6];
    const float* W_sap = (const float*)d_in[7];  const float* b_sap = (const float*)d_in[8];
    const float* W_ad  = (const float*)d_in[9];  const float* b_ad  = (const float*)d_in[10];
    const float* Wq = (const float*)d_in[11]; const float* bq = (const float*)d_in[12];
    const float* Wk = (const float*)d_in[13]; const float* bk = (const float*)d_in[14];
    const float* Wv = (const float*)d_in[15]; const float* bv = (const float*)d_in[16];
    const float* Wo = (const float*)d_in[17]; const float* bo = (const float*)d_in[18];
    const float* W_out = (const float*)d_in[19]; const float* b_out = (const float*)d_in[20];

    float* out = (float*)d_out;
    float* out_imputed = out;                 // [B,T,F]
    float* out_stoch   = out + 524288;        // [B,T,F]
    float* out_attn    = out + 1048576;       // [B,T,T]

    float* ws = (float*)d_ws;
    unsigned short* safe_bf = (unsigned short*)ws;             // bf16 [8192][64] -> [0, 262144)
    unsigned short* qBF   = (unsigned short*)(ws + 524288);    // bf16 [8192][256] -> [524288, 1572864)
    unsigned short* probs = (unsigned short*)(ws + 2621440);   // bf16 [128][256][256]
    unsigned short* ctxb  = (unsigned short*)(ws + 6815744);   // bf16 [8192][768] -> [6815744, 9961472)
    unsigned long long* sel = (unsigned long long*)(ws + 9961472); // u64 [8192][16] -> 262144 f32
    unsigned short* qbb   = (unsigned short*)(ws + 11010048);  // bf16 [8192][256]
    unsigned short* PeT   = (unsigned short*)(ws + 15204352);  // bf16 [768][1024] (dead after sel GEMM)
    float* inv_cnt        = ws + 15204352 + 393216;            // 8192 f32 (consumed by sel GEMM)
    unsigned short* kvproj = (unsigned short*)(ws + 15204352); // bf16 [8192][512] (over dead PeT)
    unsigned short* pvb   = (unsigned short*)(ws + 17301504);  // bf16 [8192][256] -> ends 18350080
    unsigned short* WoWoutT = (unsigned short*)(ws + 18350080);// bf16 [64][256]
    float* bocomb = ws + 18358272;                             // 64 f32
    float* bkv    = ws + 18358336;                             // 512 f32
    unsigned short* WadkvT = (unsigned short*)(ws + 18358848); // bf16 [512][768] -> 196608 f32
    unsigned short* WadB   = (unsigned short*)(ws + 18555456); // bf16 [768][256] -> 49152 f32
    float* pooled = ws + 19398656;
    unsigned long long* mask64 = (unsigned long long*)(ws + 19398912);
    unsigned int* plist = (unsigned int*)(ws + 19415296);
    unsigned long long* rowmask = (unsigned long long*)(plist + 2020);

    unsigned short* wT = (unsigned short*)(ws + 19419392);
    unsigned short* WnumT = wT;                  // [256][64]
    unsigned short* WadT  = wT + 16384;          // [256][768]
    unsigned short* WqT   = wT + 212992;         // [256][256]
    unsigned short* WkT   = wT + 278528;         // (WkT,WvT contiguous = WkvT [512][256])
    unsigned short* WvT   = wT + 344064;
    unsigned short* WoT   = wT + 409600;
    unsigned short* WoutT = wT + 475136;         // [64][256]

    // 1. prep
    prep_kernel<<<676, 256, 0, stream>>>(
        W_num, W_ad, Wq, Wk, Wv, Wo, W_out, bo, b_out, b_ad, bk, bv, pair_present,
        WnumT, WadT, WqT, WkT, WvT, WoT, WoutT, bocomb, bkv, WadB, plist, rowmask);
    // 2. WoWoutT = WoutT @ WoT^T
    mfma_gemm2<64,128,true,true,3><<<dim3(2,1), 256, 0, stream>>>(
        WoutT, nullptr, WoT, nullptr, nullptr, WoWoutT, 64, Hz, Hz);
    // 3. WadkvT = WkvT @ WadB^T  ([512][256] @ [256][768] = (W_ad@[Wk|Wv])^T)
    mfma_gemm2<128,128,true,true,3><<<dim3(6,4), 256, 0, stream>>>(
        WkT, nullptr, WadB, nullptr, nullptr, WadkvT, 512, Dz, Hz);
    // 4. pooled sapbert
    pooled2_kernel<<<4, 256, 0, stream>>>(sapE, W_sap, b_sap, pooled);
    // 5. masking
    mask_kernel<<<2048, 256, 0, stream>>>(batch_data, mask_probs, safe_bf, out_stoch, mask64);
    // 6. query = safe @ W_num + b_num + pooled -> bf16
    mfma_gemm2<128,128,true,true,1><<<dim3(2,64), 256, 0, stream>>>(
        safe_bf, nullptr, WnumT, b_num, pooled, qBF, BTz, Hz, Fz);
    // 7. compact selection + counts
    wbuild_compact_kernel<<<512, 256, 0, stream>>>(mask64, plist, sel, inv_cnt);
    // 8. PeT gather
    pebuild_kernel<<<NPAIRPAD, 256, 0, stream>>>(pair_emb, plist, PeT);
    // 9. pair context GEMM (A from sel bits)
    mfma_gemm_sel<<<dim3(Dz / 128, BTz / 128), 256, 0, stream>>>(
        sel, PeT, inv_cnt, ctxb, BTz, Dz, NPAIRPAD);
    // 10. q projection
    mfma_gemm2<128,128,true,true,0><<<dim3(2,64), 256, 0, stream>>>(
        qBF, nullptr, WqT, bq, nullptr, qbb, BTz, Hz, Hz);
    // 11. fused k|v projection: ctx @ WadkvT^T + bkv -> kvproj [8192][512]
    mfma_gemm2<64,256,true,true,0><<<dim3(2,128), 256, 0, stream>>>(
        ctxb, nullptr, WadkvT, bkv, nullptr, kvproj, BTz, 512, Dz);
    // 12. fused attention
    attn_fused_kernel<<<256, 256, 0, stream>>>(qbb, kvproj, probs, pvb);
    // 13. mean over heads -> out3
    meanheads_kernel<<<1024, 256, 0, stream>>>(probs, out_attn);
    // 14. imputed = qBF @ W_out + pv @ (Wo@W_out) + bocomb
    final_gemm_kernel<<<128, 256, 0, stream>>>(
        qBF, pvb, WoutT, WoWoutT, bocomb, out_imputed);
}

// Round 10
// 168.973 us; speedup vs baseline: 7.5750x; 1.1076x over previous
//
#include <hip/hip_runtime.h>
#include <hip/hip_bf16.h>

// Shapes
#define Bz 32
#define Tz 256
#define Fz 64
#define Dz 768
#define Sz 768
#define Hz 256
#define NHz 4
#define HDz 64
#define BTz 8192  // B*T
#define NPAIRPAD 1024
#define QKPAD 72   // bf16 units; 144B row stride: 2-way bank alias (free)
#define VTPAD 264
#define PLPAD 72   // PV 64-key chunk

typedef __attribute__((ext_vector_type(8))) short short8v;
typedef __attribute__((ext_vector_type(8))) unsigned short ushort8v;
typedef __attribute__((ext_vector_type(4))) float f32x4;

__device__ inline unsigned short f2bf_rne(float x) {
    unsigned u = __float_as_uint(x);
    unsigned r = (u + 0x7fffu + ((u >> 16) & 1u)) >> 16;
    return (unsigned short)r;
}
__device__ inline float bf2f(unsigned short x) {
    return __uint_as_float(((unsigned)x) << 16);
}

// ===========================================================================
// Device bodies (shared memory passed in; block index passed as bx/by)
// ===========================================================================

// Unified MFMA GEMM body. A: bf16 [M][K]. Bt: bf16 [N][K]. Out f32/bf16.
// B2MODE: 0=bias, 1=bias+bias2, 2=concat, 3=no bias.
template <int BM, int BN, bool OUTBF16, int B2MODE>
__device__ __forceinline__ void gemm2_body(
    unsigned short* __restrict__ smem,
    const unsigned short* __restrict__ A,
    const unsigned short* __restrict__ Bt,
    const float* __restrict__ bias, const float* __restrict__ bias2,
    void* __restrict__ Cv, int M, int N, int K, int bx, int by, int tid)
{
    constexpr int WC = BN / 64;
    constexpr int WR = 4 / WC;
    constexpr int RW = BM / WR;
    constexpr int MT = RW / 16;
    constexpr int NT = 4;
    unsigned short* As = smem;
    unsigned short* Bs = smem + BM * 40;
    const int lane = tid & 63, wave = tid >> 6;
    const int l15 = lane & 15, g = lane >> 4;
    const int wr = wave / WC, wc = wave % WC;
    const int row0 = by * BM, col0 = bx * BN;

    f32x4 acc[MT][NT] = {};

    for (int k0 = 0; k0 < K; k0 += 32) {
        __syncthreads();
        #pragma unroll
        for (int i = 0; i < BM * 4 / 256; ++i) {
            int e = tid + i * 256;
            int r = e >> 2, c8 = e & 3;
            *(ushort8v*)(As + r * 40 + c8 * 8) =
                *(const ushort8v*)(A + (size_t)(row0 + r) * K + k0 + c8 * 8);
        }
        #pragma unroll
        for (int i = 0; i < BN * 4 / 256; ++i) {
            int e = tid + i * 256;
            int n = e >> 2, c = e & 3;
            *(ushort8v*)(Bs + n * 40 + c * 8) =
                *(const ushort8v*)(Bt + (size_t)(col0 + n) * K + k0 + c * 8);
        }
        __syncthreads();

        short8v a[MT], b[NT];
        #pragma unroll
        for (int m = 0; m < MT; ++m)
            a[m] = *(const short8v*)(As + (wr * RW + m * 16 + l15) * 40 + g * 8);
        #pragma unroll
        for (int n = 0; n < NT; ++n)
            b[n] = *(const short8v*)(Bs + (wc * 64 + n * 16 + l15) * 40 + g * 8);
        #pragma unroll
        for (int m = 0; m < MT; ++m)
            #pragma unroll
            for (int n = 0; n < NT; ++n)
                acc[m][n] = __builtin_amdgcn_mfma_f32_16x16x32_bf16(a[m], b[n], acc[m][n], 0, 0, 0);
    }

    #pragma unroll
    for (int m = 0; m < MT; ++m) {
        #pragma unroll
        for (int rr = 0; rr < 4; ++rr) {
            int row = row0 + wr * RW + m * 16 + g * 4 + rr;
            #pragma unroll
            for (int n = 0; n < NT; ++n) {
                int col = col0 + wc * 64 + n * 16 + l15;
                float o = acc[m][n][rr];
                if (B2MODE == 2) {
                    o += (col < (N >> 1)) ? bias[col] : bias2[col - (N >> 1)];
                } else if (B2MODE != 3) {
                    o += bias[col];
                    if (B2MODE == 1) o += bias2[col];
                }
                if (OUTBF16) ((unsigned short*)Cv)[(size_t)row * N + col] = f2bf_rne(o);
                else         ((float*)Cv)[(size_t)row * N + col] = o;
            }
        }
    }
}

// pairctx GEMM body: A expanded in-LDS from sel bits (0/1 bf16), per-row scale.
__device__ __forceinline__ void gemm_sel_body(
    unsigned short* __restrict__ smem,
    const unsigned long long* __restrict__ sel,
    const unsigned short* __restrict__ Bt,
    const float* __restrict__ rs, unsigned short* __restrict__ C,
    int M, int N, int K, int bx, int by, int tid)
{
    unsigned short* As = smem;
    unsigned short* Bs = smem + 128 * 40;
    const int lane = tid & 63;
    const int wave = tid >> 6;
    const int wr = wave >> 1, wc = wave & 1;
    const int row0 = by * 128, col0 = bx * 128;

    f32x4 acc[4][4] = {};

    for (int k0 = 0; k0 < K; k0 += 32) {
        __syncthreads();
        {
            int r = tid >> 1, half = tid & 1;
            unsigned long long w = sel[(size_t)(row0 + r) * 16 + (k0 >> 6)];
            unsigned bits = (unsigned)(w >> ((k0 & 32) + half * 16)) & 0xFFFFu;
            unsigned short* dst = As + r * 40 + half * 16;
            #pragma unroll
            for (int j = 0; j < 16; j += 4) {
                unsigned long long pk = 0ull;
                if (bits & (1u << j))       pk |= 0x3f80ull;
                if (bits & (1u << (j + 1))) pk |= 0x3f80ull << 16;
                if (bits & (1u << (j + 2))) pk |= 0x3f80ull << 32;
                if (bits & (1u << (j + 3))) pk |= 0x3f80ull << 48;
                *(unsigned long long*)(dst + j) = pk;
            }
        }
        #pragma unroll
        for (int i = 0; i < 2; ++i) {
            int e = tid + i * 256;
            int n = e >> 2, c = e & 3;
            *(ushort8v*)(Bs + n * 40 + c * 8) =
                *(const ushort8v*)(Bt + (size_t)(col0 + n) * K + k0 + c * 8);
        }
        __syncthreads();

        short8v a[4], b[4];
        #pragma unroll
        for (int m = 0; m < 4; ++m)
            a[m] = *(const short8v*)(As + (wr * 64 + m * 16 + (lane & 15)) * 40 + (lane >> 4) * 8);
        #pragma unroll
        for (int n = 0; n < 4; ++n)
            b[n] = *(const short8v*)(Bs + (wc * 64 + n * 16 + (lane & 15)) * 40 + (lane >> 4) * 8);
        #pragma unroll
        for (int m = 0; m < 4; ++m)
            #pragma unroll
            for (int n = 0; n < 4; ++n)
                acc[m][n] = __builtin_amdgcn_mfma_f32_16x16x32_bf16(a[m], b[n], acc[m][n], 0, 0, 0);
    }

    #pragma unroll
    for (int m = 0; m < 4; ++m) {
        #pragma unroll
        for (int r = 0; r < 4; ++r) {
            int row = row0 + wr * 64 + m * 16 + (lane >> 4) * 4 + r;
            float s = rs[row];
            #pragma unroll
            for (int n = 0; n < 4; ++n) {
                int col = col0 + wc * 64 + n * 16 + (lane & 15);
                C[(size_t)row * N + col] = f2bf_rne(acc[m][n][r] * s);
            }
        }
    }
}

// masking body
__device__ __forceinline__ void mask_body(
    const float* __restrict__ bd, const float* __restrict__ mp,
    unsigned short* __restrict__ safe_bf, float* __restrict__ stoch_out,
    unsigned long long* __restrict__ mask64, int bid, int tid)
{
    int idx = bid * 256 + tid;
    float x = bd[idx];
    float p = mp[idx];
    unsigned xb = __float_as_uint(x);
    bool valid = ((xb & 0x7fffffffu) <= 0x7f800000u);
    bool st = (p < 0.3f) && valid;
    bool sv = valid && !st;
    safe_bf[idx] = sv ? f2bf_rne(x) : 0;
    stoch_out[idx] = st ? 1.0f : 0.0f;
    unsigned long long m = __ballot(sv);
    if ((tid & 63) == 0) mask64[idx >> 6] = m;
}

// pooled body
__device__ __forceinline__ void pooled_body(
    unsigned short* __restrict__ smem,
    const float* __restrict__ E, const float* __restrict__ W_sap,
    const float* __restrict__ b_sap, float* __restrict__ pooled, int bid, int tid)
{
    float* colmean = (float*)smem;          // 768 f32
    float* red = colmean + Sz;              // 4*64 f32
    for (int s = tid; s < Sz; s += 256) {
        float a = 0.0f;
        #pragma unroll 8
        for (int f = 0; f < Fz; ++f) a += E[(size_t)f * Sz + s];
        colmean[s] = a * (1.0f / 64.0f);
    }
    __syncthreads();
    const int hl = tid & 63, sg = tid >> 6;
    const int h = bid * 64 + hl;
    float acc = 0.0f;
    #pragma unroll 4
    for (int s = sg; s < Sz; s += 4)
        acc = fmaf(colmean[s], W_sap[(size_t)s * Hz + h], acc);
    red[sg * 64 + hl] = acc;
    __syncthreads();
    if (sg == 0)
        pooled[h] = b_sap[h] + ((red[hl] + red[64 + hl]) + (red[128 + hl] + red[192 + hl]));
}

// wbuild body: sel[bt][16] u64 + inv_cnt. Block = 16 bt.
__device__ __forceinline__ void wbuild_body(
    unsigned short* __restrict__ smem,
    const unsigned long long* __restrict__ mask64,
    const unsigned int* __restrict__ plist,
    unsigned long long* __restrict__ sel, float* __restrict__ inv_cnt,
    int bid, int tid)
{
    unsigned int* pl = (unsigned int*)smem;
    for (int i = tid; i < NPAIRPAD; i += 256) pl[i] = plist[1 + i];
    __syncthreads();
    const int np = (int)plist[0];
    const int btl = tid >> 4, w = tid & 15;
    const int bt = bid * 16 + btl;
    unsigned long long m = mask64[bt];
    unsigned long long word = 0ull;
    int pbase = w * 64;
    int jmax = min(64, np - pbase);
    for (int j = 0; j < jmax; ++j) {
        unsigned ij = pl[pbase + j];
        unsigned long long bit = (m >> (ij >> 6)) & (m >> (ij & 63)) & 1ull;
        word |= bit << j;
    }
    sel[(size_t)bt * 16 + w] = word;
    int c = __popcll(word);
    #pragma unroll
    for (int s = 1; s < 16; s <<= 1) c += __shfl_xor(c, s);
    if (w == 0) inv_cnt[bt] = c > 0 ? 1.0f / (float)c : 0.0f;
}

// pebuild body
__device__ __forceinline__ void pebuild_body(
    const float* __restrict__ pair_emb, const unsigned int* __restrict__ plist,
    unsigned short* __restrict__ PeT, int p, int t)
{
    int np = (int)plist[0];
    if (p < np) {
        unsigned ij = plist[1 + p];
        const float* src = pair_emb + (size_t)ij * Dz;
        #pragma unroll
        for (int c = 0; c < 3; ++c)
            PeT[(size_t)(t + c * 256) * NPAIRPAD + p] = f2bf_rne(src[t + c * 256]);
    } else {
        #pragma unroll
        for (int c = 0; c < 3; ++c)
            PeT[(size_t)(t + c * 256) * NPAIRPAD + p] = 0;
    }
}

// meanheads body
__device__ __forceinline__ void meanheads_body(
    const unsigned short* __restrict__ probs, float* __restrict__ out3,
    int bid, int tid)
{
    int idx = bid * 256 + tid;
    int tk8 = idx & 31;
    int btq = idx >> 5;
    int b = btq >> 8, tq = btq & 255;
    float acc[8] = {};
    #pragma unroll
    for (int h = 0; h < 4; ++h) {
        int bh = b * 4 + h;
        ushort8v p = *(const ushort8v*)&probs[(((size_t)bh * Tz + tq) << 8) + tk8 * 8];
        #pragma unroll
        for (int j = 0; j < 8; ++j) acc[j] += bf2f(p[j]) * 0.25f;
    }
    float* dst = out3 + ((size_t)btq << 8) + tk8 * 8;
    float4 o0 = {acc[0], acc[1], acc[2], acc[3]};
    float4 o1 = {acc[4], acc[5], acc[6], acc[7]};
    *(float4*)dst = o0;
    *(float4*)(dst + 4) = o1;
}

// final body: out = qBF @ WoutT^T + pvb @ WWT^T + bocomb.
__device__ __forceinline__ void final_body(
    unsigned short* __restrict__ smem,
    const unsigned short* __restrict__ qBF, const unsigned short* __restrict__ pvb,
    const unsigned short* __restrict__ WoutT, const unsigned short* __restrict__ WWT,
    const float* __restrict__ bias, float* __restrict__ C, int bid, int tid)
{
    unsigned short* As = smem;
    unsigned short* Bs = smem + 64 * 40;
    const int lane = tid & 63, wave = tid >> 6;
    const int l15 = lane & 15, g = lane >> 4;
    const int row0 = bid * 64;

    f32x4 acc[4] = {};

    for (int ph = 0; ph < 2; ++ph) {
        const unsigned short* Am = ph == 0 ? qBF : pvb;
        const unsigned short* Bm = ph == 0 ? WoutT : WWT;
        for (int k0 = 0; k0 < 256; k0 += 32) {
            __syncthreads();
            {
                int r = tid >> 2, c8 = tid & 3;
                *(ushort8v*)(As + r * 40 + c8 * 8) =
                    *(const ushort8v*)(Am + (size_t)(row0 + r) * Hz + k0 + c8 * 8);
                *(ushort8v*)(Bs + r * 40 + c8 * 8) =
                    *(const ushort8v*)(Bm + (size_t)r * Hz + k0 + c8 * 8);
            }
            __syncthreads();
            short8v a = *(const short8v*)(As + (wave * 16 + l15) * 40 + g * 8);
            #pragma unroll
            for (int n = 0; n < 4; ++n) {
                short8v bn = *(const short8v*)(Bs + (n * 16 + l15) * 40 + g * 8);
                acc[n] = __builtin_amdgcn_mfma_f32_16x16x32_bf16(a, bn, acc[n], 0, 0, 0);
            }
        }
    }

    #pragma unroll
    for (int rr = 0; rr < 4; ++rr) {
        int row = row0 + wave * 16 + g * 4 + rr;
        #pragma unroll
        for (int n = 0; n < 4; ++n) {
            int col = n * 16 + l15;
            C[(size_t)row * Fz + col] = acc[n][rr] + bias[col];
        }
    }
}

// ===========================================================================
// Kernels
// ===========================================================================

// prep: weight transposes + pairlist + bocomb + bkv + WadB.
__device__ inline void transpose_tile2(const float* __restrict__ in,
                                       unsigned short* __restrict__ out,
                                       int R, int C, int bx, int by, int tid)
{
    __shared__ float t[32][33];
    const int c0 = bx * 32, r0 = by * 32;
    const int lc = tid & 31, lr8 = tid >> 5;
    #pragma unroll
    for (int i = 0; i < 4; ++i) {
        int r = lr8 + i * 8;
        t[r][lc] = in[(size_t)(r0 + r) * C + c0 + lc];
    }
    __syncthreads();
    #pragma unroll
    for (int i = 0; i < 4; ++i) {
        int oc = lr8 + i * 8;
        out[(size_t)(c0 + oc) * R + r0 + lc] = f2bf_rne(t[lc][oc]);
    }
}

__global__ __launch_bounds__(256) void prep_kernel(
    const float* __restrict__ W_num, const float* __restrict__ W_ad,
    const float* __restrict__ Wq, const float* __restrict__ Wk,
    const float* __restrict__ Wv, const float* __restrict__ Wo,
    const float* __restrict__ W_out, const float* __restrict__ bo,
    const float* __restrict__ b_out, const float* __restrict__ b_ad,
    const float* __restrict__ bk, const float* __restrict__ bv,
    const int* __restrict__ present,
    unsigned short* __restrict__ WnumT, unsigned short* __restrict__ WadT,
    unsigned short* __restrict__ WqT, unsigned short* __restrict__ WkT,
    unsigned short* __restrict__ WvT, unsigned short* __restrict__ WoT,
    unsigned short* __restrict__ WoutT, float* __restrict__ bocomb,
    float* __restrict__ bkv, unsigned short* __restrict__ WadB,
    unsigned int* __restrict__ plist)
{
    const int bid = blockIdx.x;
    const int tid = threadIdx.x;
    if (bid < 16) {
        transpose_tile2(W_num, WnumT, Fz, Hz, bid & 7, bid >> 3, tid);
    } else if (bid < 208) {
        int lid = bid - 16;
        transpose_tile2(W_ad, WadT, Dz, Hz, lid & 7, lid >> 3, tid);
    } else if (bid < 464) {
        int lid = bid - 208;
        int which = lid >> 6, t8 = lid & 63;
        const float* in = which == 0 ? Wq : which == 1 ? Wk : which == 2 ? Wv : Wo;
        unsigned short* out = which == 0 ? WqT : which == 1 ? WkT : which == 2 ? WvT : WoT;
        transpose_tile2(in, out, Hz, Hz, t8 & 7, t8 >> 3, tid);
    } else if (bid < 480) {
        int lid = bid - 464;
        transpose_tile2(W_out, WoutT, Hz, Fz, lid & 1, lid >> 1, tid);
    } else if (bid == 480) {              // pairlist
        __shared__ int cnt[64];
        __shared__ int off[64];
        int i = tid;
        if (i < 64) {
            int c = 0;
            for (int j = i + 1; j < 64; ++j)
                if (present[i * 64 + j] != 0) c++;
            cnt[i] = c;
        }
        __syncthreads();
        if (i == 0) {
            int t = 0;
            for (int r = 0; r < 64; ++r) { off[r] = t; t += cnt[r]; }
            plist[0] = (unsigned)t;
        }
        __syncthreads();
        if (i < 64) {
            int o = 1 + off[i];
            for (int j = i + 1; j < 64; ++j)
                if (present[i * 64 + j] != 0) plist[o++] = (unsigned)(i * 64 + j);
        }
    } else if (bid == 481) {              // bocomb
        int c = tid;
        if (c < 64) {
            float a = b_out[c];
            for (int j = 0; j < 256; ++j) a = fmaf(bo[j], W_out[(size_t)j * 64 + c], a);
            bocomb[c] = a;
        }
    } else if (bid < 484) {               // bkv
        int c = tid;
        const float* Wx = (bid == 482) ? Wk : Wv;
        const float* bx = (bid == 482) ? bk : bv;
        float a = bx[c];
        for (int j = 0; j < 256; ++j) a = fmaf(b_ad[j], Wx[(size_t)j * Hz + c], a);
        bkv[(bid - 482) * 256 + c] = a;
    } else {                              // WadB bf16 copy
        int lid = bid - 484;
        int base = lid * 1024 + tid * 4;
        #pragma unroll
        for (int j = 0; j < 4; ++j) WadB[base + j] = f2bf_rne(W_ad[base + j]);
    }
}

// combo1: WoWoutT(2) | WadkvT(24) | pooled2(4) | mask(2048)
__global__ __launch_bounds__(256) void combo1_kernel(
    const unsigned short* __restrict__ WoutT, const unsigned short* __restrict__ WoT,
    unsigned short* __restrict__ WoWoutT,
    const unsigned short* __restrict__ WkT, const unsigned short* __restrict__ WadB,
    unsigned short* __restrict__ WadkvT,
    const float* __restrict__ sapE, const float* __restrict__ W_sap,
    const float* __restrict__ b_sap, float* __restrict__ pooled,
    const float* __restrict__ batch_data, const float* __restrict__ mask_probs,
    unsigned short* __restrict__ safe_bf, float* __restrict__ stoch_out,
    unsigned long long* __restrict__ mask64)
{
    __shared__ unsigned short smem[10240];   // 20 KB
    const int bid = blockIdx.x;
    const int tid = threadIdx.x;
    if (bid < 2) {
        gemm2_body<64, 128, true, 3>(smem, WoutT, WoT, nullptr, nullptr,
                                     WoWoutT, 64, Hz, Hz, bid, 0, tid);
    } else if (bid < 26) {
        int lid = bid - 2;
        gemm2_body<128, 128, true, 3>(smem, WkT, WadB, nullptr, nullptr,
                                      WadkvT, 512, Dz, Hz, lid % 6, lid / 6, tid);
    } else if (bid < 30) {
        pooled_body(smem, sapE, W_sap, b_sap, pooled, bid - 26, tid);
    } else {
        mask_body(batch_data, mask_probs, safe_bf, stoch_out, mask64, bid - 30, tid);
    }
}

// combo2: queryGEMM(128) | wbuild(512) | pebuild(1024)
__global__ __launch_bounds__(256) void combo2_kernel(
    const unsigned short* __restrict__ safe_bf, const unsigned short* __restrict__ WnumT,
    const float* __restrict__ b_num, const float* __restrict__ pooled,
    unsigned short* __restrict__ qBF,
    const unsigned long long* __restrict__ mask64, const unsigned int* __restrict__ plist,
    unsigned long long* __restrict__ sel, float* __restrict__ inv_cnt,
    const float* __restrict__ pair_emb, unsigned short* __restrict__ PeT)
{
    __shared__ unsigned short smem[10240];
    const int bid = blockIdx.x;
    const int tid = threadIdx.x;
    if (bid < 128) {
        gemm2_body<128, 128, true, 1>(smem, safe_bf, WnumT, b_num, pooled,
                                      qBF, BTz, Hz, Fz, bid & 1, bid >> 1, tid);
    } else if (bid < 640) {
        wbuild_body(smem, mask64, plist, sel, inv_cnt, bid - 128, tid);
    } else {
        pebuild_body(pair_emb, plist, PeT, bid - 640, tid);
    }
}

// combo3: selGEMM(384) | qproj(128)
__global__ __launch_bounds__(256) void combo3_kernel(
    const unsigned long long* __restrict__ sel, const unsigned short* __restrict__ PeT,
    const float* __restrict__ inv_cnt, unsigned short* __restrict__ ctxb,
    const unsigned short* __restrict__ qBF, const unsigned short* __restrict__ WqT,
    const float* __restrict__ bq, unsigned short* __restrict__ qbb)
{
    __shared__ unsigned short smem[10240];
    const int bid = blockIdx.x;
    const int tid = threadIdx.x;
    if (bid < 384) {
        gemm_sel_body(smem, sel, PeT, inv_cnt, ctxb, BTz, Dz, NPAIRPAD,
                      bid % 6, bid / 6, tid);
    } else {
        int lid = bid - 384;
        gemm2_body<128, 128, true, 0>(smem, qBF, WqT, bq, nullptr,
                                      qbb, BTz, Hz, Hz, lid & 1, lid >> 1, tid);
    }
}

// kvproj GEMM (standalone): ctx @ WadkvT^T + bkv -> kvproj [8192][512]
__global__ __launch_bounds__(256) void kvproj_kernel(
    const unsigned short* __restrict__ ctxb, const unsigned short* __restrict__ WadkvT,
    const float* __restrict__ bkv, unsigned short* __restrict__ kvproj)
{
    __shared__ unsigned short smem[64 * 40 + 256 * 40];
    gemm2_body<64, 256, true, 0>(smem, ctxb, WadkvT, bkv, nullptr,
                                 kvproj, BTz, 512, Dz, blockIdx.x & 1, blockIdx.x >> 1,
                                 threadIdx.x);
}

// Fused attention: QK^T -> softmax -> PV (PV in 64-key chunks).
__global__ __launch_bounds__(256) void attn_fused_kernel(
    const unsigned short* __restrict__ q, const unsigned short* __restrict__ kp,
    unsigned short* __restrict__ probs, unsigned short* __restrict__ pv)
{
    int blk = blockIdx.x;
    int bh = blk >> 1, half = blk & 1;
    int b = bh >> 2, h = bh & 3;
    __shared__ unsigned short smem[128 * QKPAD + 256 * QKPAD];
    unsigned short* Ql = smem;
    unsigned short* Kl = smem + 128 * QKPAD;
    const int tid = threadIdx.x;

    const unsigned short* qbase = q + (size_t)(b * Tz + half * 128) * Hz + h * HDz;
    #pragma unroll
    for (int i = 0; i < 4; ++i) {
        int e = tid + i * 256;
        int r = e >> 3, c8 = e & 7;
        *(ushort8v*)&Ql[r * QKPAD + c8 * 8] =
            *(const ushort8v*)(qbase + (size_t)r * Hz + c8 * 8);
    }
    const unsigned short* kbase = kp + (size_t)(b * Tz) * 512 + h * HDz;
    #pragma unroll
    for (int i = 0; i < 8; ++i) {
        int e = tid + i * 256;
        int r = e >> 3, c8 = e & 7;
        *(ushort8v*)&Kl[r * QKPAD + c8 * 8] =
            *(const ushort8v*)(kbase + (size_t)r * 512 + c8 * 8);
    }
    __syncthreads();

    const int lane = tid & 63, wave = tid >> 6;
    const int l15 = lane & 15, g = lane >> 4;

    f32x4 acc[2][16] = {};
    #pragma unroll
    for (int ks = 0; ks < 2; ++ks) {
        short8v a0 = *(const short8v*)&Ql[(wave * 32 + l15) * QKPAD + ks * 32 + g * 8];
        short8v a1 = *(const short8v*)&Ql[(wave * 32 + 16 + l15) * QKPAD + ks * 32 + g * 8];
        #pragma unroll
        for (int n = 0; n < 16; ++n) {
            short8v bn = *(const short8v*)&Kl[(n * 16 + l15) * QKPAD + ks * 32 + g * 8];
            acc[0][n] = __builtin_amdgcn_mfma_f32_16x16x32_bf16(a0, bn, acc[0][n], 0, 0, 0);
            acc[1][n] = __builtin_amdgcn_mfma_f32_16x16x32_bf16(a1, bn, acc[1][n], 0, 0, 0);
        }
    }

    #pragma unroll
    for (int m = 0; m < 2; ++m) {
        #pragma unroll
        for (int rr = 0; rr < 4; ++rr) {
            float mx = -1e30f;
            #pragma unroll
            for (int n = 0; n < 16; ++n) mx = fmaxf(mx, acc[m][n][rr]);
            #pragma unroll
            for (int s = 1; s < 16; s <<= 1) mx = fmaxf(mx, __shfl_xor(mx, s));
            float sum = 0.0f;
            #pragma unroll
            for (int n = 0; n < 16; ++n) {
                float e = __expf(0.125f * (acc[m][n][rr] - mx));
                acc[m][n][rr] = e;
                sum += e;
            }
            #pragma unroll
            for (int s = 1; s < 16; s <<= 1) sum += __shfl_xor(sum, s);
            float inv = 1.0f / sum;
            int row = half * 128 + wave * 32 + m * 16 + g * 4 + rr;
            unsigned short* dst = probs + ((size_t)bh * Tz + row) * Tz;
            #pragma unroll
            for (int n = 0; n < 16; ++n) {
                float p = acc[m][n][rr] * inv;
                acc[m][n][rr] = p;
                dst[n * 16 + l15] = f2bf_rne(p);
            }
        }
    }
    __syncthreads();

    unsigned short* Vt = smem;                 // [64][VTPAD]
    unsigned short* Pl = smem + 64 * VTPAD;    // [128][PLPAD=72]
    const unsigned short* vbase = kp + (size_t)(b * Tz) * 512 + 256 + h * HDz;
    #pragma unroll
    for (int i = 0; i < 8; ++i) {
        int e = tid + i * 256;
        int key = e >> 3, c8 = e & 7;
        ushort8v v8 = *(const ushort8v*)(vbase + (size_t)key * 512 + c8 * 8);
        #pragma unroll
        for (int j = 0; j < 8; ++j)
            Vt[(c8 * 8 + j) * VTPAD + key] = v8[j];
    }

    f32x4 accpv[2][4] = {};
    for (int ks = 0; ks < 4; ++ks) {          // 64-key chunks
        #pragma unroll
        for (int m = 0; m < 2; ++m) {
            #pragma unroll
            for (int rr = 0; rr < 4; ++rr) {
                int row = wave * 32 + m * 16 + g * 4 + rr;
                #pragma unroll
                for (int j = 0; j < 4; ++j)
                    Pl[row * PLPAD + j * 16 + l15] = f2bf_rne(acc[m][4 * ks + j][rr]);
            }
        }
        __syncthreads();   // Vt ready (1st iter) + Pl ready
        #pragma unroll
        for (int kk = 0; kk < 2; ++kk) {
            short8v a0 = *(const short8v*)&Pl[(wave * 32 + l15) * PLPAD + kk * 32 + g * 8];
            short8v a1 = *(const short8v*)&Pl[(wave * 32 + 16 + l15) * PLPAD + kk * 32 + g * 8];
            #pragma unroll
            for (int n = 0; n < 4; ++n) {
                short8v bn = *(const short8v*)&Vt[(n * 16 + l15) * VTPAD + ks * 64 + kk * 32 + g * 8];
                accpv[0][n] = __builtin_amdgcn_mfma_f32_16x16x32_bf16(a0, bn, accpv[0][n], 0, 0, 0);
                accpv[1][n] = __builtin_amdgcn_mfma_f32_16x16x32_bf16(a1, bn, accpv[1][n], 0, 0, 0);
            }
        }
        __syncthreads();
    }

    #pragma unroll
    for (int m = 0; m < 2; ++m) {
        #pragma unroll
        for (int rr = 0; rr < 4; ++rr) {
            int row = b * Tz + half * 128 + wave * 32 + m * 16 + g * 4 + rr;
            #pragma unroll
            for (int n = 0; n < 4; ++n)
                pv[(size_t)row * Hz + h * HDz + n * 16 + l15] = f2bf_rne(accpv[m][n][rr]);
        }
    }
}

// combo4: meanheads(1024) | final(128)
__global__ __launch_bounds__(256) void combo4_kernel(
    const unsigned short* __restrict__ probs, float* __restrict__ out_attn,
    const unsigned short* __restrict__ qBF, const unsigned short* __restrict__ pvb,
    const unsigned short* __restrict__ WoutT, const unsigned short* __restrict__ WoWoutT,
    const float* __restrict__ bocomb, float* __restrict__ out_imputed)
{
    __shared__ unsigned short smem[5120];
    const int bid = blockIdx.x;
    const int tid = threadIdx.x;
    if (bid < 1024) {
        meanheads_body(probs, out_attn, bid, tid);
    } else {
        final_body(smem, qBF, pvb, WoutT, WoWoutT, bocomb, out_imputed, bid - 1024, tid);
    }
}

// ---------------------------------------------------------------------------
extern "C" void kernel_launch(void* const* d_in, const int* in_sizes, int n_in,
                              void* d_out, int out_size, void* d_ws, size_t ws_size,
                              hipStream_t stream)
{
    const float* batch_data = (const float*)d_in[0];
    const float* mask_probs = (const float*)d_in[1];
    const float* sapE       = (const float*)d_in[2];
    const float* pair_emb   = (const float*)d_in[3];
    const int*   pair_present = (const int*)d_in[4];
    const float* W_num = (const float*)d_in[5];  const float* b_num = (const float*)d_in[6];
    const float* W_sap = (const float*)d_in[7];  const float* b_sap = (const float*)d_in[8];
    const float* W_ad  = (const float*)d_in[9];  const float* b_ad  = (const float*)d_in[10];
    const float* Wq = (const float*)d_in[11]; const float* bq = (const float*)d_in[12];
    const float* Wk = (const float*)d_in[13]; const float* bk = (const float*)d_in[14];
    const float* Wv = (const float*)d_in[15]; const float* bv = (const float*)d_in[16];
    const float* Wo = (const float*)d_in[17]; const float* bo = (const float*)d_in[18];
    const float* W_out = (const float*)d_in[19]; const float* b_out = (const float*)d_in[20];

    float* out = (float*)d_out;
    float* out_imputed = out;                 // [B,T,F]
    float* out_stoch   = out + 524288;        // [B,T,F]
    float* out_attn    = out + 1048576;       // [B,T,T]

    float* ws = (float*)d_ws;
    unsigned short* safe_bf = (unsigned short*)ws;             // bf16 [8192][64]
    unsigned short* qBF   = (unsigned short*)(ws + 524288);    // bf16 [8192][256]
    unsigned short* probs = (unsigned short*)(ws + 2621440);   // bf16 [128][256][256]
    unsigned short* ctxb  = (unsigned short*)(ws + 6815744);   // bf16 [8192][768]
    unsigned long long* sel = (unsigned long long*)(ws + 9961472); // u64 [8192][16]
    unsigned short* qbb   = (unsigned short*)(ws + 11010048);  // bf16 [8192][256]
    unsigned short* PeT   = (unsigned short*)(ws + 15204352);  // bf16 [768][1024] (dead after combo3)
    float* inv_cnt        = ws + 15204352 + 393216;            // 8192 f32 (consumed combo3)
    unsigned short* kvproj = (unsigned short*)(ws + 15204352); // bf16 [8192][512] (over dead PeT)
    unsigned short* pvb   = (unsigned short*)(ws + 17301504);  // bf16 [8192][256]
    unsigned short* WoWoutT = (unsigned short*)(ws + 18350080);// bf16 [64][256]
    float* bocomb = ws + 18358272;                             // 64 f32
    float* bkv    = ws + 18358336;                             // 512 f32
    unsigned short* WadkvT = (unsigned short*)(ws + 18358848); // bf16 [512][768]
    unsigned short* WadB   = (unsigned short*)(ws + 18555456); // bf16 [768][256]
    float* pooled = ws + 19398656;
    unsigned long long* mask64 = (unsigned long long*)(ws + 19398912);
    unsigned int* plist = (unsigned int*)(ws + 19415296);

    unsigned short* wT = (unsigned short*)(ws + 19419392);
    unsigned short* WnumT = wT;                  // [256][64]
    unsigned short* WadT  = wT + 16384;          // [256][768]
    unsigned short* WqT   = wT + 212992;         // [256][256]
    unsigned short* WkT   = wT + 278528;         // (WkT,WvT contiguous)
    unsigned short* WvT   = wT + 344064;
    unsigned short* WoT   = wT + 409600;
    unsigned short* WoutT = wT + 475136;         // [64][256]

    // 1. prep
    prep_kernel<<<676, 256, 0, stream>>>(
        W_num, W_ad, Wq, Wk, Wv, Wo, W_out, bo, b_out, b_ad, bk, bv, pair_present,
        WnumT, WadT, WqT, WkT, WvT, WoT, WoutT, bocomb, bkv, WadB, plist);
    // 2. combo1: WoWoutT | WadkvT | pooled | mask
    combo1_kernel<<<2078, 256, 0, stream>>>(
        WoutT, WoT, WoWoutT, WkT, WadB, WadkvT,
        sapE, W_sap, b_sap, pooled,
        batch_data, mask_probs, safe_bf, out_stoch, mask64);
    // 3. combo2: query GEMM | wbuild | pebuild
    combo2_kernel<<<1664, 256, 0, stream>>>(
        safe_bf, WnumT, b_num, pooled, qBF,
        mask64, plist, sel, inv_cnt, pair_emb, PeT);
    // 4. combo3: sel GEMM | q projection
    combo3_kernel<<<512, 256, 0, stream>>>(
        sel, PeT, inv_cnt, ctxb, qBF, WqT, bq, qbb);
    // 5. kvproj
    kvproj_kernel<<<dim3(256), 256, 0, stream>>>(ctxb, WadkvT, bkv, kvproj);
    // 6. fused attention
    attn_fused_kernel<<<256, 256, 0, stream>>>(qbb, kvproj, probs, pvb);
    // 7. combo4: meanheads | final
    combo4_kernel<<<1152, 256, 0, stream>>>(
        probs, out_attn, qBF, pvb, WoutT, WoWoutT, bocomb, out_imputed);
}

// Round 11
// 123.709 us; speedup vs baseline: 10.3466x; 1.3659x over previous
//
#include <hip/hip_runtime.h>
#include <hip/hip_bf16.h>

// Shapes
#define Bz 32
#define Tz 256
#define Fz 64
#define Dz 768
#define Sz 768
#define Hz 256
#define NHz 4
#define HDz 64
#define BTz 8192  // B*T
#define NPAIRPAD 1024
#define QKPAD 72   // bf16 units; 144B row stride: 2-way bank alias (free)
#define VTPAD 264
#define PLPAD 72   // PV 64-key chunk

typedef __attribute__((ext_vector_type(8))) short short8v;
typedef __attribute__((ext_vector_type(8))) unsigned short ushort8v;
typedef __attribute__((ext_vector_type(4))) float f32x4;

__device__ inline unsigned short f2bf_rne(float x) {
    unsigned u = __float_as_uint(x);
    unsigned r = (u + 0x7fffu + ((u >> 16) & 1u)) >> 16;
    return (unsigned short)r;
}
__device__ inline float bf2f(unsigned short x) {
    return __uint_as_float(((unsigned)x) << 16);
}

// ===========================================================================
// Device bodies
// ===========================================================================

// Unified MFMA GEMM body. A: bf16 [M][K]. Bt: bf16 [N][K]. Out f32/bf16.
// B2MODE: 0=bias, 1=bias+bias2, 2=concat, 3=no bias.
template <int BM, int BN, bool OUTBF16, int B2MODE>
__device__ __forceinline__ void gemm2_body(
    unsigned short* __restrict__ smem,
    const unsigned short* __restrict__ A,
    const unsigned short* __restrict__ Bt,
    const float* __restrict__ bias, const float* __restrict__ bias2,
    void* __restrict__ Cv, int M, int N, int K, int bx, int by, int tid)
{
    constexpr int WC = BN / 64;
    constexpr int WR = 4 / WC;
    constexpr int RW = BM / WR;
    constexpr int MT = RW / 16;
    constexpr int NT = 4;
    unsigned short* As = smem;
    unsigned short* Bs = smem + BM * 40;
    const int lane = tid & 63, wave = tid >> 6;
    const int l15 = lane & 15, g = lane >> 4;
    const int wr = wave / WC, wc = wave % WC;
    const int row0 = by * BM, col0 = bx * BN;

    f32x4 acc[MT][NT] = {};

    for (int k0 = 0; k0 < K; k0 += 32) {
        __syncthreads();
        #pragma unroll
        for (int i = 0; i < BM * 4 / 256; ++i) {
            int e = tid + i * 256;
            int r = e >> 2, c8 = e & 3;
            *(ushort8v*)(As + r * 40 + c8 * 8) =
                *(const ushort8v*)(A + (size_t)(row0 + r) * K + k0 + c8 * 8);
        }
        #pragma unroll
        for (int i = 0; i < BN * 4 / 256; ++i) {
            int e = tid + i * 256;
            int n = e >> 2, c = e & 3;
            *(ushort8v*)(Bs + n * 40 + c * 8) =
                *(const ushort8v*)(Bt + (size_t)(col0 + n) * K + k0 + c * 8);
        }
        __syncthreads();

        short8v a[MT], b[NT];
        #pragma unroll
        for (int m = 0; m < MT; ++m)
            a[m] = *(const short8v*)(As + (wr * RW + m * 16 + l15) * 40 + g * 8);
        #pragma unroll
        for (int n = 0; n < NT; ++n)
            b[n] = *(const short8v*)(Bs + (wc * 64 + n * 16 + l15) * 40 + g * 8);
        #pragma unroll
        for (int m = 0; m < MT; ++m)
            #pragma unroll
            for (int n = 0; n < NT; ++n)
                acc[m][n] = __builtin_amdgcn_mfma_f32_16x16x32_bf16(a[m], b[n], acc[m][n], 0, 0, 0);
    }

    #pragma unroll
    for (int m = 0; m < MT; ++m) {
        #pragma unroll
        for (int rr = 0; rr < 4; ++rr) {
            int row = row0 + wr * RW + m * 16 + g * 4 + rr;
            #pragma unroll
            for (int n = 0; n < NT; ++n) {
                int col = col0 + wc * 64 + n * 16 + l15;
                float o = acc[m][n][rr];
                if (B2MODE == 2) {
                    o += (col < (N >> 1)) ? bias[col] : bias2[col - (N >> 1)];
                } else if (B2MODE != 3) {
                    o += bias[col];
                    if (B2MODE == 1) o += bias2[col];
                }
                if (OUTBF16) ((unsigned short*)Cv)[(size_t)row * N + col] = f2bf_rne(o);
                else         ((float*)Cv)[(size_t)row * N + col] = o;
            }
        }
    }
}

// selkv GEMM body: kvproj = inv_cnt ⊙ (Sel-bits @ PeWaT^T) + bkv.
// BM=64, BN=128, K=1024. A expanded in-LDS from sel bits (0/1 bf16).
__device__ __forceinline__ void gemm_selkv_body(
    unsigned short* __restrict__ smem,
    const unsigned long long* __restrict__ sel,
    const unsigned short* __restrict__ Bt,     // PeWaT [512][1024]
    const float* __restrict__ rs,              // inv_cnt [8192]
    const float* __restrict__ bias,            // bkv [512]
    unsigned short* __restrict__ C,            // kvproj [8192][512]
    int bx, int by, int tid)
{
    unsigned short* As = smem;               // [64][40]
    unsigned short* Bs = smem + 64 * 40;     // [128][40]
    const int lane = tid & 63, wave = tid >> 6;
    const int l15 = lane & 15, g = lane >> 4;
    const int wr = wave >> 1, wc = wave & 1;
    const int row0 = by * 64, col0 = bx * 128;

    f32x4 acc[2][4] = {};

    for (int k0 = 0; k0 < 1024; k0 += 32) {
        __syncthreads();
        {   // A-expand: 64 rows x 32 sel bits -> 0/1 bf16
            int r = tid >> 2, q = tid & 3;
            unsigned long long w = sel[(size_t)(row0 + r) * 16 + (k0 >> 6)];
            unsigned bits = (unsigned)(w >> ((k0 & 32) + q * 8)) & 0xFFu;
            unsigned short* dst = As + r * 40 + q * 8;
            unsigned long long pk0 = 0ull, pk1 = 0ull;
            if (bits & 1u)   pk0 |= 0x3f80ull;
            if (bits & 2u)   pk0 |= 0x3f80ull << 16;
            if (bits & 4u)   pk0 |= 0x3f80ull << 32;
            if (bits & 8u)   pk0 |= 0x3f80ull << 48;
            if (bits & 16u)  pk1 |= 0x3f80ull;
            if (bits & 32u)  pk1 |= 0x3f80ull << 16;
            if (bits & 64u)  pk1 |= 0x3f80ull << 32;
            if (bits & 128u) pk1 |= 0x3f80ull << 48;
            *(unsigned long long*)(dst) = pk0;
            *(unsigned long long*)(dst + 4) = pk1;
        }
        #pragma unroll
        for (int i = 0; i < 2; ++i) {   // B-stage: 128 cols x 32 k
            int e = tid + i * 256;
            int n = e >> 2, c = e & 3;
            *(ushort8v*)(Bs + n * 40 + c * 8) =
                *(const ushort8v*)(Bt + (size_t)(col0 + n) * 1024 + k0 + c * 8);
        }
        __syncthreads();

        short8v a[2], b[4];
        #pragma unroll
        for (int m = 0; m < 2; ++m)
            a[m] = *(const short8v*)(As + (wr * 32 + m * 16 + l15) * 40 + g * 8);
        #pragma unroll
        for (int n = 0; n < 4; ++n)
            b[n] = *(const short8v*)(Bs + (wc * 64 + n * 16 + l15) * 40 + g * 8);
        #pragma unroll
        for (int m = 0; m < 2; ++m)
            #pragma unroll
            for (int n = 0; n < 4; ++n)
                acc[m][n] = __builtin_amdgcn_mfma_f32_16x16x32_bf16(a[m], b[n], acc[m][n], 0, 0, 0);
    }

    #pragma unroll
    for (int m = 0; m < 2; ++m) {
        #pragma unroll
        for (int rr = 0; rr < 4; ++rr) {
            int row = row0 + wr * 32 + m * 16 + g * 4 + rr;
            float s = rs[row];
            #pragma unroll
            for (int n = 0; n < 4; ++n) {
                int col = col0 + wc * 64 + n * 16 + l15;
                C[(size_t)row * 512 + col] = f2bf_rne(acc[m][n][rr] * s + bias[col]);
            }
        }
    }
}

// masking body
__device__ __forceinline__ void mask_body(
    const float* __restrict__ bd, const float* __restrict__ mp,
    unsigned short* __restrict__ safe_bf, float* __restrict__ stoch_out,
    unsigned long long* __restrict__ mask64, int bid, int tid)
{
    int idx = bid * 256 + tid;
    float x = bd[idx];
    float p = mp[idx];
    unsigned xb = __float_as_uint(x);
    bool valid = ((xb & 0x7fffffffu) <= 0x7f800000u);
    bool st = (p < 0.3f) && valid;
    bool sv = valid && !st;
    safe_bf[idx] = sv ? f2bf_rne(x) : 0;
    stoch_out[idx] = st ? 1.0f : 0.0f;
    unsigned long long m = __ballot(sv);
    if ((tid & 63) == 0) mask64[idx >> 6] = m;
}

// pooled body
__device__ __forceinline__ void pooled_body(
    unsigned short* __restrict__ smem,
    const float* __restrict__ E, const float* __restrict__ W_sap,
    const float* __restrict__ b_sap, float* __restrict__ pooled, int bid, int tid)
{
    float* colmean = (float*)smem;          // 768 f32
    float* red = colmean + Sz;              // 4*64 f32
    for (int s = tid; s < Sz; s += 256) {
        float a = 0.0f;
        #pragma unroll 8
        for (int f = 0; f < Fz; ++f) a += E[(size_t)f * Sz + s];
        colmean[s] = a * (1.0f / 64.0f);
    }
    __syncthreads();
    const int hl = tid & 63, sg = tid >> 6;
    const int h = bid * 64 + hl;
    float acc = 0.0f;
    #pragma unroll 4
    for (int s = sg; s < Sz; s += 4)
        acc = fmaf(colmean[s], W_sap[(size_t)s * Hz + h], acc);
    red[sg * 64 + hl] = acc;
    __syncthreads();
    if (sg == 0)
        pooled[h] = b_sap[h] + ((red[hl] + red[64 + hl]) + (red[128 + hl] + red[192 + hl]));
}

// wbuild body: sel[bt][16] u64 + inv_cnt. Block = 16 bt.
__device__ __forceinline__ void wbuild_body(
    unsigned short* __restrict__ smem,
    const unsigned long long* __restrict__ mask64,
    const unsigned int* __restrict__ plist,
    unsigned long long* __restrict__ sel, float* __restrict__ inv_cnt,
    int bid, int tid)
{
    unsigned int* pl = (unsigned int*)smem;
    for (int i = tid; i < NPAIRPAD; i += 256) pl[i] = plist[1 + i];
    __syncthreads();
    const int np = (int)plist[0];
    const int btl = tid >> 4, w = tid & 15;
    const int bt = bid * 16 + btl;
    unsigned long long m = mask64[bt];
    unsigned long long word = 0ull;
    int pbase = w * 64;
    int jmax = min(64, np - pbase);
    for (int j = 0; j < jmax; ++j) {
        unsigned ij = pl[pbase + j];
        unsigned long long bit = (m >> (ij >> 6)) & (m >> (ij & 63)) & 1ull;
        word |= bit << j;
    }
    sel[(size_t)bt * 16 + w] = word;
    int c = __popcll(word);
    #pragma unroll
    for (int s = 1; s < 16; s <<= 1) c += __shfl_xor(c, s);
    if (w == 0) inv_cnt[bt] = c > 0 ? 1.0f / (float)c : 0.0f;
}

// pe body: gather pair_emb rows -> row-major bf16 Pe[1024][768].
__device__ __forceinline__ void pe_body(
    const float* __restrict__ pair_emb, const unsigned int* __restrict__ plist,
    unsigned short* __restrict__ Pe, int p, int t)
{
    int np = (int)plist[0];
    if (p < np) {
        unsigned ij = plist[1 + p];
        const float* src = pair_emb + (size_t)ij * Dz;
        #pragma unroll
        for (int c = 0; c < 3; ++c)
            Pe[(size_t)p * Dz + t + c * 256] = f2bf_rne(src[t + c * 256]);
    } else {
        #pragma unroll
        for (int c = 0; c < 3; ++c)
            Pe[(size_t)p * Dz + t + c * 256] = 0;
    }
}

// meanheads body
__device__ __forceinline__ void meanheads_body(
    const unsigned short* __restrict__ probs, float* __restrict__ out3,
    int bid, int tid)
{
    int idx = bid * 256 + tid;
    int tk8 = idx & 31;
    int btq = idx >> 5;
    int b = btq >> 8, tq = btq & 255;
    float acc[8] = {};
    #pragma unroll
    for (int h = 0; h < 4; ++h) {
        int bh = b * 4 + h;
        ushort8v p = *(const ushort8v*)&probs[(((size_t)bh * Tz + tq) << 8) + tk8 * 8];
        #pragma unroll
        for (int j = 0; j < 8; ++j) acc[j] += bf2f(p[j]) * 0.25f;
    }
    float* dst = out3 + ((size_t)btq << 8) + tk8 * 8;
    float4 o0 = {acc[0], acc[1], acc[2], acc[3]};
    float4 o1 = {acc[4], acc[5], acc[6], acc[7]};
    *(float4*)dst = o0;
    *(float4*)(dst + 4) = o1;
}

// final body: out = qBF @ WoutT^T + pvb @ WWT^T + bocomb.
__device__ __forceinline__ void final_body(
    unsigned short* __restrict__ smem,
    const unsigned short* __restrict__ qBF, const unsigned short* __restrict__ pvb,
    const unsigned short* __restrict__ WoutT, const unsigned short* __restrict__ WWT,
    const float* __restrict__ bias, float* __restrict__ C, int bid, int tid)
{
    unsigned short* As = smem;
    unsigned short* Bs = smem + 64 * 40;
    const int lane = tid & 63, wave = tid >> 6;
    const int l15 = lane & 15, g = lane >> 4;
    const int row0 = bid * 64;

    f32x4 acc[4] = {};

    for (int ph = 0; ph < 2; ++ph) {
        const unsigned short* Am = ph == 0 ? qBF : pvb;
        const unsigned short* Bm = ph == 0 ? WoutT : WWT;
        for (int k0 = 0; k0 < 256; k0 += 32) {
            __syncthreads();
            {
                int r = tid >> 2, c8 = tid & 3;
                *(ushort8v*)(As + r * 40 + c8 * 8) =
                    *(const ushort8v*)(Am + (size_t)(row0 + r) * Hz + k0 + c8 * 8);
                *(ushort8v*)(Bs + r * 40 + c8 * 8) =
                    *(const ushort8v*)(Bm + (size_t)r * Hz + k0 + c8 * 8);
            }
            __syncthreads();
            short8v a = *(const short8v*)(As + (wave * 16 + l15) * 40 + g * 8);
            #pragma unroll
            for (int n = 0; n < 4; ++n) {
                short8v bn = *(const short8v*)(Bs + (n * 16 + l15) * 40 + g * 8);
                acc[n] = __builtin_amdgcn_mfma_f32_16x16x32_bf16(a, bn, acc[n], 0, 0, 0);
            }
        }
    }

    #pragma unroll
    for (int rr = 0; rr < 4; ++rr) {
        int row = row0 + wave * 16 + g * 4 + rr;
        #pragma unroll
        for (int n = 0; n < 4; ++n) {
            int col = n * 16 + l15;
            C[(size_t)row * Fz + col] = acc[n][rr] + bias[col];
        }
    }
}

// ===========================================================================
// Kernels
// ===========================================================================

__device__ inline void transpose_tile2(const float* __restrict__ in,
                                       unsigned short* __restrict__ out,
                                       int R, int C, int bx, int by, int tid)
{
    __shared__ float t[32][33];
    const int c0 = bx * 32, r0 = by * 32;
    const int lc = tid & 31, lr8 = tid >> 5;
    #pragma unroll
    for (int i = 0; i < 4; ++i) {
        int r = lr8 + i * 8;
        t[r][lc] = in[(size_t)(r0 + r) * C + c0 + lc];
    }
    __syncthreads();
    #pragma unroll
    for (int i = 0; i < 4; ++i) {
        int oc = lr8 + i * 8;
        out[(size_t)(c0 + oc) * R + r0 + lc] = f2bf_rne(t[lc][oc]);
    }
}

__global__ __launch_bounds__(256) void prep_kernel(
    const float* __restrict__ W_num, const float* __restrict__ W_ad,
    const float* __restrict__ Wq, const float* __restrict__ Wk,
    const float* __restrict__ Wv, const float* __restrict__ Wo,
    const float* __restrict__ W_out, const float* __restrict__ bo,
    const float* __restrict__ b_out, const float* __restrict__ b_ad,
    const float* __restrict__ bk, const float* __restrict__ bv,
    const int* __restrict__ present,
    unsigned short* __restrict__ WnumT, unsigned short* __restrict__ WadT,
    unsigned short* __restrict__ WqT, unsigned short* __restrict__ WkT,
    unsigned short* __restrict__ WvT, unsigned short* __restrict__ WoT,
    unsigned short* __restrict__ WoutT, float* __restrict__ bocomb,
    float* __restrict__ bkv, unsigned short* __restrict__ WadB,
    unsigned int* __restrict__ plist)
{
    const int bid = blockIdx.x;
    const int tid = threadIdx.x;
    if (bid < 16) {
        transpose_tile2(W_num, WnumT, Fz, Hz, bid & 7, bid >> 3, tid);
    } else if (bid < 208) {
        int lid = bid - 16;
        transpose_tile2(W_ad, WadT, Dz, Hz, lid & 7, lid >> 3, tid);
    } else if (bid < 464) {
        int lid = bid - 208;
        int which = lid >> 6, t8 = lid & 63;
        const float* in = which == 0 ? Wq : which == 1 ? Wk : which == 2 ? Wv : Wo;
        unsigned short* out = which == 0 ? WqT : which == 1 ? WkT : which == 2 ? WvT : WoT;
        transpose_tile2(in, out, Hz, Hz, t8 & 7, t8 >> 3, tid);
    } else if (bid < 480) {
        int lid = bid - 464;
        transpose_tile2(W_out, WoutT, Hz, Fz, lid & 1, lid >> 1, tid);
    } else if (bid == 480) {              // pairlist
        __shared__ int cnt[64];
        __shared__ int off[64];
        int i = tid;
        if (i < 64) {
            int c = 0;
            for (int j = i + 1; j < 64; ++j)
                if (present[i * 64 + j] != 0) c++;
            cnt[i] = c;
        }
        __syncthreads();
        if (i == 0) {
            int t = 0;
            for (int r = 0; r < 64; ++r) { off[r] = t; t += cnt[r]; }
            plist[0] = (unsigned)t;
        }
        __syncthreads();
        if (i < 64) {
            int o = 1 + off[i];
            for (int j = i + 1; j < 64; ++j)
                if (present[i * 64 + j] != 0) plist[o++] = (unsigned)(i * 64 + j);
        }
    } else if (bid == 481) {              // bocomb
        int c = tid;
        if (c < 64) {
            float a = b_out[c];
            for (int j = 0; j < 256; ++j) a = fmaf(bo[j], W_out[(size_t)j * 64 + c], a);
            bocomb[c] = a;
        }
    } else if (bid < 484) {               // bkv
        int c = tid;
        const float* Wx = (bid == 482) ? Wk : Wv;
        const float* bx = (bid == 482) ? bk : bv;
        float a = bx[c];
        for (int j = 0; j < 256; ++j) a = fmaf(b_ad[j], Wx[(size_t)j * Hz + c], a);
        bkv[(bid - 482) * 256 + c] = a;
    } else {                              // WadB bf16 copy
        int lid = bid - 484;
        int base = lid * 1024 + tid * 4;
        #pragma unroll
        for (int j = 0; j < 4; ++j) WadB[base + j] = f2bf_rne(W_ad[base + j]);
    }
}

// combo1: WoWoutT(2) | WadkvT(24) | pooled2(4) | mask(2048) | pe(1024)
__global__ __launch_bounds__(256) void combo1_kernel(
    const unsigned short* __restrict__ WoutT, const unsigned short* __restrict__ WoT,
    unsigned short* __restrict__ WoWoutT,
    const unsigned short* __restrict__ WkT, const unsigned short* __restrict__ WadB,
    unsigned short* __restrict__ WadkvT,
    const float* __restrict__ sapE, const float* __restrict__ W_sap,
    const float* __restrict__ b_sap, float* __restrict__ pooled,
    const float* __restrict__ batch_data, const float* __restrict__ mask_probs,
    unsigned short* __restrict__ safe_bf, float* __restrict__ stoch_out,
    unsigned long long* __restrict__ mask64,
    const float* __restrict__ pair_emb, const unsigned int* __restrict__ plist,
    unsigned short* __restrict__ Pe)
{
    __shared__ unsigned short smem[10240];   // 20 KB
    const int bid = blockIdx.x;
    const int tid = threadIdx.x;
    if (bid < 2) {
        gemm2_body<64, 128, true, 3>(smem, WoutT, WoT, nullptr, nullptr,
                                     WoWoutT, 64, Hz, Hz, bid, 0, tid);
    } else if (bid < 26) {
        int lid = bid - 2;
        gemm2_body<128, 128, true, 3>(smem, WkT, WadB, nullptr, nullptr,
                                      WadkvT, 512, Dz, Hz, lid % 6, lid / 6, tid);
    } else if (bid < 30) {
        pooled_body(smem, sapE, W_sap, b_sap, pooled, bid - 26, tid);
    } else if (bid < 2078) {
        mask_body(batch_data, mask_probs, safe_bf, stoch_out, mask64, bid - 30, tid);
    } else {
        pe_body(pair_emb, plist, Pe, bid - 2078, tid);
    }
}

// combo2: queryGEMM(128) | wbuild(512) | PeWaT GEMM(32)
__global__ __launch_bounds__(256) void combo2_kernel(
    const unsigned short* __restrict__ safe_bf, const unsigned short* __restrict__ WnumT,
    const float* __restrict__ b_num, const float* __restrict__ pooled,
    unsigned short* __restrict__ qBF,
    const unsigned long long* __restrict__ mask64, const unsigned int* __restrict__ plist,
    unsigned long long* __restrict__ sel, float* __restrict__ inv_cnt,
    const unsigned short* __restrict__ WadkvT, const unsigned short* __restrict__ Pe,
    unsigned short* __restrict__ PeWaT)
{
    __shared__ unsigned short smem[10240];
    const int bid = blockIdx.x;
    const int tid = threadIdx.x;
    if (bid < 128) {
        gemm2_body<128, 128, true, 1>(smem, safe_bf, WnumT, b_num, pooled,
                                      qBF, BTz, Hz, Fz, bid & 1, bid >> 1, tid);
    } else if (bid < 640) {
        wbuild_body(smem, mask64, plist, sel, inv_cnt, bid - 128, tid);
    } else {
        int lid = bid - 640;   // 32 blocks: M=512 (by 0..3), N=1024 (bx 0..7)
        gemm2_body<128, 128, true, 3>(smem, WadkvT, Pe, nullptr, nullptr,
                                      PeWaT, 512, NPAIRPAD, Dz, lid & 7, lid >> 3, tid);
    }
}

// combo3: selkv GEMM(512) | qproj(128)
__global__ __launch_bounds__(256) void combo3_kernel(
    const unsigned long long* __restrict__ sel, const unsigned short* __restrict__ PeWaT,
    const float* __restrict__ inv_cnt, const float* __restrict__ bkv,
    unsigned short* __restrict__ kvproj,
    const unsigned short* __restrict__ qBF, const unsigned short* __restrict__ WqT,
    const float* __restrict__ bq, unsigned short* __restrict__ qbb)
{
    __shared__ unsigned short smem[10240];
    const int bid = blockIdx.x;
    const int tid = threadIdx.x;
    if (bid < 512) {
        gemm_selkv_body(smem, sel, PeWaT, inv_cnt, bkv, kvproj,
                        bid & 3, bid >> 2, tid);
    } else {
        int lid = bid - 512;
        gemm2_body<128, 128, true, 0>(smem, qBF, WqT, bq, nullptr,
                                      qbb, BTz, Hz, Hz, lid & 1, lid >> 1, tid);
    }
}

// Fused attention: QK^T -> softmax -> PV (PV in 64-key chunks).
__global__ __launch_bounds__(256) void attn_fused_kernel(
    const unsigned short* __restrict__ q, const unsigned short* __restrict__ kp,
    unsigned short* __restrict__ probs, unsigned short* __restrict__ pv)
{
    int blk = blockIdx.x;
    int bh = blk >> 1, half = blk & 1;
    int b = bh >> 2, h = bh & 3;
    __shared__ unsigned short smem[128 * QKPAD + 256 * QKPAD];
    unsigned short* Ql = smem;
    unsigned short* Kl = smem + 128 * QKPAD;
    const int tid = threadIdx.x;

    const unsigned short* qbase = q + (size_t)(b * Tz + half * 128) * Hz + h * HDz;
    #pragma unroll
    for (int i = 0; i < 4; ++i) {
        int e = tid + i * 256;
        int r = e >> 3, c8 = e & 7;
        *(ushort8v*)&Ql[r * QKPAD + c8 * 8] =
            *(const ushort8v*)(qbase + (size_t)r * Hz + c8 * 8);
    }
    const unsigned short* kbase = kp + (size_t)(b * Tz) * 512 + h * HDz;
    #pragma unroll
    for (int i = 0; i < 8; ++i) {
        int e = tid + i * 256;
        int r = e >> 3, c8 = e & 7;
        *(ushort8v*)&Kl[r * QKPAD + c8 * 8] =
            *(const ushort8v*)(kbase + (size_t)r * 512 + c8 * 8);
    }
    __syncthreads();

    const int lane = tid & 63, wave = tid >> 6;
    const int l15 = lane & 15, g = lane >> 4;

    f32x4 acc[2][16] = {};
    #pragma unroll
    for (int ks = 0; ks < 2; ++ks) {
        short8v a0 = *(const short8v*)&Ql[(wave * 32 + l15) * QKPAD + ks * 32 + g * 8];
        short8v a1 = *(const short8v*)&Ql[(wave * 32 + 16 + l15) * QKPAD + ks * 32 + g * 8];
        #pragma unroll
        for (int n = 0; n < 16; ++n) {
            short8v bn = *(const short8v*)&Kl[(n * 16 + l15) * QKPAD + ks * 32 + g * 8];
            acc[0][n] = __builtin_amdgcn_mfma_f32_16x16x32_bf16(a0, bn, acc[0][n], 0, 0, 0);
            acc[1][n] = __builtin_amdgcn_mfma_f32_16x16x32_bf16(a1, bn, acc[1][n], 0, 0, 0);
        }
    }

    #pragma unroll
    for (int m = 0; m < 2; ++m) {
        #pragma unroll
        for (int rr = 0; rr < 4; ++rr) {
            float mx = -1e30f;
            #pragma unroll
            for (int n = 0; n < 16; ++n) mx = fmaxf(mx, acc[m][n][rr]);
            #pragma unroll
            for (int s = 1; s < 16; s <<= 1) mx = fmaxf(mx, __shfl_xor(mx, s));
            float sum = 0.0f;
            #pragma unroll
            for (int n = 0; n < 16; ++n) {
                float e = __expf(0.125f * (acc[m][n][rr] - mx));
                acc[m][n][rr] = e;
                sum += e;
            }
            #pragma unroll
            for (int s = 1; s < 16; s <<= 1) sum += __shfl_xor(sum, s);
            float inv = 1.0f / sum;
            int row = half * 128 + wave * 32 + m * 16 + g * 4 + rr;
            unsigned short* dst = probs + ((size_t)bh * Tz + row) * Tz;
            #pragma unroll
            for (int n = 0; n < 16; ++n) {
                float p = acc[m][n][rr] * inv;
                acc[m][n][rr] = p;
                dst[n * 16 + l15] = f2bf_rne(p);
            }
        }
    }
    __syncthreads();

    unsigned short* Vt = smem;                 // [64][VTPAD]
    unsigned short* Pl = smem + 64 * VTPAD;    // [128][PLPAD=72]
    const unsigned short* vbase = kp + (size_t)(b * Tz) * 512 + 256 + h * HDz;
    #pragma unroll
    for (int i = 0; i < 8; ++i) {
        int e = tid + i * 256;
        int key = e >> 3, c8 = e & 7;
        ushort8v v8 = *(const ushort8v*)(vbase + (size_t)key * 512 + c8 * 8);
        #pragma unroll
        for (int j = 0; j < 8; ++j)
            Vt[(c8 * 8 + j) * VTPAD + key] = v8[j];
    }

    f32x4 accpv[2][4] = {};
    for (int ks = 0; ks < 4; ++ks) {          // 64-key chunks
        #pragma unroll
        for (int m = 0; m < 2; ++m) {
            #pragma unroll
            for (int rr = 0; rr < 4; ++rr) {
                int row = wave * 32 + m * 16 + g * 4 + rr;
                #pragma unroll
                for (int j = 0; j < 4; ++j)
                    Pl[row * PLPAD + j * 16 + l15] = f2bf_rne(acc[m][4 * ks + j][rr]);
            }
        }
        __syncthreads();   // Vt ready (1st iter) + Pl ready
        #pragma unroll
        for (int kk = 0; kk < 2; ++kk) {
            short8v a0 = *(const short8v*)&Pl[(wave * 32 + l15) * PLPAD + kk * 32 + g * 8];
            short8v a1 = *(const short8v*)&Pl[(wave * 32 + 16 + l15) * PLPAD + kk * 32 + g * 8];
            #pragma unroll
            for (int n = 0; n < 4; ++n) {
                short8v bn = *(const short8v*)&Vt[(n * 16 + l15) * VTPAD + ks * 64 + kk * 32 + g * 8];
                accpv[0][n] = __builtin_amdgcn_mfma_f32_16x16x32_bf16(a0, bn, accpv[0][n], 0, 0, 0);
                accpv[1][n] = __builtin_amdgcn_mfma_f32_16x16x32_bf16(a1, bn, accpv[1][n], 0, 0, 0);
            }
        }
        __syncthreads();
    }

    #pragma unroll
    for (int m = 0; m < 2; ++m) {
        #pragma unroll
        for (int rr = 0; rr < 4; ++rr) {
            int row = b * Tz + half * 128 + wave * 32 + m * 16 + g * 4 + rr;
            #pragma unroll
            for (int n = 0; n < 4; ++n)
                pv[(size_t)row * Hz + h * HDz + n * 16 + l15] = f2bf_rne(accpv[m][n][rr]);
        }
    }
}

// combo4: meanheads(1024) | final(128)
__global__ __launch_bounds__(256) void combo4_kernel(
    const unsigned short* __restrict__ probs, float* __restrict__ out_attn,
    const unsigned short* __restrict__ qBF, const unsigned short* __restrict__ pvb,
    const unsigned short* __restrict__ WoutT, const unsigned short* __restrict__ WoWoutT,
    const float* __restrict__ bocomb, float* __restrict__ out_imputed)
{
    __shared__ unsigned short smem[5120];
    const int bid = blockIdx.x;
    const int tid = threadIdx.x;
    if (bid < 1024) {
        meanheads_body(probs, out_attn, bid, tid);
    } else {
        final_body(smem, qBF, pvb, WoutT, WoWoutT, bocomb, out_imputed, bid - 1024, tid);
    }
}

// ---------------------------------------------------------------------------
extern "C" void kernel_launch(void* const* d_in, const int* in_sizes, int n_in,
                              void* d_out, int out_size, void* d_ws, size_t ws_size,
                              hipStream_t stream)
{
    const float* batch_data = (const float*)d_in[0];
    const float* mask_probs = (const float*)d_in[1];
    const float* sapE       = (const float*)d_in[2];
    const float* pair_emb   = (const float*)d_in[3];
    const int*   pair_present = (const int*)d_in[4];
    const float* W_num = (const float*)d_in[5];  const float* b_num = (const float*)d_in[6];
    const float* W_sap = (const float*)d_in[7];  const float* b_sap = (const float*)d_in[8];
    const float* W_ad  = (const float*)d_in[9];  const float* b_ad  = (const float*)d_in[10];
    const float* Wq = (const float*)d_in[11]; const float* bq = (const float*)d_in[12];
    const float* Wk = (const float*)d_in[13]; const float* bk = (const float*)d_in[14];
    const float* Wv = (const float*)d_in[15]; const float* bv = (const float*)d_in[16];
    const float* Wo = (const float*)d_in[17]; const float* bo = (const float*)d_in[18];
    const float* W_out = (const float*)d_in[19]; const float* b_out = (const float*)d_in[20];

    float* out = (float*)d_out;
    float* out_imputed = out;                 // [B,T,F]
    float* out_stoch   = out + 524288;        // [B,T,F]
    float* out_attn    = out + 1048576;       // [B,T,T]

    float* ws = (float*)d_ws;
    unsigned short* safe_bf = (unsigned short*)ws;             // bf16 [8192][64]
    unsigned short* qBF   = (unsigned short*)(ws + 524288);    // bf16 [8192][256]
    unsigned short* probs = (unsigned short*)(ws + 2621440);   // bf16 [128][256][256]
    unsigned long long* sel = (unsigned long long*)(ws + 9961472); // u64 [8192][16]
    unsigned short* qbb   = (unsigned short*)(ws + 11010048);  // bf16 [8192][256]
    unsigned short* Pe    = (unsigned short*)(ws + 15204352);  // bf16 [1024][768] (dead after combo2)
    unsigned short* kvproj = (unsigned short*)(ws + 15204352); // bf16 [8192][512] (over dead Pe)
    unsigned short* pvb   = (unsigned short*)(ws + 17301504);  // bf16 [8192][256]
    unsigned short* WoWoutT = (unsigned short*)(ws + 18350080);// bf16 [64][256]
    float* bocomb = ws + 18358272;                             // 64 f32
    float* bkv    = ws + 18358336;                             // 512 f32
    float* inv_cnt = ws + 18358848;                            // 8192 f32
    unsigned short* WadkvT = (unsigned short*)(ws + 18367040); // bf16 [512][768]
    unsigned short* WadB   = (unsigned short*)(ws + 18563648); // bf16 [768][256]
    unsigned short* PeWaT  = (unsigned short*)(ws + 18661952); // bf16 [512][1024]
    float* pooled = ws + 19398656;
    unsigned long long* mask64 = (unsigned long long*)(ws + 19398912);
    unsigned int* plist = (unsigned int*)(ws + 19415296);

    unsigned short* wT = (unsigned short*)(ws + 19419392);
    unsigned short* WnumT = wT;                  // [256][64]
    unsigned short* WadT  = wT + 16384;          // [256][768]
    unsigned short* WqT   = wT + 212992;         // [256][256]
    unsigned short* WkT   = wT + 278528;         // (WkT,WvT contiguous)
    unsigned short* WvT   = wT + 344064;
    unsigned short* WoT   = wT + 409600;
    unsigned short* WoutT = wT + 475136;         // [64][256]

    // 1. prep
    prep_kernel<<<676, 256, 0, stream>>>(
        W_num, W_ad, Wq, Wk, Wv, Wo, W_out, bo, b_out, b_ad, bk, bv, pair_present,
        WnumT, WadT, WqT, WkT, WvT, WoT, WoutT, bocomb, bkv, WadB, plist);
    // 2. combo1: WoWoutT | WadkvT | pooled | mask | Pe gather
    combo1_kernel<<<3102, 256, 0, stream>>>(
        WoutT, WoT, WoWoutT, WkT, WadB, WadkvT,
        sapE, W_sap, b_sap, pooled,
        batch_data, mask_probs, safe_bf, out_stoch, mask64,
        pair_emb, plist, Pe);
    // 3. combo2: query GEMM | wbuild | PeWaT = WadkvT @ Pe^T
    combo2_kernel<<<672, 256, 0, stream>>>(
        safe_bf, WnumT, b_num, pooled, qBF,
        mask64, plist, sel, inv_cnt, WadkvT, Pe, PeWaT);
    // 4. combo3: selkv GEMM (kvproj, algebraic ctx fusion) | q projection
    combo3_kernel<<<640, 256, 0, stream>>>(
        sel, PeWaT, inv_cnt, bkv, kvproj, qBF, WqT, bq, qbb);
    // 5. fused attention
    attn_fused_kernel<<<256, 256, 0, stream>>>(qbb, kvproj, probs, pvb);
    // 6. combo4: meanheads | final
    combo4_kernel<<<1152, 256, 0, stream>>>(
        probs, out_attn, qBF, pvb, WoutT, WoWoutT, bocomb, out_imputed);
}